// Round 4
// baseline (1243.046 us; speedup 1.0000x reference)
//
#include <hip/hip_runtime.h>
#include <cstdint>

// ---------------------------------------------------------------------------
// GCN twin-tower forward, f32. Round 4: GEMM rework.
//   - 64x128 tile (782 blocks -> ~3 blocks/CU), 256 thr, 8x4 per thread
//   - A staged [m][k] (pitch 36): a-frags = broadcast ds_read_b128 (k-quads)
//   - B staged [k][n] (pitch 132): b-frags contiguous 16B/lane
//   - double-buffered LDS, register prefetch, 1 barrier per K-step
// ---------------------------------------------------------------------------

// ---------------- BN stats: per-feature sum / sumsq over N rows -------------
__global__ __launch_bounds__(256) void bn_stats_k(
    const float* __restrict__ x, float* __restrict__ bnsum,
    float* __restrict__ bnsq, int n) {
  __shared__ float ls[256], lq[256];
  const int tid = threadIdx.x;
  const int f = tid & 63;
  const int rb = tid >> 6;  // 0..3
  float s = 0.f, q = 0.f;
  for (int r = blockIdx.x * 4 + rb; r < n; r += gridDim.x * 4) {
    float v = x[(size_t)r * 64 + f];
    s += v;
    q += v * v;
  }
  ls[tid] = s;
  lq[tid] = q;
  __syncthreads();
  if (tid < 64) {
    s = ls[tid] + ls[tid + 64] + ls[tid + 128] + ls[tid + 192];
    q = lq[tid] + lq[tid + 64] + lq[tid + 128] + lq[tid + 192];
    atomicAdd(&bnsum[tid], s);
    atomicAdd(&bnsq[tid], q);
  }
}

// ------------- Fold BN affine into W1 (64x256) and b1 (256) ----------------
__global__ __launch_bounds__(256) void bn_fold_k(
    const float* __restrict__ bnsum, const float* __restrict__ bnsq,
    const float* __restrict__ gamma, const float* __restrict__ beta,
    const float* __restrict__ W1, const float* __restrict__ b1,
    float* __restrict__ W1f, float* __restrict__ b1f, float inv_n) {
  __shared__ float a[64], bf[64];
  const int tid = threadIdx.x;
  if (tid < 64) {
    float mu = bnsum[tid] * inv_n;
    float var = bnsq[tid] * inv_n - mu * mu;
    float s = gamma[tid] * rsqrtf(var + 1e-5f);
    a[tid] = s;
    bf[tid] = beta[tid] - mu * s;
  }
  __syncthreads();
  float acc = 0.f;
#pragma unroll
  for (int f = 0; f < 64; ++f) {
    float w = W1[f * 256 + tid];
    W1f[f * 256 + tid] = a[f] * w;
    acc += bf[f] * w;
  }
  b1f[tid] = b1[tid] + acc;
}

// ---------------- f32 GEMM: C = relu?(A@B + bias) --------------------------
// A: [M,K] row-major, B: [K,N] row-major. Requires K%32==0, N%128==0.
// 64x128 tile, 256 threads, 8x4 per thread, double-buffered LDS.
#define GBM 64
#define GBN 128
#define GBK 32
__global__ __launch_bounds__(256) void gemm_f32(
    const float* __restrict__ A, const float* __restrict__ Bm,
    const float* __restrict__ bias, float* __restrict__ C, int M, int N, int K,
    int relu) {
  __shared__ float As[2][GBM][36];   // [m][k], pitch 36 (144B, 16B-aligned)
  __shared__ float Bs[2][GBK][132];  // [k][n], pitch 132 (528B, 16B-aligned)
  const int tid = threadIdx.x;
  const int bx = blockIdx.x, by = blockIdx.y;
  const int tn = tid & 31;  // col group: 4 cols
  const int tm = tid >> 5;  // row group: 8 rows
  // staging assignment
  const int am = tid >> 2;         // 0..63  (A row)
  const int ak = (tid & 3) * 8;    // A k offset (2 float4)
  const int br = tid >> 3;         // 0..31  (B k-row)
  const int bc = (tid & 7) * 16;   // B col offset (4 float4)
  const int arow = by * GBM + am;
  const float* aptr = A + (size_t)arow * K + ak;
  const float* bptr = Bm + (size_t)br * N + bx * GBN + bc;

  float4 pa0, pa1, pb0, pb1, pb2, pb3;
  // ---- load tile 0 into regs, then LDS[0]
  if (arow < M) {
    pa0 = *(const float4*)aptr;
    pa1 = *(const float4*)(aptr + 4);
  } else {
    pa0 = make_float4(0.f, 0.f, 0.f, 0.f);
    pa1 = pa0;
  }
  pb0 = *(const float4*)bptr;
  pb1 = *(const float4*)(bptr + 4);
  pb2 = *(const float4*)(bptr + 8);
  pb3 = *(const float4*)(bptr + 12);
  *(float4*)&As[0][am][ak] = pa0;
  *(float4*)&As[0][am][ak + 4] = pa1;
  *(float4*)&Bs[0][br][bc] = pb0;
  *(float4*)&Bs[0][br][bc + 4] = pb1;
  *(float4*)&Bs[0][br][bc + 8] = pb2;
  *(float4*)&Bs[0][br][bc + 12] = pb3;
  __syncthreads();

  float acc[8][4] = {};
  const int nk = K / GBK;
  for (int t = 0; t < nk; ++t) {
    const int cur = t & 1;
    const bool more = (t + 1) < nk;
    if (more) {  // prefetch next tile into regs (latency hides under FMAs)
      const float* ap = aptr + (t + 1) * GBK;
      if (arow < M) {
        pa0 = *(const float4*)ap;
        pa1 = *(const float4*)(ap + 4);
      } else {
        pa0 = make_float4(0.f, 0.f, 0.f, 0.f);
        pa1 = pa0;
      }
      const float* bp = bptr + (size_t)(t + 1) * GBK * N;
      pb0 = *(const float4*)bp;
      pb1 = *(const float4*)(bp + 4);
      pb2 = *(const float4*)(bp + 8);
      pb3 = *(const float4*)(bp + 12);
    }
#pragma unroll
    for (int kq = 0; kq < GBK / 4; ++kq) {
      float4 ar[8];
#pragma unroll
      for (int i = 0; i < 8; ++i)
        ar[i] = *(const float4*)&As[cur][tm * 8 + i][kq * 4];
      float4 brg[4];
#pragma unroll
      for (int kk = 0; kk < 4; ++kk)
        brg[kk] = *(const float4*)&Bs[cur][kq * 4 + kk][tn * 4];
#pragma unroll
      for (int i = 0; i < 8; ++i) {
        acc[i][0] += ar[i].x * brg[0].x;
        acc[i][1] += ar[i].x * brg[0].y;
        acc[i][2] += ar[i].x * brg[0].z;
        acc[i][3] += ar[i].x * brg[0].w;
        acc[i][0] += ar[i].y * brg[1].x;
        acc[i][1] += ar[i].y * brg[1].y;
        acc[i][2] += ar[i].y * brg[1].z;
        acc[i][3] += ar[i].y * brg[1].w;
        acc[i][0] += ar[i].z * brg[2].x;
        acc[i][1] += ar[i].z * brg[2].y;
        acc[i][2] += ar[i].z * brg[2].z;
        acc[i][3] += ar[i].z * brg[2].w;
        acc[i][0] += ar[i].w * brg[3].x;
        acc[i][1] += ar[i].w * brg[3].y;
        acc[i][2] += ar[i].w * brg[3].z;
        acc[i][3] += ar[i].w * brg[3].w;
      }
    }
    if (more) {
      const int alt = cur ^ 1;
      *(float4*)&As[alt][am][ak] = pa0;
      *(float4*)&As[alt][am][ak + 4] = pa1;
      *(float4*)&Bs[alt][br][bc] = pb0;
      *(float4*)&Bs[alt][br][bc + 4] = pb1;
      *(float4*)&Bs[alt][br][bc + 8] = pb2;
      *(float4*)&Bs[alt][br][bc + 12] = pb3;
      __syncthreads();
    }
  }

  const int col0 = bx * GBN + tn * 4;
  float4 bv = make_float4(0.f, 0.f, 0.f, 0.f);
  if (bias) bv = *(const float4*)(bias + col0);
#pragma unroll
  for (int i = 0; i < 8; ++i) {
    const int r = by * GBM + tm * 8 + i;
    if (r >= M) continue;
    float4 v;
    v.x = acc[i][0] + bv.x;
    v.y = acc[i][1] + bv.y;
    v.z = acc[i][2] + bv.z;
    v.w = acc[i][3] + bv.w;
    if (relu) {
      v.x = fmaxf(v.x, 0.f);
      v.y = fmaxf(v.y, 0.f);
      v.z = fmaxf(v.z, 0.f);
      v.w = fmaxf(v.w, 0.f);
    }
    *(float4*)(C + (size_t)r * N + col0) = v;
  }
}

// ---------------- degree count (incoming edges per node) -------------------
__global__ __launch_bounds__(256) void count_deg_k(const int* __restrict__ dst,
                                                   int* __restrict__ cnt,
                                                   int e) {
  int i = blockIdx.x * 256 + threadIdx.x;
  if (i < e) atomicAdd(&cnt[dst[i]], 1);
}

__global__ __launch_bounds__(256) void dinv_k(const int* __restrict__ cnt,
                                              float* __restrict__ dinv, int n) {
  int i = blockIdx.x * 256 + threadIdx.x;
  if (i < n) dinv[i] = rsqrtf((float)(cnt[i] + 1));  // +1 self loop
}

// ---------------- CSR build: exclusive scan of deg over N ------------------
__global__ __launch_bounds__(256) void scan1_k(const int* __restrict__ deg,
                                               int* __restrict__ bsum, int n) {
  __shared__ int ls[256];
  const int base = blockIdx.x * 1024;
  int s = 0;
  for (int j = threadIdx.x; j < 1024; j += 256) {
    int i = base + j;
    s += (i < n) ? deg[i] : 0;
  }
  ls[threadIdx.x] = s;
  __syncthreads();
  for (int off = 128; off > 0; off >>= 1) {
    if (threadIdx.x < off) ls[threadIdx.x] += ls[threadIdx.x + off];
    __syncthreads();
  }
  if (threadIdx.x == 0) bsum[blockIdx.x] = ls[0];
}

__global__ void scan2_k(int* __restrict__ bsum, int nb) {
  if (threadIdx.x == 0 && blockIdx.x == 0) {
    int acc = 0;
    for (int i = 0; i < nb; ++i) {
      int v = bsum[i];
      bsum[i] = acc;
      acc += v;
    }
  }
}

__global__ __launch_bounds__(256) void scan3_k(
    const int* __restrict__ deg, const int* __restrict__ bsum,
    int* __restrict__ rowstart, int* __restrict__ cursor, int n, int e) {
  __shared__ int ts[256];
  const int tid = threadIdx.x;
  const int i0 = blockIdx.x * 1024 + tid * 4;
  int v[4];
  int s = 0;
#pragma unroll
  for (int j = 0; j < 4; ++j) {
    int i = i0 + j;
    v[j] = (i < n) ? deg[i] : 0;
    s += v[j];
  }
  ts[tid] = s;
  __syncthreads();
  for (int off = 1; off < 256; off <<= 1) {
    int t = (tid >= off) ? ts[tid - off] : 0;
    __syncthreads();
    ts[tid] += t;
    __syncthreads();
  }
  int run = bsum[blockIdx.x] + ts[tid] - s;  // exclusive prefix
#pragma unroll
  for (int j = 0; j < 4; ++j) {
    int i = i0 + j;
    if (i < n) {
      rowstart[i] = run;
      cursor[i] = run;
    }
    run += v[j];
  }
  if (blockIdx.x == 0 && tid == 0) rowstart[n] = e;
}

// fill: dst-sorted packed (src, norm) edges; norm computed inline
__global__ __launch_bounds__(256) void fillnorm_k(
    const int* __restrict__ src, const int* __restrict__ dst,
    const float* __restrict__ dinv, int* __restrict__ cursor,
    int2* __restrict__ epack, int e) {
  int i = blockIdx.x * 256 + threadIdx.x;
  if (i >= e) return;
  int s = src[i], d = dst[i];
  int pos = atomicAdd(&cursor[d], 1);
  epack[pos] = make_int2(s, __float_as_int(dinv[s] * dinv[d]));
}

// ---------------- gather: out[v] = relu(self + sum_in + bias) --------------
// 32 threads per node, float4 per thread (128 feat).
__global__ __launch_bounds__(256) void gather_k(
    const int* __restrict__ rowstart, const int2* __restrict__ epack,
    const float* __restrict__ xw, const float* __restrict__ dinv,
    const float* __restrict__ bias, float* __restrict__ out, int n) {
  int gid = blockIdx.x * 256 + threadIdx.x;
  int v = gid >> 5;
  if (v >= n) return;
  int q = gid & 31;
  const float4* xw4 = (const float4*)xw;
  float d = dinv[v];
  float sl = d * d;
  float4 acc = xw4[(size_t)v * 32 + q];
  acc.x *= sl; acc.y *= sl; acc.z *= sl; acc.w *= sl;
  int s0 = rowstart[v], s1 = rowstart[v + 1];
  for (int e = s0; e < s1; ++e) {
    int2 ed = epack[e];
    float w = __int_as_float(ed.y);
    float4 t = xw4[(size_t)ed.x * 32 + q];
    acc.x += t.x * w;
    acc.y += t.y * w;
    acc.z += t.z * w;
    acc.w += t.w * w;
  }
  float4 bb = ((const float4*)bias)[q];
  acc.x = fmaxf(acc.x + bb.x, 0.f);
  acc.y = fmaxf(acc.y + bb.y, 0.f);
  acc.z = fmaxf(acc.z + bb.z, 0.f);
  acc.w = fmaxf(acc.w + bb.w, 0.f);
  ((float4*)out)[(size_t)v * 32 + q] = acc;
}

// ---------------- pool: segmented mean over sorted batch -------------------
__global__ __launch_bounds__(256) void bstart_k(const int* __restrict__ batch,
                                                int* __restrict__ bstart,
                                                int n, int nb) {
  int b = blockIdx.x * 256 + threadIdx.x;
  if (b > nb) return;
  int lo = 0, hi = n;
  while (lo < hi) {
    int mid = (lo + hi) >> 1;
    if (batch[mid] < b) lo = mid + 1; else hi = mid;
  }
  bstart[b] = lo;
}

// one block (128 threads) per graph; h rows are contiguous per graph
__global__ __launch_bounds__(128) void pool_seg_k(
    const float* __restrict__ h, const int* __restrict__ bstart,
    float* __restrict__ cat, int toff) {
  int b = blockIdx.x;
  int s = bstart[b], e = bstart[b + 1];
  int f = threadIdx.x;
  float acc = 0.f;
  for (int v = s; v < e; ++v) acc += h[(size_t)v * 128 + f];
  float c = fmaxf((float)(e - s), 1.f);
  cat[(size_t)b * 256 + toff + f] = acc / c;
}

// ---------------- final: out[r] = z2[r,:]@W5 + b5 --------------------------
__global__ __launch_bounds__(256) void final_k(const float* __restrict__ z2,
                                               const float* __restrict__ W5,
                                               const float* __restrict__ b5,
                                               float* __restrict__ out,
                                               int rows) {
  int r = blockIdx.x * 256 + threadIdx.x;
  if (r >= rows) return;
  float acc = b5[0];
#pragma unroll
  for (int k = 0; k < 128; ++k) acc += z2[(size_t)r * 128 + k] * W5[k];
  out[r] = acc;
}

// ---------------------------------------------------------------------------
extern "C" void kernel_launch(void* const* d_in, const int* in_sizes, int n_in,
                              void* d_out, int out_size, void* d_ws,
                              size_t ws_size, hipStream_t stream) {
  const float* x[2] = {(const float*)d_in[0], (const float*)d_in[3]};
  const int* ei[2] = {(const int*)d_in[1], (const int*)d_in[4]};
  const int* batch[2] = {(const int*)d_in[2], (const int*)d_in[5]};
  const float* gamma = (const float*)d_in[6];
  const float* beta = (const float*)d_in[7];
  const float* W1 = (const float*)d_in[8];
  const float* b1 = (const float*)d_in[9];
  const float* W2 = (const float*)d_in[10];
  const float* b2 = (const float*)d_in[11];
  const float* Wc[3] = {(const float*)d_in[12], (const float*)d_in[14],
                        (const float*)d_in[16]};
  const float* bc[3] = {(const float*)d_in[13], (const float*)d_in[15],
                        (const float*)d_in[17]};
  const float* W3 = (const float*)d_in[18];
  const float* b3 = (const float*)d_in[19];
  const float* W4 = (const float*)d_in[20];
  const float* b4 = (const float*)d_in[21];
  const float* W5 = (const float*)d_in[22];
  const float* b5 = (const float*)d_in[23];
  float* out = (float*)d_out;

  const int N = in_sizes[0] / 64;  // 50000
  const int E = in_sizes[1] / 2;   // 600000
  const int B = out_size;          // 512

  // ---- workspace layout ----
  float* ws = (float*)d_ws;
  float* bufA = ws;                            // N*256
  float* bufB = bufA + (size_t)N * 256;        // N*128
  float* bufC = bufB + (size_t)N * 128;        // N*128
  float* dinv = bufC + (size_t)N * 128;        // N
  int2* epack = (int2*)(dinv + N);             // E int2 (8B, offset even)
  int* degc = (int*)(epack + E);               // N
  int* rowstart = degc + N;                    // N+1
  int* cursor = rowstart + N + 1;              // N
  int* bsum = cursor + N;                      // 64
  int* bstart = bsum + 64;                     // B+1
  float* bnsum = (float*)(bstart + B + 1);     // 64
  float* bnsq = bnsum + 64;                    // 64
  float* W1f = bnsq + 64;                      // 16384
  float* b1f = W1f + 16384;                    // 256
  float* catb = b1f + 256;                     // B*256
  float* z1 = catb + (size_t)B * 256;          // B*256
  float* z2 = z1 + (size_t)B * 256;            // B*128
  size_t need = (size_t)((char*)(z2 + (size_t)B * 128) - (char*)d_ws);
  if (ws_size < need) return;  // workspace too small -> fail loudly

  const int nb_e = (E + 255) / 256;
  const int nb_n = (N + 255) / 256;
  const int nb_scan = (N + 1023) / 1024;
  const int nb_ga = (N * 32 + 255) / 256;
  const int gby = (N + GBM - 1) / GBM;  // 782

  for (int t = 0; t < 2; ++t) {
    const int* srcp = ei[t];
    const int* dstp = ei[t] + E;

    hipMemsetAsync(bnsum, 0, 128 * sizeof(float), stream);
    hipMemsetAsync(degc, 0, (size_t)N * sizeof(int), stream);

    bn_stats_k<<<256, 256, 0, stream>>>(x[t], bnsum, bnsq, N);
    bn_fold_k<<<1, 256, 0, stream>>>(bnsum, bnsq, gamma, beta, W1, b1, W1f,
                                     b1f, 1.0f / (float)N);

    gemm_f32<<<dim3(2, gby), 256, 0, stream>>>(x[t], W1f, b1f, bufA, N, 256,
                                               64, 1);
    gemm_f32<<<dim3(1, gby), 256, 0, stream>>>(bufA, W2, b2, bufB, N, 128, 256,
                                               1);

    count_deg_k<<<nb_e, 256, 0, stream>>>(dstp, degc, E);
    dinv_k<<<nb_n, 256, 0, stream>>>(degc, dinv, N);

    scan1_k<<<nb_scan, 256, 0, stream>>>(degc, bsum, N);
    scan2_k<<<1, 64, 0, stream>>>(bsum, nb_scan);
    scan3_k<<<nb_scan, 256, 0, stream>>>(degc, bsum, rowstart, cursor, N, E);
    fillnorm_k<<<nb_e, 256, 0, stream>>>(srcp, dstp, dinv, cursor, epack, E);

    bstart_k<<<(B + 256) / 256, 256, 0, stream>>>(batch[t], bstart, N, B);

    float* hin = bufB;
    for (int c = 0; c < 3; ++c) {
      float* hout = (c == 1) ? bufB : bufA;  // ping-pong: B->A->B->A
      gemm_f32<<<dim3(1, gby), 256, 0, stream>>>(hin, Wc[c], nullptr, bufC, N,
                                                 128, 128, 0);
      gather_k<<<nb_ga, 256, 0, stream>>>(rowstart, epack, bufC, dinv, bc[c],
                                          hout, N);
      hin = hout;
    }

    pool_seg_k<<<B, 128, 0, stream>>>(hin, bstart, catb, t * 128);
  }

  gemm_f32<<<dim3(2, (B + GBM - 1) / GBM), 256, 0, stream>>>(catb, W3, b3, z1,
                                                             B, 256, 256, 1);
  gemm_f32<<<dim3(1, (B + GBM - 1) / GBM), 256, 0, stream>>>(z1, W4, b4, z2, B,
                                                             128, 256, 1);
  final_k<<<(B + 255) / 256, 256, 0, stream>>>(z2, W5, b5, out, B);
}

// Round 5
// 1025.456 us; speedup vs baseline: 1.2122x; 1.2122x over previous
//
#include <hip/hip_runtime.h>
#include <cstdint>

// ---------------------------------------------------------------------------
// GCN twin-tower forward, f32. Round 5: GEMM fix (revert dbuf, keep layout).
//   - 64x128 tile (782 blocks ~ 3/CU), 256 thr, 8x4/thread
//   - SINGLE LDS buffer (26KB), As[m][k] pitch 36 (broadcast b128 A-frags),
//     Bs[k][n] pitch 132 (contiguous b128 B-frags)
//   - register prefetch issued AFTER staging barrier -> hides under FMAs,
//     short live range keeps VGPR ~120 (round 4's 228 VGPR killed occupancy)
// ---------------------------------------------------------------------------

// ---------------- BN stats: per-feature sum / sumsq over N rows -------------
__global__ __launch_bounds__(256) void bn_stats_k(
    const float* __restrict__ x, float* __restrict__ bnsum,
    float* __restrict__ bnsq, int n) {
  __shared__ float ls[256], lq[256];
  const int tid = threadIdx.x;
  const int f = tid & 63;
  const int rb = tid >> 6;  // 0..3
  float s = 0.f, q = 0.f;
  for (int r = blockIdx.x * 4 + rb; r < n; r += gridDim.x * 4) {
    float v = x[(size_t)r * 64 + f];
    s += v;
    q += v * v;
  }
  ls[tid] = s;
  lq[tid] = q;
  __syncthreads();
  if (tid < 64) {
    s = ls[tid] + ls[tid + 64] + ls[tid + 128] + ls[tid + 192];
    q = lq[tid] + lq[tid + 64] + lq[tid + 128] + lq[tid + 192];
    atomicAdd(&bnsum[tid], s);
    atomicAdd(&bnsq[tid], q);
  }
}

// ------------- Fold BN affine into W1 (64x256) and b1 (256) ----------------
__global__ __launch_bounds__(256) void bn_fold_k(
    const float* __restrict__ bnsum, const float* __restrict__ bnsq,
    const float* __restrict__ gamma, const float* __restrict__ beta,
    const float* __restrict__ W1, const float* __restrict__ b1,
    float* __restrict__ W1f, float* __restrict__ b1f, float inv_n) {
  __shared__ float a[64], bf[64];
  const int tid = threadIdx.x;
  if (tid < 64) {
    float mu = bnsum[tid] * inv_n;
    float var = bnsq[tid] * inv_n - mu * mu;
    float s = gamma[tid] * rsqrtf(var + 1e-5f);
    a[tid] = s;
    bf[tid] = beta[tid] - mu * s;
  }
  __syncthreads();
  float acc = 0.f;
#pragma unroll
  for (int f = 0; f < 64; ++f) {
    float w = W1[f * 256 + tid];
    W1f[f * 256 + tid] = a[f] * w;
    acc += bf[f] * w;
  }
  b1f[tid] = b1[tid] + acc;
}

// ---------------- f32 GEMM: C = relu?(A@B + bias) --------------------------
// A: [M,K] row-major, B: [K,N] row-major. Requires K%32==0, N%128==0.
// 64x128 tile, 256 threads, 8x4 per thread, single-buffer LDS + reg prefetch.
#define GBM 64
#define GBN 128
#define GBK 32
__global__ __launch_bounds__(256) void gemm_f32(
    const float* __restrict__ A, const float* __restrict__ Bm,
    const float* __restrict__ bias, float* __restrict__ C, int M, int N, int K,
    int relu) {
  __shared__ float As[GBM][36];   // [m][k], pitch 36 (144B, 16B-aligned)
  __shared__ float Bs[GBK][132];  // [k][n], pitch 132 (528B, 16B-aligned)
  const int tid = threadIdx.x;
  const int bx = blockIdx.x, by = blockIdx.y;
  const int tn = tid & 31;  // col group: 4 cols
  const int tm = tid >> 5;  // row group: 8 rows
  // staging assignment
  const int am = tid >> 2;        // 0..63  (A row)
  const int ak = (tid & 3) * 8;   // A k offset (2 float4)
  const int br = tid >> 3;        // 0..31  (B k-row)
  const int bc = (tid & 7) * 16;  // B col offset (4 float4)
  const int arow = by * GBM + am;
  const float* aptr = A + (size_t)arow * K + ak;
  const float* bptr = Bm + (size_t)br * N + bx * GBN + bc;

  float4 pa0, pa1, pb0, pb1, pb2, pb3;
  // load tile 0 into regs
  if (arow < M) {
    pa0 = *(const float4*)aptr;
    pa1 = *(const float4*)(aptr + 4);
  } else {
    pa0 = make_float4(0.f, 0.f, 0.f, 0.f);
    pa1 = pa0;
  }
  pb0 = *(const float4*)bptr;
  pb1 = *(const float4*)(bptr + 4);
  pb2 = *(const float4*)(bptr + 8);
  pb3 = *(const float4*)(bptr + 12);

  float acc[8][4] = {};
  const int nk = K / GBK;
  for (int t = 0; t < nk; ++t) {
    if (t) __syncthreads();  // previous compute done
    *(float4*)&As[am][ak] = pa0;
    *(float4*)&As[am][ak + 4] = pa1;
    *(float4*)&Bs[br][bc] = pb0;
    *(float4*)&Bs[br][bc + 4] = pb1;
    *(float4*)&Bs[br][bc + 8] = pb2;
    *(float4*)&Bs[br][bc + 12] = pb3;
    __syncthreads();  // staging done
    if (t + 1 < nk) {  // issue next-tile loads; latency hides under FMAs
      const float* ap = aptr + (t + 1) * GBK;
      if (arow < M) {
        pa0 = *(const float4*)ap;
        pa1 = *(const float4*)(ap + 4);
      } else {
        pa0 = make_float4(0.f, 0.f, 0.f, 0.f);
        pa1 = pa0;
      }
      const float* bp = bptr + (size_t)(t + 1) * GBK * N;
      pb0 = *(const float4*)bp;
      pb1 = *(const float4*)(bp + 4);
      pb2 = *(const float4*)(bp + 8);
      pb3 = *(const float4*)(bp + 12);
    }
#pragma unroll
    for (int kq = 0; kq < GBK / 4; ++kq) {
      float4 ar[8];
#pragma unroll
      for (int i = 0; i < 8; ++i)
        ar[i] = *(const float4*)&As[tm * 8 + i][kq * 4];
      float4 brg[4];
#pragma unroll
      for (int kk = 0; kk < 4; ++kk)
        brg[kk] = *(const float4*)&Bs[kq * 4 + kk][tn * 4];
#pragma unroll
      for (int i = 0; i < 8; ++i) {
        acc[i][0] += ar[i].x * brg[0].x;
        acc[i][1] += ar[i].x * brg[0].y;
        acc[i][2] += ar[i].x * brg[0].z;
        acc[i][3] += ar[i].x * brg[0].w;
        acc[i][0] += ar[i].y * brg[1].x;
        acc[i][1] += ar[i].y * brg[1].y;
        acc[i][2] += ar[i].y * brg[1].z;
        acc[i][3] += ar[i].y * brg[1].w;
        acc[i][0] += ar[i].z * brg[2].x;
        acc[i][1] += ar[i].z * brg[2].y;
        acc[i][2] += ar[i].z * brg[2].z;
        acc[i][3] += ar[i].z * brg[2].w;
        acc[i][0] += ar[i].w * brg[3].x;
        acc[i][1] += ar[i].w * brg[3].y;
        acc[i][2] += ar[i].w * brg[3].z;
        acc[i][3] += ar[i].w * brg[3].w;
      }
    }
  }

  const int col0 = bx * GBN + tn * 4;
  float4 bv = make_float4(0.f, 0.f, 0.f, 0.f);
  if (bias) bv = *(const float4*)(bias + col0);
#pragma unroll
  for (int i = 0; i < 8; ++i) {
    const int r = by * GBM + tm * 8 + i;
    if (r >= M) continue;
    float4 v;
    v.x = acc[i][0] + bv.x;
    v.y = acc[i][1] + bv.y;
    v.z = acc[i][2] + bv.z;
    v.w = acc[i][3] + bv.w;
    if (relu) {
      v.x = fmaxf(v.x, 0.f);
      v.y = fmaxf(v.y, 0.f);
      v.z = fmaxf(v.z, 0.f);
      v.w = fmaxf(v.w, 0.f);
    }
    *(float4*)(C + (size_t)r * N + col0) = v;
  }
}

// ---------------- degree count (incoming edges per node) -------------------
__global__ __launch_bounds__(256) void count_deg_k(const int* __restrict__ dst,
                                                   int* __restrict__ cnt,
                                                   int e) {
  int i = blockIdx.x * 256 + threadIdx.x;
  if (i < e) atomicAdd(&cnt[dst[i]], 1);
}

__global__ __launch_bounds__(256) void dinv_k(const int* __restrict__ cnt,
                                              float* __restrict__ dinv, int n) {
  int i = blockIdx.x * 256 + threadIdx.x;
  if (i < n) dinv[i] = rsqrtf((float)(cnt[i] + 1));  // +1 self loop
}

// ---------------- CSR build: exclusive scan of deg over N ------------------
__global__ __launch_bounds__(256) void scan1_k(const int* __restrict__ deg,
                                               int* __restrict__ bsum, int n) {
  __shared__ int ls[256];
  const int base = blockIdx.x * 1024;
  int s = 0;
  for (int j = threadIdx.x; j < 1024; j += 256) {
    int i = base + j;
    s += (i < n) ? deg[i] : 0;
  }
  ls[threadIdx.x] = s;
  __syncthreads();
  for (int off = 128; off > 0; off >>= 1) {
    if (threadIdx.x < off) ls[threadIdx.x] += ls[threadIdx.x + off];
    __syncthreads();
  }
  if (threadIdx.x == 0) bsum[blockIdx.x] = ls[0];
}

__global__ void scan2_k(int* __restrict__ bsum, int nb) {
  if (threadIdx.x == 0 && blockIdx.x == 0) {
    int acc = 0;
    for (int i = 0; i < nb; ++i) {
      int v = bsum[i];
      bsum[i] = acc;
      acc += v;
    }
  }
}

__global__ __launch_bounds__(256) void scan3_k(
    const int* __restrict__ deg, const int* __restrict__ bsum,
    int* __restrict__ rowstart, int* __restrict__ cursor, int n, int e) {
  __shared__ int ts[256];
  const int tid = threadIdx.x;
  const int i0 = blockIdx.x * 1024 + tid * 4;
  int v[4];
  int s = 0;
#pragma unroll
  for (int j = 0; j < 4; ++j) {
    int i = i0 + j;
    v[j] = (i < n) ? deg[i] : 0;
    s += v[j];
  }
  ts[tid] = s;
  __syncthreads();
  for (int off = 1; off < 256; off <<= 1) {
    int t = (tid >= off) ? ts[tid - off] : 0;
    __syncthreads();
    ts[tid] += t;
    __syncthreads();
  }
  int run = bsum[blockIdx.x] + ts[tid] - s;  // exclusive prefix
#pragma unroll
  for (int j = 0; j < 4; ++j) {
    int i = i0 + j;
    if (i < n) {
      rowstart[i] = run;
      cursor[i] = run;
    }
    run += v[j];
  }
  if (blockIdx.x == 0 && tid == 0) rowstart[n] = e;
}

// fill: dst-sorted packed (src, norm) edges; norm computed inline
__global__ __launch_bounds__(256) void fillnorm_k(
    const int* __restrict__ src, const int* __restrict__ dst,
    const float* __restrict__ dinv, int* __restrict__ cursor,
    int2* __restrict__ epack, int e) {
  int i = blockIdx.x * 256 + threadIdx.x;
  if (i >= e) return;
  int s = src[i], d = dst[i];
  int pos = atomicAdd(&cursor[d], 1);
  epack[pos] = make_int2(s, __float_as_int(dinv[s] * dinv[d]));
}

// ---------------- gather: out[v] = relu(self + sum_in + bias) --------------
// 32 threads per node, float4 per thread (128 feat).
__global__ __launch_bounds__(256) void gather_k(
    const int* __restrict__ rowstart, const int2* __restrict__ epack,
    const float* __restrict__ xw, const float* __restrict__ dinv,
    const float* __restrict__ bias, float* __restrict__ out, int n) {
  int gid = blockIdx.x * 256 + threadIdx.x;
  int v = gid >> 5;
  if (v >= n) return;
  int q = gid & 31;
  const float4* xw4 = (const float4*)xw;
  float d = dinv[v];
  float sl = d * d;
  float4 acc = xw4[(size_t)v * 32 + q];
  acc.x *= sl; acc.y *= sl; acc.z *= sl; acc.w *= sl;
  int s0 = rowstart[v], s1 = rowstart[v + 1];
  for (int e = s0; e < s1; ++e) {
    int2 ed = epack[e];
    float w = __int_as_float(ed.y);
    float4 t = xw4[(size_t)ed.x * 32 + q];
    acc.x += t.x * w;
    acc.y += t.y * w;
    acc.z += t.z * w;
    acc.w += t.w * w;
  }
  float4 bb = ((const float4*)bias)[q];
  acc.x = fmaxf(acc.x + bb.x, 0.f);
  acc.y = fmaxf(acc.y + bb.y, 0.f);
  acc.z = fmaxf(acc.z + bb.z, 0.f);
  acc.w = fmaxf(acc.w + bb.w, 0.f);
  ((float4*)out)[(size_t)v * 32 + q] = acc;
}

// ---------------- pool: segmented mean over sorted batch -------------------
__global__ __launch_bounds__(256) void bstart_k(const int* __restrict__ batch,
                                                int* __restrict__ bstart,
                                                int n, int nb) {
  int b = blockIdx.x * 256 + threadIdx.x;
  if (b > nb) return;
  int lo = 0, hi = n;
  while (lo < hi) {
    int mid = (lo + hi) >> 1;
    if (batch[mid] < b) lo = mid + 1; else hi = mid;
  }
  bstart[b] = lo;
}

// one block (128 threads) per graph; h rows are contiguous per graph
__global__ __launch_bounds__(128) void pool_seg_k(
    const float* __restrict__ h, const int* __restrict__ bstart,
    float* __restrict__ cat, int toff) {
  int b = blockIdx.x;
  int s = bstart[b], e = bstart[b + 1];
  int f = threadIdx.x;
  float acc = 0.f;
  for (int v = s; v < e; ++v) acc += h[(size_t)v * 128 + f];
  float c = fmaxf((float)(e - s), 1.f);
  cat[(size_t)b * 256 + toff + f] = acc / c;
}

// ---------------- final: out[r] = z2[r,:]@W5 + b5 --------------------------
__global__ __launch_bounds__(256) void final_k(const float* __restrict__ z2,
                                               const float* __restrict__ W5,
                                               const float* __restrict__ b5,
                                               float* __restrict__ out,
                                               int rows) {
  int r = blockIdx.x * 256 + threadIdx.x;
  if (r >= rows) return;
  float acc = b5[0];
#pragma unroll
  for (int k = 0; k < 128; ++k) acc += z2[(size_t)r * 128 + k] * W5[k];
  out[r] = acc;
}

// ---------------------------------------------------------------------------
extern "C" void kernel_launch(void* const* d_in, const int* in_sizes, int n_in,
                              void* d_out, int out_size, void* d_ws,
                              size_t ws_size, hipStream_t stream) {
  const float* x[2] = {(const float*)d_in[0], (const float*)d_in[3]};
  const int* ei[2] = {(const int*)d_in[1], (const int*)d_in[4]};
  const int* batch[2] = {(const int*)d_in[2], (const int*)d_in[5]};
  const float* gamma = (const float*)d_in[6];
  const float* beta = (const float*)d_in[7];
  const float* W1 = (const float*)d_in[8];
  const float* b1 = (const float*)d_in[9];
  const float* W2 = (const float*)d_in[10];
  const float* b2 = (const float*)d_in[11];
  const float* Wc[3] = {(const float*)d_in[12], (const float*)d_in[14],
                        (const float*)d_in[16]};
  const float* bc[3] = {(const float*)d_in[13], (const float*)d_in[15],
                        (const float*)d_in[17]};
  const float* W3 = (const float*)d_in[18];
  const float* b3 = (const float*)d_in[19];
  const float* W4 = (const float*)d_in[20];
  const float* b4 = (const float*)d_in[21];
  const float* W5 = (const float*)d_in[22];
  const float* b5 = (const float*)d_in[23];
  float* out = (float*)d_out;

  const int N = in_sizes[0] / 64;  // 50000
  const int E = in_sizes[1] / 2;   // 600000
  const int B = out_size;          // 512

  // ---- workspace layout ----
  float* ws = (float*)d_ws;
  float* bufA = ws;                            // N*256
  float* bufB = bufA + (size_t)N * 256;        // N*128
  float* bufC = bufB + (size_t)N * 128;        // N*128
  float* dinv = bufC + (size_t)N * 128;        // N
  int2* epack = (int2*)(dinv + N);             // E int2 (8B, offset even)
  int* degc = (int*)(epack + E);               // N
  int* rowstart = degc + N;                    // N+1
  int* cursor = rowstart + N + 1;              // N
  int* bsum = cursor + N;                      // 64
  int* bstart = bsum + 64;                     // B+1
  float* bnsum = (float*)(bstart + B + 1);     // 64
  float* bnsq = bnsum + 64;                    // 64
  float* W1f = bnsq + 64;                      // 16384
  float* b1f = W1f + 16384;                    // 256
  float* catb = b1f + 256;                     // B*256
  float* z1 = catb + (size_t)B * 256;          // B*256
  float* z2 = z1 + (size_t)B * 256;            // B*128
  size_t need = (size_t)((char*)(z2 + (size_t)B * 128) - (char*)d_ws);
  if (ws_size < need) return;  // workspace too small -> fail loudly

  const int nb_e = (E + 255) / 256;
  const int nb_n = (N + 255) / 256;
  const int nb_scan = (N + 1023) / 1024;
  const int nb_ga = (N * 32 + 255) / 256;
  const int gby = (N + GBM - 1) / GBM;  // 782

  for (int t = 0; t < 2; ++t) {
    const int* srcp = ei[t];
    const int* dstp = ei[t] + E;

    hipMemsetAsync(bnsum, 0, 128 * sizeof(float), stream);
    hipMemsetAsync(degc, 0, (size_t)N * sizeof(int), stream);

    bn_stats_k<<<256, 256, 0, stream>>>(x[t], bnsum, bnsq, N);
    bn_fold_k<<<1, 256, 0, stream>>>(bnsum, bnsq, gamma, beta, W1, b1, W1f,
                                     b1f, 1.0f / (float)N);

    gemm_f32<<<dim3(2, gby), 256, 0, stream>>>(x[t], W1f, b1f, bufA, N, 256,
                                               64, 1);
    gemm_f32<<<dim3(1, gby), 256, 0, stream>>>(bufA, W2, b2, bufB, N, 128, 256,
                                               1);

    count_deg_k<<<nb_e, 256, 0, stream>>>(dstp, degc, E);
    dinv_k<<<nb_n, 256, 0, stream>>>(degc, dinv, N);

    scan1_k<<<nb_scan, 256, 0, stream>>>(degc, bsum, N);
    scan2_k<<<1, 64, 0, stream>>>(bsum, nb_scan);
    scan3_k<<<nb_scan, 256, 0, stream>>>(degc, bsum, rowstart, cursor, N, E);
    fillnorm_k<<<nb_e, 256, 0, stream>>>(srcp, dstp, dinv, cursor, epack, E);

    bstart_k<<<(B + 256) / 256, 256, 0, stream>>>(batch[t], bstart, N, B);

    float* hin = bufB;
    for (int c = 0; c < 3; ++c) {
      float* hout = (c == 1) ? bufB : bufA;  // ping-pong: B->A->B->A
      gemm_f32<<<dim3(1, gby), 256, 0, stream>>>(hin, Wc[c], nullptr, bufC, N,
                                                 128, 128, 0);
      gather_k<<<nb_ga, 256, 0, stream>>>(rowstart, epack, bufC, dinv, bc[c],
                                          hout, N);
      hin = hout;
    }

    pool_seg_k<<<B, 128, 0, stream>>>(hin, bstart, catb, t * 128);
  }

  gemm_f32<<<dim3(2, (B + GBM - 1) / GBM), 256, 0, stream>>>(catb, W3, b3, z1,
                                                             B, 256, 256, 1);
  gemm_f32<<<dim3(1, (B + GBM - 1) / GBM), 256, 0, stream>>>(z1, W4, b4, z2, B,
                                                             128, 256, 1);
  final_k<<<(B + 255) / 256, 256, 0, stream>>>(z2, W5, b5, out, B);
}

// Round 6
// 817.957 us; speedup vs baseline: 1.5197x; 1.2537x over previous
//
#include <hip/hip_runtime.h>
#include <cstdint>

// ---------------------------------------------------------------------------
// GCN twin-tower forward. Round 6: GEMMs on matrix cores via fp16-split.
//   f32 a = ah + al (both fp16); a*b ~= ah*bh + ah*bl + al*bh  (3 MFMAs,
//   ~2^-22 relative error, far below the 2.6e-5 harness threshold).
//   - weights pre-transposed+split to f16 [N][K] once (wtrans_k)
//   - A split to f16 hi/lo during LDS staging
//   - mfma_f32_16x16x32_f16 with swapped operands: D' = Bt x At ->
//     lane&15 = m, (lane>>4)*4+reg = n -> contiguous float4 C-stores
//   - LDS pitch 40 f16 (80B, 16B aligned): frag b128 reads 2-way (free)
// Everything else (CSR gather, segmented pool) unchanged from round 5.
// ---------------------------------------------------------------------------

typedef _Float16 f16;
typedef f16 f16x8 __attribute__((ext_vector_type(8)));
typedef float f32x4 __attribute__((ext_vector_type(4)));

// ---------------- BN stats: per-feature sum / sumsq over N rows -------------
__global__ __launch_bounds__(256) void bn_stats_k(
    const float* __restrict__ x, float* __restrict__ bnsum,
    float* __restrict__ bnsq, int n) {
  __shared__ float ls[256], lq[256];
  const int tid = threadIdx.x;
  const int f = tid & 63;
  const int rb = tid >> 6;  // 0..3
  float s = 0.f, q = 0.f;
  for (int r = blockIdx.x * 4 + rb; r < n; r += gridDim.x * 4) {
    float v = x[(size_t)r * 64 + f];
    s += v;
    q += v * v;
  }
  ls[tid] = s;
  lq[tid] = q;
  __syncthreads();
  if (tid < 64) {
    s = ls[tid] + ls[tid + 64] + ls[tid + 128] + ls[tid + 192];
    q = lq[tid] + lq[tid + 64] + lq[tid + 128] + lq[tid + 192];
    atomicAdd(&bnsum[tid], s);
    atomicAdd(&bnsq[tid], q);
  }
}

// ------------- Fold BN affine into W1 (64x256) and b1 (256) ----------------
__global__ __launch_bounds__(256) void bn_fold_k(
    const float* __restrict__ bnsum, const float* __restrict__ bnsq,
    const float* __restrict__ gamma, const float* __restrict__ beta,
    const float* __restrict__ W1, const float* __restrict__ b1,
    float* __restrict__ W1f, float* __restrict__ b1f, float inv_n) {
  __shared__ float a[64], bf[64];
  const int tid = threadIdx.x;
  if (tid < 64) {
    float mu = bnsum[tid] * inv_n;
    float var = bnsq[tid] * inv_n - mu * mu;
    float s = gamma[tid] * rsqrtf(var + 1e-5f);
    a[tid] = s;
    bf[tid] = beta[tid] - mu * s;
  }
  __syncthreads();
  float acc = 0.f;
#pragma unroll
  for (int f = 0; f < 64; ++f) {
    float w = W1[f * 256 + tid];
    W1f[f * 256 + tid] = a[f] * w;
    acc += bf[f] * w;
  }
  b1f[tid] = b1[tid] + acc;
}

// -------- transpose + fp16-split weights: W[K][N] f32 -> Wt[N][K] f16 ------
// grid(N/64, K/4), 256 threads
__global__ __launch_bounds__(256) void wtrans_k(const float* __restrict__ W,
                                                f16* __restrict__ Wth,
                                                f16* __restrict__ Wtl, int K,
                                                int N) {
  int n = blockIdx.x * 64 + (threadIdx.x & 63);
  int k = blockIdx.y * 4 + (threadIdx.x >> 6);
  float v = W[(size_t)k * N + n];
  f16 h = (f16)v;
  f16 l = (f16)(v - (float)h);
  Wth[(size_t)n * K + k] = h;
  Wtl[(size_t)n * K + k] = l;
}

// ---------------- MFMA GEMM: C = relu?(A@B + bias) -------------------------
// A [M,K] f32 row-major; B given as Wth/Wtl [N][K] f16 (transposed, split).
// Tile 64(m) x 128(n), BK=32, 256 threads = 4 waves (2m x 2n), K%32==0.
__global__ __launch_bounds__(256) void gemm_mfma(
    const float* __restrict__ A, const f16* __restrict__ Wth,
    const f16* __restrict__ Wtl, const float* __restrict__ bias,
    float* __restrict__ C, int M, int N, int K, int relu) {
  __shared__ f16 Ah[64][40], Al[64][40];    // [m][k], pitch 40 (80B)
  __shared__ f16 Bh[128][40], Bl[128][40];  // [n][k], pitch 40
  const int tid = threadIdx.x;
  const int wave = tid >> 6;
  const int lane = tid & 63;
  const int wm = wave & 1;   // m-half (32 rows)
  const int wn = wave >> 1;  // n-half (64 cols)
  const int l15 = lane & 15;
  const int lk8 = (lane >> 4) * 8;  // frag k offset
  // staging assignment
  const int sam = tid >> 2;        // A row 0..63
  const int sak = (tid & 3) * 8;   // A k offset
  const int sbn = tid >> 1;        // Bt row (n) 0..127
  const int sbk = (tid & 1) * 16;  // Bt k offset
  const int arow = blockIdx.y * 64 + sam;
  const float* aptr = A + (size_t)arow * K + sak;
  const f16* bhp = Wth + (size_t)(blockIdx.x * 128 + sbn) * K + sbk;
  const f16* blp = Wtl + (size_t)(blockIdx.x * 128 + sbn) * K + sbk;

  f32x4 acc[2][4];
#pragma unroll
  for (int mi = 0; mi < 2; ++mi)
#pragma unroll
    for (int ni = 0; ni < 4; ++ni) acc[mi][ni] = (f32x4){0.f, 0.f, 0.f, 0.f};

  // prologue: tile 0 into regs
  float4 pa0, pa1;
  if (arow < M) {
    pa0 = *(const float4*)aptr;
    pa1 = *(const float4*)(aptr + 4);
  } else {
    pa0 = make_float4(0.f, 0.f, 0.f, 0.f);
    pa1 = pa0;
  }
  f16x8 pbh0 = *(const f16x8*)bhp;
  f16x8 pbh1 = *(const f16x8*)(bhp + 8);
  f16x8 pbl0 = *(const f16x8*)blp;
  f16x8 pbl1 = *(const f16x8*)(blp + 8);

  const int nk = K / 32;
  for (int t = 0; t < nk; ++t) {
    if (t) __syncthreads();
    {  // convert + write A tile
      float av[8] = {pa0.x, pa0.y, pa0.z, pa0.w, pa1.x, pa1.y, pa1.z, pa1.w};
      f16x8 vh, vl;
#pragma unroll
      for (int j = 0; j < 8; ++j) {
        f16 h = (f16)av[j];
        vh[j] = h;
        vl[j] = (f16)(av[j] - (float)h);
      }
      *(f16x8*)&Ah[sam][sak] = vh;
      *(f16x8*)&Al[sam][sak] = vl;
    }
    *(f16x8*)&Bh[sbn][sbk] = pbh0;
    *(f16x8*)&Bh[sbn][sbk + 8] = pbh1;
    *(f16x8*)&Bl[sbn][sbk] = pbl0;
    *(f16x8*)&Bl[sbn][sbk + 8] = pbl1;
    __syncthreads();
    if (t + 1 < nk) {  // issue next-tile loads; hide under MFMAs
      const int k0 = (t + 1) * 32;
      if (arow < M) {
        pa0 = *(const float4*)(aptr + k0);
        pa1 = *(const float4*)(aptr + k0 + 4);
      } else {
        pa0 = make_float4(0.f, 0.f, 0.f, 0.f);
        pa1 = pa0;
      }
      pbh0 = *(const f16x8*)(bhp + k0);
      pbh1 = *(const f16x8*)(bhp + k0 + 8);
      pbl0 = *(const f16x8*)(blp + k0);
      pbl1 = *(const f16x8*)(blp + k0 + 8);
    }
    // fragments
    f16x8 ath[2], atl[2];
#pragma unroll
    for (int mi = 0; mi < 2; ++mi) {
      const int r = wm * 32 + mi * 16 + l15;
      ath[mi] = *(const f16x8*)&Ah[r][lk8];
      atl[mi] = *(const f16x8*)&Al[r][lk8];
    }
    f16x8 bth[4], btl[4];
#pragma unroll
    for (int ni = 0; ni < 4; ++ni) {
      const int r = wn * 64 + ni * 16 + l15;
      bth[ni] = *(const f16x8*)&Bh[r][lk8];
      btl[ni] = *(const f16x8*)&Bl[r][lk8];
    }
#pragma unroll
    for (int mi = 0; mi < 2; ++mi)
#pragma unroll
      for (int ni = 0; ni < 4; ++ni) {
        acc[mi][ni] = __builtin_amdgcn_mfma_f32_16x16x32_f16(
            bth[ni], ath[mi], acc[mi][ni], 0, 0, 0);
        acc[mi][ni] = __builtin_amdgcn_mfma_f32_16x16x32_f16(
            bth[ni], atl[mi], acc[mi][ni], 0, 0, 0);
        acc[mi][ni] = __builtin_amdgcn_mfma_f32_16x16x32_f16(
            btl[ni], ath[mi], acc[mi][ni], 0, 0, 0);
      }
  }

  // epilogue: lane holds C[m][nb..nb+3], m = base + (lane&15)
#pragma unroll
  for (int mi = 0; mi < 2; ++mi) {
    const int m = blockIdx.y * 64 + wm * 32 + mi * 16 + l15;
    if (m >= M) continue;
#pragma unroll
    for (int ni = 0; ni < 4; ++ni) {
      const int nb = blockIdx.x * 128 + wn * 64 + ni * 16 + (lane >> 4) * 4;
      float4 bv = make_float4(0.f, 0.f, 0.f, 0.f);
      if (bias) bv = *(const float4*)(bias + nb);
      float4 v;
      v.x = acc[mi][ni][0] + bv.x;
      v.y = acc[mi][ni][1] + bv.y;
      v.z = acc[mi][ni][2] + bv.z;
      v.w = acc[mi][ni][3] + bv.w;
      if (relu) {
        v.x = fmaxf(v.x, 0.f);
        v.y = fmaxf(v.y, 0.f);
        v.z = fmaxf(v.z, 0.f);
        v.w = fmaxf(v.w, 0.f);
      }
      *(float4*)(C + (size_t)m * N + nb) = v;
    }
  }
}

// ---------------- degree count (incoming edges per node) -------------------
__global__ __launch_bounds__(256) void count_deg_k(const int* __restrict__ dst,
                                                   int* __restrict__ cnt,
                                                   int e) {
  int i = blockIdx.x * 256 + threadIdx.x;
  if (i < e) atomicAdd(&cnt[dst[i]], 1);
}

__global__ __launch_bounds__(256) void dinv_k(const int* __restrict__ cnt,
                                              float* __restrict__ dinv, int n) {
  int i = blockIdx.x * 256 + threadIdx.x;
  if (i < n) dinv[i] = rsqrtf((float)(cnt[i] + 1));  // +1 self loop
}

// ---------------- CSR build: exclusive scan of deg over N ------------------
__global__ __launch_bounds__(256) void scan1_k(const int* __restrict__ deg,
                                               int* __restrict__ bsum, int n) {
  __shared__ int ls[256];
  const int base = blockIdx.x * 1024;
  int s = 0;
  for (int j = threadIdx.x; j < 1024; j += 256) {
    int i = base + j;
    s += (i < n) ? deg[i] : 0;
  }
  ls[threadIdx.x] = s;
  __syncthreads();
  for (int off = 128; off > 0; off >>= 1) {
    if (threadIdx.x < off) ls[threadIdx.x] += ls[threadIdx.x + off];
    __syncthreads();
  }
  if (threadIdx.x == 0) bsum[blockIdx.x] = ls[0];
}

__global__ void scan2_k(int* __restrict__ bsum, int nb) {
  if (threadIdx.x == 0 && blockIdx.x == 0) {
    int acc = 0;
    for (int i = 0; i < nb; ++i) {
      int v = bsum[i];
      bsum[i] = acc;
      acc += v;
    }
  }
}

__global__ __launch_bounds__(256) void scan3_k(
    const int* __restrict__ deg, const int* __restrict__ bsum,
    int* __restrict__ rowstart, int* __restrict__ cursor, int n, int e) {
  __shared__ int ts[256];
  const int tid = threadIdx.x;
  const int i0 = blockIdx.x * 1024 + tid * 4;
  int v[4];
  int s = 0;
#pragma unroll
  for (int j = 0; j < 4; ++j) {
    int i = i0 + j;
    v[j] = (i < n) ? deg[i] : 0;
    s += v[j];
  }
  ts[tid] = s;
  __syncthreads();
  for (int off = 1; off < 256; off <<= 1) {
    int t = (tid >= off) ? ts[tid - off] : 0;
    __syncthreads();
    ts[tid] += t;
    __syncthreads();
  }
  int run = bsum[blockIdx.x] + ts[tid] - s;  // exclusive prefix
#pragma unroll
  for (int j = 0; j < 4; ++j) {
    int i = i0 + j;
    if (i < n) {
      rowstart[i] = run;
      cursor[i] = run;
    }
    run += v[j];
  }
  if (blockIdx.x == 0 && tid == 0) rowstart[n] = e;
}

// fill: dst-sorted packed (src, norm) edges; norm computed inline
__global__ __launch_bounds__(256) void fillnorm_k(
    const int* __restrict__ src, const int* __restrict__ dst,
    const float* __restrict__ dinv, int* __restrict__ cursor,
    int2* __restrict__ epack, int e) {
  int i = blockIdx.x * 256 + threadIdx.x;
  if (i >= e) return;
  int s = src[i], d = dst[i];
  int pos = atomicAdd(&cursor[d], 1);
  epack[pos] = make_int2(s, __float_as_int(dinv[s] * dinv[d]));
}

// ---------------- gather: out[v] = relu(self + sum_in + bias) --------------
// 32 threads per node, float4 per thread (128 feat).
__global__ __launch_bounds__(256) void gather_k(
    const int* __restrict__ rowstart, const int2* __restrict__ epack,
    const float* __restrict__ xw, const float* __restrict__ dinv,
    const float* __restrict__ bias, float* __restrict__ out, int n) {
  int gid = blockIdx.x * 256 + threadIdx.x;
  int v = gid >> 5;
  if (v >= n) return;
  int q = gid & 31;
  const float4* xw4 = (const float4*)xw;
  float d = dinv[v];
  float sl = d * d;
  float4 acc = xw4[(size_t)v * 32 + q];
  acc.x *= sl; acc.y *= sl; acc.z *= sl; acc.w *= sl;
  int s0 = rowstart[v], s1 = rowstart[v + 1];
  for (int e = s0; e < s1; ++e) {
    int2 ed = epack[e];
    float w = __int_as_float(ed.y);
    float4 t = xw4[(size_t)ed.x * 32 + q];
    acc.x += t.x * w;
    acc.y += t.y * w;
    acc.z += t.z * w;
    acc.w += t.w * w;
  }
  float4 bb = ((const float4*)bias)[q];
  acc.x = fmaxf(acc.x + bb.x, 0.f);
  acc.y = fmaxf(acc.y + bb.y, 0.f);
  acc.z = fmaxf(acc.z + bb.z, 0.f);
  acc.w = fmaxf(acc.w + bb.w, 0.f);
  ((float4*)out)[(size_t)v * 32 + q] = acc;
}

// ---------------- pool: segmented mean over sorted batch -------------------
__global__ __launch_bounds__(256) void bstart_k(const int* __restrict__ batch,
                                                int* __restrict__ bstart,
                                                int n, int nb) {
  int b = blockIdx.x * 256 + threadIdx.x;
  if (b > nb) return;
  int lo = 0, hi = n;
  while (lo < hi) {
    int mid = (lo + hi) >> 1;
    if (batch[mid] < b) lo = mid + 1; else hi = mid;
  }
  bstart[b] = lo;
}

// one block (128 threads) per graph; h rows are contiguous per graph
__global__ __launch_bounds__(128) void pool_seg_k(
    const float* __restrict__ h, const int* __restrict__ bstart,
    float* __restrict__ cat, int toff) {
  int b = blockIdx.x;
  int s = bstart[b], e = bstart[b + 1];
  int f = threadIdx.x;
  float acc = 0.f;
  for (int v = s; v < e; ++v) acc += h[(size_t)v * 128 + f];
  float c = fmaxf((float)(e - s), 1.f);
  cat[(size_t)b * 256 + toff + f] = acc / c;
}

// ---------------- final: out[r] = z2[r,:]@W5 + b5 --------------------------
__global__ __launch_bounds__(256) void final_k(const float* __restrict__ z2,
                                               const float* __restrict__ W5,
                                               const float* __restrict__ b5,
                                               float* __restrict__ out,
                                               int rows) {
  int r = blockIdx.x * 256 + threadIdx.x;
  if (r >= rows) return;
  float acc = b5[0];
#pragma unroll
  for (int k = 0; k < 128; ++k) acc += z2[(size_t)r * 128 + k] * W5[k];
  out[r] = acc;
}

// ---------------------------------------------------------------------------
extern "C" void kernel_launch(void* const* d_in, const int* in_sizes, int n_in,
                              void* d_out, int out_size, void* d_ws,
                              size_t ws_size, hipStream_t stream) {
  const float* x[2] = {(const float*)d_in[0], (const float*)d_in[3]};
  const int* ei[2] = {(const int*)d_in[1], (const int*)d_in[4]};
  const int* batch[2] = {(const int*)d_in[2], (const int*)d_in[5]};
  const float* gamma = (const float*)d_in[6];
  const float* beta = (const float*)d_in[7];
  const float* W1 = (const float*)d_in[8];
  const float* b1 = (const float*)d_in[9];
  const float* W2 = (const float*)d_in[10];
  const float* b2 = (const float*)d_in[11];
  const float* Wc[3] = {(const float*)d_in[12], (const float*)d_in[14],
                        (const float*)d_in[16]};
  const float* bc[3] = {(const float*)d_in[13], (const float*)d_in[15],
                        (const float*)d_in[17]};
  const float* W3 = (const float*)d_in[18];
  const float* b3 = (const float*)d_in[19];
  const float* W4 = (const float*)d_in[20];
  const float* b4 = (const float*)d_in[21];
  const float* W5 = (const float*)d_in[22];
  const float* b5 = (const float*)d_in[23];
  float* out = (float*)d_out;

  const int N = in_sizes[0] / 64;  // 50000
  const int E = in_sizes[1] / 2;   // 600000
  const int B = out_size;          // 512

  // ---- workspace layout ----
  float* ws = (float*)d_ws;
  float* bufA = ws;                            // N*256
  float* bufB = bufA + (size_t)N * 256;        // N*128
  float* bufC = bufB + (size_t)N * 128;        // N*128
  float* dinv = bufC + (size_t)N * 128;        // N
  int2* epack = (int2*)(dinv + N);             // E int2
  int* degc = (int*)(epack + E);               // N
  int* rowstart = degc + N;                    // N+1
  int* cursor = rowstart + N + 1;              // N
  int* bsum = cursor + N;                      // 64
  int* bstart = bsum + 64;                     // B+1
  float* bnsum = (float*)(bstart + B + 1);     // 64
  float* bnsq = bnsum + 64;                    // 64
  float* W1f = bnsq + 64;                      // 16384
  float* b1f = W1f + 16384;                    // 256
  float* catb = b1f + 256;                     // B*256
  float* z1 = catb + (size_t)B * 256;          // B*256
  float* z2 = z1 + (size_t)B * 256;            // B*128
  // f16 transposed/split weights (64B-aligned)
  f16* wtp = (f16*)(((uintptr_t)(z2 + (size_t)B * 128) + 63) &
                    ~(uintptr_t)63);
  f16* w1t_h = wtp; wtp += 16384;   // [256][64]
  f16* w1t_l = wtp; wtp += 16384;
  f16* w2t_h = wtp; wtp += 32768;   // [128][256]
  f16* w2t_l = wtp; wtp += 32768;
  f16* wct_h[3]; f16* wct_l[3];
  for (int c = 0; c < 3; ++c) {
    wct_h[c] = wtp; wtp += 16384;   // [128][128]
    wct_l[c] = wtp; wtp += 16384;
  }
  f16* w3t_h = wtp; wtp += 65536;   // [256][256]
  f16* w3t_l = wtp; wtp += 65536;
  f16* w4t_h = wtp; wtp += 32768;   // [128][256]
  f16* w4t_l = wtp; wtp += 32768;
  size_t need = (size_t)((char*)wtp - (char*)d_ws);
  if (ws_size < need) return;  // workspace too small -> fail loudly

  const int nb_e = (E + 255) / 256;
  const int nb_n = (N + 255) / 256;
  const int nb_scan = (N + 1023) / 1024;
  const int nb_ga = (N * 32 + 255) / 256;
  const int gby = (N + 63) / 64;  // 782

  // shared weights: transpose+split once
  wtrans_k<<<dim3(2, 64), 256, 0, stream>>>(W2, w2t_h, w2t_l, 256, 128);
  for (int c = 0; c < 3; ++c)
    wtrans_k<<<dim3(2, 32), 256, 0, stream>>>(Wc[c], wct_h[c], wct_l[c], 128,
                                              128);
  wtrans_k<<<dim3(4, 64), 256, 0, stream>>>(W3, w3t_h, w3t_l, 256, 256);
  wtrans_k<<<dim3(2, 64), 256, 0, stream>>>(W4, w4t_h, w4t_l, 256, 128);

  for (int t = 0; t < 2; ++t) {
    const int* srcp = ei[t];
    const int* dstp = ei[t] + E;

    hipMemsetAsync(bnsum, 0, 128 * sizeof(float), stream);
    hipMemsetAsync(degc, 0, (size_t)N * sizeof(int), stream);

    bn_stats_k<<<256, 256, 0, stream>>>(x[t], bnsum, bnsq, N);
    bn_fold_k<<<1, 256, 0, stream>>>(bnsum, bnsq, gamma, beta, W1, b1, W1f,
                                     b1f, 1.0f / (float)N);
    wtrans_k<<<dim3(4, 16), 256, 0, stream>>>(W1f, w1t_h, w1t_l, 64, 256);

    gemm_mfma<<<dim3(2, gby), 256, 0, stream>>>(x[t], w1t_h, w1t_l, b1f, bufA,
                                                N, 256, 64, 1);
    gemm_mfma<<<dim3(1, gby), 256, 0, stream>>>(bufA, w2t_h, w2t_l, b2, bufB,
                                                N, 128, 256, 1);

    count_deg_k<<<nb_e, 256, 0, stream>>>(dstp, degc, E);
    dinv_k<<<nb_n, 256, 0, stream>>>(degc, dinv, N);

    scan1_k<<<nb_scan, 256, 0, stream>>>(degc, bsum, N);
    scan2_k<<<1, 64, 0, stream>>>(bsum, nb_scan);
    scan3_k<<<nb_scan, 256, 0, stream>>>(degc, bsum, rowstart, cursor, N, E);
    fillnorm_k<<<nb_e, 256, 0, stream>>>(srcp, dstp, dinv, cursor, epack, E);

    bstart_k<<<(B + 256) / 256, 256, 0, stream>>>(batch[t], bstart, N, B);

    float* hin = bufB;
    for (int c = 0; c < 3; ++c) {
      float* hout = (c == 1) ? bufB : bufA;  // ping-pong: B->A->B->A
      gemm_mfma<<<dim3(1, gby), 256, 0, stream>>>(hin, wct_h[c], wct_l[c],
                                                  nullptr, bufC, N, 128, 128,
                                                  0);
      gather_k<<<nb_ga, 256, 0, stream>>>(rowstart, epack, bufC, dinv, bc[c],
                                          hout, N);
      hin = hout;
    }

    pool_seg_k<<<B, 128, 0, stream>>>(hin, bstart, catb, t * 128);
  }

  gemm_mfma<<<dim3(2, (B + 63) / 64), 256, 0, stream>>>(catb, w3t_h, w3t_l,
                                                        b3, z1, B, 256, 256,
                                                        1);
  gemm_mfma<<<dim3(1, (B + 63) / 64), 256, 0, stream>>>(z1, w4t_h, w4t_l, b4,
                                                        z2, B, 128, 256, 1);
  final_k<<<(B + 255) / 256, 256, 0, stream>>>(z2, W5, b5, out, B);
}

// Round 7
// 708.526 us; speedup vs baseline: 1.7544x; 1.1544x over previous
//
#include <hip/hip_runtime.h>
#include <cstdint>

// ---------------------------------------------------------------------------
// GCN twin-tower forward. Round 7: f16 gather path.
//   Conv GEMMs write xw directly as f16 [N][128] (256B rows) -> gather
//   traffic halves (the 144MB/dispatch FETCH was the #1 cost). Gather
//   converts f16->f32 and accumulates in f32; self-loop uses the same f16
//   row. GEMM internals stay 3-MFMA fp16-split (2^-22 products).
// ---------------------------------------------------------------------------

typedef _Float16 f16;
typedef f16 f16x8 __attribute__((ext_vector_type(8)));
typedef f16 f16x4 __attribute__((ext_vector_type(4)));
typedef float f32x4 __attribute__((ext_vector_type(4)));

// ---------------- BN stats: per-feature sum / sumsq over N rows -------------
__global__ __launch_bounds__(256) void bn_stats_k(
    const float* __restrict__ x, float* __restrict__ bnsum,
    float* __restrict__ bnsq, int n) {
  __shared__ float ls[256], lq[256];
  const int tid = threadIdx.x;
  const int f = tid & 63;
  const int rb = tid >> 6;  // 0..3
  float s = 0.f, q = 0.f;
  for (int r = blockIdx.x * 4 + rb; r < n; r += gridDim.x * 4) {
    float v = x[(size_t)r * 64 + f];
    s += v;
    q += v * v;
  }
  ls[tid] = s;
  lq[tid] = q;
  __syncthreads();
  if (tid < 64) {
    s = ls[tid] + ls[tid + 64] + ls[tid + 128] + ls[tid + 192];
    q = lq[tid] + lq[tid + 64] + lq[tid + 128] + lq[tid + 192];
    atomicAdd(&bnsum[tid], s);
    atomicAdd(&bnsq[tid], q);
  }
}

// ------------- Fold BN affine into W1 (64x256) and b1 (256) ----------------
__global__ __launch_bounds__(256) void bn_fold_k(
    const float* __restrict__ bnsum, const float* __restrict__ bnsq,
    const float* __restrict__ gamma, const float* __restrict__ beta,
    const float* __restrict__ W1, const float* __restrict__ b1,
    float* __restrict__ W1f, float* __restrict__ b1f, float inv_n) {
  __shared__ float a[64], bf[64];
  const int tid = threadIdx.x;
  if (tid < 64) {
    float mu = bnsum[tid] * inv_n;
    float var = bnsq[tid] * inv_n - mu * mu;
    float s = gamma[tid] * rsqrtf(var + 1e-5f);
    a[tid] = s;
    bf[tid] = beta[tid] - mu * s;
  }
  __syncthreads();
  float acc = 0.f;
#pragma unroll
  for (int f = 0; f < 64; ++f) {
    float w = W1[f * 256 + tid];
    W1f[f * 256 + tid] = a[f] * w;
    acc += bf[f] * w;
  }
  b1f[tid] = b1[tid] + acc;
}

// -------- transpose + fp16-split weights: W[K][N] f32 -> Wt[N][K] f16 ------
// grid(N/64, K/4), 256 threads
__global__ __launch_bounds__(256) void wtrans_k(const float* __restrict__ W,
                                                f16* __restrict__ Wth,
                                                f16* __restrict__ Wtl, int K,
                                                int N) {
  int n = blockIdx.x * 64 + (threadIdx.x & 63);
  int k = blockIdx.y * 4 + (threadIdx.x >> 6);
  float v = W[(size_t)k * N + n];
  f16 h = (f16)v;
  f16 l = (f16)(v - (float)h);
  Wth[(size_t)n * K + k] = h;
  Wtl[(size_t)n * K + k] = l;
}

// ---------------- MFMA GEMM core (shared by f32/f16 output) ----------------
// A [M,K] f32 row-major; B as Wth/Wtl [N][K] f16 (transposed, split).
// Tile 64(m) x 128(n), BK=32, 256 threads = 4 waves (2m x 2n), K%32==0.
// OUT16: write f16 [M][N] rows, no bias/relu. else: f32 + bias + optional relu.
template <int OUT16>
__device__ __forceinline__ void gemm_mfma_core(
    const float* __restrict__ A, const f16* __restrict__ Wth,
    const f16* __restrict__ Wtl, const float* __restrict__ bias,
    float* __restrict__ C, f16* __restrict__ C16, int M, int N, int K,
    int relu) {
  __shared__ f16 Ah[64][40], Al[64][40];    // [m][k], pitch 40 (80B)
  __shared__ f16 Bh[128][40], Bl[128][40];  // [n][k], pitch 40
  const int tid = threadIdx.x;
  const int wave = tid >> 6;
  const int lane = tid & 63;
  const int wm = wave & 1;   // m-half (32 rows)
  const int wn = wave >> 1;  // n-half (64 cols)
  const int l15 = lane & 15;
  const int lk8 = (lane >> 4) * 8;  // frag k offset
  const int sam = tid >> 2;         // A row 0..63
  const int sak = (tid & 3) * 8;    // A k offset
  const int sbn = tid >> 1;         // Bt row (n) 0..127
  const int sbk = (tid & 1) * 16;   // Bt k offset
  const int arow = blockIdx.y * 64 + sam;
  const float* aptr = A + (size_t)arow * K + sak;
  const f16* bhp = Wth + (size_t)(blockIdx.x * 128 + sbn) * K + sbk;
  const f16* blp = Wtl + (size_t)(blockIdx.x * 128 + sbn) * K + sbk;

  f32x4 acc[2][4];
#pragma unroll
  for (int mi = 0; mi < 2; ++mi)
#pragma unroll
    for (int ni = 0; ni < 4; ++ni) acc[mi][ni] = (f32x4){0.f, 0.f, 0.f, 0.f};

  float4 pa0, pa1;
  if (arow < M) {
    pa0 = *(const float4*)aptr;
    pa1 = *(const float4*)(aptr + 4);
  } else {
    pa0 = make_float4(0.f, 0.f, 0.f, 0.f);
    pa1 = pa0;
  }
  f16x8 pbh0 = *(const f16x8*)bhp;
  f16x8 pbh1 = *(const f16x8*)(bhp + 8);
  f16x8 pbl0 = *(const f16x8*)blp;
  f16x8 pbl1 = *(const f16x8*)(blp + 8);

  const int nk = K / 32;
  for (int t = 0; t < nk; ++t) {
    if (t) __syncthreads();
    {
      float av[8] = {pa0.x, pa0.y, pa0.z, pa0.w, pa1.x, pa1.y, pa1.z, pa1.w};
      f16x8 vh, vl;
#pragma unroll
      for (int j = 0; j < 8; ++j) {
        f16 h = (f16)av[j];
        vh[j] = h;
        vl[j] = (f16)(av[j] - (float)h);
      }
      *(f16x8*)&Ah[sam][sak] = vh;
      *(f16x8*)&Al[sam][sak] = vl;
    }
    *(f16x8*)&Bh[sbn][sbk] = pbh0;
    *(f16x8*)&Bh[sbn][sbk + 8] = pbh1;
    *(f16x8*)&Bl[sbn][sbk] = pbl0;
    *(f16x8*)&Bl[sbn][sbk + 8] = pbl1;
    __syncthreads();
    if (t + 1 < nk) {  // issue next-tile loads; hide under MFMAs
      const int k0 = (t + 1) * 32;
      if (arow < M) {
        pa0 = *(const float4*)(aptr + k0);
        pa1 = *(const float4*)(aptr + k0 + 4);
      } else {
        pa0 = make_float4(0.f, 0.f, 0.f, 0.f);
        pa1 = pa0;
      }
      pbh0 = *(const f16x8*)(bhp + k0);
      pbh1 = *(const f16x8*)(bhp + k0 + 8);
      pbl0 = *(const f16x8*)(blp + k0);
      pbl1 = *(const f16x8*)(blp + k0 + 8);
    }
    f16x8 ath[2], atl[2];
#pragma unroll
    for (int mi = 0; mi < 2; ++mi) {
      const int r = wm * 32 + mi * 16 + l15;
      ath[mi] = *(const f16x8*)&Ah[r][lk8];
      atl[mi] = *(const f16x8*)&Al[r][lk8];
    }
    f16x8 bth[4], btl[4];
#pragma unroll
    for (int ni = 0; ni < 4; ++ni) {
      const int r = wn * 64 + ni * 16 + l15;
      bth[ni] = *(const f16x8*)&Bh[r][lk8];
      btl[ni] = *(const f16x8*)&Bl[r][lk8];
    }
#pragma unroll
    for (int mi = 0; mi < 2; ++mi)
#pragma unroll
      for (int ni = 0; ni < 4; ++ni) {
        acc[mi][ni] = __builtin_amdgcn_mfma_f32_16x16x32_f16(
            bth[ni], ath[mi], acc[mi][ni], 0, 0, 0);
        acc[mi][ni] = __builtin_amdgcn_mfma_f32_16x16x32_f16(
            bth[ni], atl[mi], acc[mi][ni], 0, 0, 0);
        acc[mi][ni] = __builtin_amdgcn_mfma_f32_16x16x32_f16(
            btl[ni], ath[mi], acc[mi][ni], 0, 0, 0);
      }
  }

  // epilogue: lane holds C[m][nb..nb+3], m = base + (lane&15)
#pragma unroll
  for (int mi = 0; mi < 2; ++mi) {
    const int m = blockIdx.y * 64 + wm * 32 + mi * 16 + l15;
    if (m >= M) continue;
#pragma unroll
    for (int ni = 0; ni < 4; ++ni) {
      const int nb = blockIdx.x * 128 + wn * 64 + ni * 16 + (lane >> 4) * 4;
      if (OUT16) {
        f16x4 h;
        h[0] = (f16)acc[mi][ni][0];
        h[1] = (f16)acc[mi][ni][1];
        h[2] = (f16)acc[mi][ni][2];
        h[3] = (f16)acc[mi][ni][3];
        *(f16x4*)(C16 + (size_t)m * N + nb) = h;
      } else {
        float4 bv = make_float4(0.f, 0.f, 0.f, 0.f);
        if (bias) bv = *(const float4*)(bias + nb);
        float4 v;
        v.x = acc[mi][ni][0] + bv.x;
        v.y = acc[mi][ni][1] + bv.y;
        v.z = acc[mi][ni][2] + bv.z;
        v.w = acc[mi][ni][3] + bv.w;
        if (relu) {
          v.x = fmaxf(v.x, 0.f);
          v.y = fmaxf(v.y, 0.f);
          v.z = fmaxf(v.z, 0.f);
          v.w = fmaxf(v.w, 0.f);
        }
        *(float4*)(C + (size_t)m * N + nb) = v;
      }
    }
  }
}

__global__ __launch_bounds__(256) void gemm_mfma(
    const float* __restrict__ A, const f16* __restrict__ Wth,
    const f16* __restrict__ Wtl, const float* __restrict__ bias,
    float* __restrict__ C, int M, int N, int K, int relu) {
  gemm_mfma_core<0>(A, Wth, Wtl, bias, C, nullptr, M, N, K, relu);
}

__global__ __launch_bounds__(256) void gemm_mfma_f16o(
    const float* __restrict__ A, const f16* __restrict__ Wth,
    const f16* __restrict__ Wtl, f16* __restrict__ C16, int M, int N, int K) {
  gemm_mfma_core<1>(A, Wth, Wtl, nullptr, nullptr, C16, M, N, K, 0);
}

// ---------------- degree count (incoming edges per node) -------------------
__global__ __launch_bounds__(256) void count_deg_k(const int* __restrict__ dst,
                                                   int* __restrict__ cnt,
                                                   int e) {
  int i = blockIdx.x * 256 + threadIdx.x;
  if (i < e) atomicAdd(&cnt[dst[i]], 1);
}

__global__ __launch_bounds__(256) void dinv_k(const int* __restrict__ cnt,
                                              float* __restrict__ dinv, int n) {
  int i = blockIdx.x * 256 + threadIdx.x;
  if (i < n) dinv[i] = rsqrtf((float)(cnt[i] + 1));  // +1 self loop
}

// ---------------- CSR build: exclusive scan of deg over N ------------------
__global__ __launch_bounds__(256) void scan1_k(const int* __restrict__ deg,
                                               int* __restrict__ bsum, int n) {
  __shared__ int ls[256];
  const int base = blockIdx.x * 1024;
  int s = 0;
  for (int j = threadIdx.x; j < 1024; j += 256) {
    int i = base + j;
    s += (i < n) ? deg[i] : 0;
  }
  ls[threadIdx.x] = s;
  __syncthreads();
  for (int off = 128; off > 0; off >>= 1) {
    if (threadIdx.x < off) ls[threadIdx.x] += ls[threadIdx.x + off];
    __syncthreads();
  }
  if (threadIdx.x == 0) bsum[blockIdx.x] = ls[0];
}

__global__ void scan2_k(int* __restrict__ bsum, int nb) {
  if (threadIdx.x == 0 && blockIdx.x == 0) {
    int acc = 0;
    for (int i = 0; i < nb; ++i) {
      int v = bsum[i];
      bsum[i] = acc;
      acc += v;
    }
  }
}

__global__ __launch_bounds__(256) void scan3_k(
    const int* __restrict__ deg, const int* __restrict__ bsum,
    int* __restrict__ rowstart, int* __restrict__ cursor, int n, int e) {
  __shared__ int ts[256];
  const int tid = threadIdx.x;
  const int i0 = blockIdx.x * 1024 + tid * 4;
  int v[4];
  int s = 0;
#pragma unroll
  for (int j = 0; j < 4; ++j) {
    int i = i0 + j;
    v[j] = (i < n) ? deg[i] : 0;
    s += v[j];
  }
  ts[tid] = s;
  __syncthreads();
  for (int off = 1; off < 256; off <<= 1) {
    int t = (tid >= off) ? ts[tid - off] : 0;
    __syncthreads();
    ts[tid] += t;
    __syncthreads();
  }
  int run = bsum[blockIdx.x] + ts[tid] - s;  // exclusive prefix
#pragma unroll
  for (int j = 0; j < 4; ++j) {
    int i = i0 + j;
    if (i < n) {
      rowstart[i] = run;
      cursor[i] = run;
    }
    run += v[j];
  }
  if (blockIdx.x == 0 && tid == 0) rowstart[n] = e;
}

// fill: dst-sorted packed (src, norm) edges; norm computed inline
__global__ __launch_bounds__(256) void fillnorm_k(
    const int* __restrict__ src, const int* __restrict__ dst,
    const float* __restrict__ dinv, int* __restrict__ cursor,
    int2* __restrict__ epack, int e) {
  int i = blockIdx.x * 256 + threadIdx.x;
  if (i >= e) return;
  int s = src[i], d = dst[i];
  int pos = atomicAdd(&cursor[d], 1);
  epack[pos] = make_int2(s, __float_as_int(dinv[s] * dinv[d]));
}

// ---------------- gather (f16 rows): out = relu(self + sum_in + bias) ------
// 16 threads per node, f16x8 (16B) per thread (128 feat).
__global__ __launch_bounds__(256) void gather16_k(
    const int* __restrict__ rowstart, const int2* __restrict__ epack,
    const f16* __restrict__ xw16, const float* __restrict__ dinv,
    const float* __restrict__ bias, float* __restrict__ out, int n) {
  int gid = blockIdx.x * 256 + threadIdx.x;
  int v = gid >> 4;
  if (v >= n) return;
  int q = gid & 15;
  const f16x8* x8 = (const f16x8*)xw16;  // 16 vectors per row
  float d = dinv[v];
  float sl = d * d;
  f16x8 sv = x8[(size_t)v * 16 + q];
  float acc[8];
#pragma unroll
  for (int j = 0; j < 8; ++j) acc[j] = (float)sv[j] * sl;
  int s0 = rowstart[v], s1 = rowstart[v + 1];
  for (int e = s0; e < s1; ++e) {
    int2 ed = epack[e];
    float w = __int_as_float(ed.y);
    f16x8 t = x8[(size_t)ed.x * 16 + q];
#pragma unroll
    for (int j = 0; j < 8; ++j) acc[j] += (float)t[j] * w;
  }
  float4 b0 = *(const float4*)(bias + q * 8);
  float4 b1 = *(const float4*)(bias + q * 8 + 4);
  float4 o0, o1;
  o0.x = fmaxf(acc[0] + b0.x, 0.f);
  o0.y = fmaxf(acc[1] + b0.y, 0.f);
  o0.z = fmaxf(acc[2] + b0.z, 0.f);
  o0.w = fmaxf(acc[3] + b0.w, 0.f);
  o1.x = fmaxf(acc[4] + b1.x, 0.f);
  o1.y = fmaxf(acc[5] + b1.y, 0.f);
  o1.z = fmaxf(acc[6] + b1.z, 0.f);
  o1.w = fmaxf(acc[7] + b1.w, 0.f);
  *(float4*)(out + (size_t)v * 128 + q * 8) = o0;
  *(float4*)(out + (size_t)v * 128 + q * 8 + 4) = o1;
}

// ---------------- pool: segmented mean over sorted batch -------------------
__global__ __launch_bounds__(256) void bstart_k(const int* __restrict__ batch,
                                                int* __restrict__ bstart,
                                                int n, int nb) {
  int b = blockIdx.x * 256 + threadIdx.x;
  if (b > nb) return;
  int lo = 0, hi = n;
  while (lo < hi) {
    int mid = (lo + hi) >> 1;
    if (batch[mid] < b) lo = mid + 1; else hi = mid;
  }
  bstart[b] = lo;
}

// one block (128 threads) per graph; h rows are contiguous per graph
__global__ __launch_bounds__(128) void pool_seg_k(
    const float* __restrict__ h, const int* __restrict__ bstart,
    float* __restrict__ cat, int toff) {
  int b = blockIdx.x;
  int s = bstart[b], e = bstart[b + 1];
  int f = threadIdx.x;
  float acc = 0.f;
  for (int v = s; v < e; ++v) acc += h[(size_t)v * 128 + f];
  float c = fmaxf((float)(e - s), 1.f);
  cat[(size_t)b * 256 + toff + f] = acc / c;
}

// ---------------- final: out[r] = z2[r,:]@W5 + b5 --------------------------
__global__ __launch_bounds__(256) void final_k(const float* __restrict__ z2,
                                               const float* __restrict__ W5,
                                               const float* __restrict__ b5,
                                               float* __restrict__ out,
                                               int rows) {
  int r = blockIdx.x * 256 + threadIdx.x;
  if (r >= rows) return;
  float acc = b5[0];
#pragma unroll
  for (int k = 0; k < 128; ++k) acc += z2[(size_t)r * 128 + k] * W5[k];
  out[r] = acc;
}

// ---------------------------------------------------------------------------
extern "C" void kernel_launch(void* const* d_in, const int* in_sizes, int n_in,
                              void* d_out, int out_size, void* d_ws,
                              size_t ws_size, hipStream_t stream) {
  const float* x[2] = {(const float*)d_in[0], (const float*)d_in[3]};
  const int* ei[2] = {(const int*)d_in[1], (const int*)d_in[4]};
  const int* batch[2] = {(const int*)d_in[2], (const int*)d_in[5]};
  const float* gamma = (const float*)d_in[6];
  const float* beta = (const float*)d_in[7];
  const float* W1 = (const float*)d_in[8];
  const float* b1 = (const float*)d_in[9];
  const float* W2 = (const float*)d_in[10];
  const float* b2 = (const float*)d_in[11];
  const float* Wc[3] = {(const float*)d_in[12], (const float*)d_in[14],
                        (const float*)d_in[16]};
  const float* bc[3] = {(const float*)d_in[13], (const float*)d_in[15],
                        (const float*)d_in[17]};
  const float* W3 = (const float*)d_in[18];
  const float* b3 = (const float*)d_in[19];
  const float* W4 = (const float*)d_in[20];
  const float* b4 = (const float*)d_in[21];
  const float* W5 = (const float*)d_in[22];
  const float* b5 = (const float*)d_in[23];
  float* out = (float*)d_out;

  const int N = in_sizes[0] / 64;  // 50000
  const int E = in_sizes[1] / 2;   // 600000
  const int B = out_size;          // 512

  // ---- workspace layout ----
  float* ws = (float*)d_ws;
  float* bufA = ws;                            // N*256
  float* bufB = bufA + (size_t)N * 256;        // N*128
  float* bufC = bufB + (size_t)N * 128;        // N*128 (reused: xw16 f16)
  f16* xw16 = (f16*)bufC;                      // N*128 f16 (fits in bufC)
  float* dinv = bufC + (size_t)N * 128;        // N
  int2* epack = (int2*)(dinv + N);             // E int2
  int* degc = (int*)(epack + E);               // N
  int* rowstart = degc + N;                    // N+1
  int* cursor = rowstart + N + 1;              // N
  int* bsum = cursor + N;                      // 64
  int* bstart = bsum + 64;                     // B+1
  float* bnsum = (float*)(bstart + B + 1);     // 64
  float* bnsq = bnsum + 64;                    // 64
  float* W1f = bnsq + 64;                      // 16384
  float* b1f = W1f + 16384;                    // 256
  float* catb = b1f + 256;                     // B*256
  float* z1 = catb + (size_t)B * 256;          // B*256
  float* z2 = z1 + (size_t)B * 256;            // B*128
  // f16 transposed/split weights (64B-aligned)
  f16* wtp = (f16*)(((uintptr_t)(z2 + (size_t)B * 128) + 63) &
                    ~(uintptr_t)63);
  f16* w1t_h = wtp; wtp += 16384;   // [256][64]
  f16* w1t_l = wtp; wtp += 16384;
  f16* w2t_h = wtp; wtp += 32768;   // [128][256]
  f16* w2t_l = wtp; wtp += 32768;
  f16* wct_h[3]; f16* wct_l[3];
  for (int c = 0; c < 3; ++c) {
    wct_h[c] = wtp; wtp += 16384;   // [128][128]
    wct_l[c] = wtp; wtp += 16384;
  }
  f16* w3t_h = wtp; wtp += 65536;   // [256][256]
  f16* w3t_l = wtp; wtp += 65536;
  f16* w4t_h = wtp; wtp += 32768;   // [128][256]
  f16* w4t_l = wtp; wtp += 32768;
  size_t need = (size_t)((char*)wtp - (char*)d_ws);
  if (ws_size < need) return;  // workspace too small -> fail loudly

  const int nb_e = (E + 255) / 256;
  const int nb_n = (N + 255) / 256;
  const int nb_scan = (N + 1023) / 1024;
  const int nb_g16 = (N * 16 + 255) / 256;
  const int gby = (N + 63) / 64;  // 782

  // shared weights: transpose+split once
  wtrans_k<<<dim3(2, 64), 256, 0, stream>>>(W2, w2t_h, w2t_l, 256, 128);
  for (int c = 0; c < 3; ++c)
    wtrans_k<<<dim3(2, 32), 256, 0, stream>>>(Wc[c], wct_h[c], wct_l[c], 128,
                                              128);
  wtrans_k<<<dim3(4, 64), 256, 0, stream>>>(W3, w3t_h, w3t_l, 256, 256);
  wtrans_k<<<dim3(2, 64), 256, 0, stream>>>(W4, w4t_h, w4t_l, 256, 128);

  for (int t = 0; t < 2; ++t) {
    const int* srcp = ei[t];
    const int* dstp = ei[t] + E;

    hipMemsetAsync(bnsum, 0, 128 * sizeof(float), stream);
    hipMemsetAsync(degc, 0, (size_t)N * sizeof(int), stream);

    bn_stats_k<<<256, 256, 0, stream>>>(x[t], bnsum, bnsq, N);
    bn_fold_k<<<1, 256, 0, stream>>>(bnsum, bnsq, gamma, beta, W1, b1, W1f,
                                     b1f, 1.0f / (float)N);
    wtrans_k<<<dim3(4, 16), 256, 0, stream>>>(W1f, w1t_h, w1t_l, 64, 256);

    gemm_mfma<<<dim3(2, gby), 256, 0, stream>>>(x[t], w1t_h, w1t_l, b1f, bufA,
                                                N, 256, 64, 1);
    gemm_mfma<<<dim3(1, gby), 256, 0, stream>>>(bufA, w2t_h, w2t_l, b2, bufB,
                                                N, 128, 256, 1);

    count_deg_k<<<nb_e, 256, 0, stream>>>(dstp, degc, E);
    dinv_k<<<nb_n, 256, 0, stream>>>(degc, dinv, N);

    scan1_k<<<nb_scan, 256, 0, stream>>>(degc, bsum, N);
    scan2_k<<<1, 64, 0, stream>>>(bsum, nb_scan);
    scan3_k<<<nb_scan, 256, 0, stream>>>(degc, bsum, rowstart, cursor, N, E);
    fillnorm_k<<<nb_e, 256, 0, stream>>>(srcp, dstp, dinv, cursor, epack, E);

    bstart_k<<<(B + 256) / 256, 256, 0, stream>>>(batch[t], bstart, N, B);

    float* hin = bufB;
    for (int c = 0; c < 3; ++c) {
      float* hout = (c == 1) ? bufB : bufA;  // ping-pong: B->A->B->A
      gemm_mfma_f16o<<<dim3(1, gby), 256, 0, stream>>>(hin, wct_h[c],
                                                       wct_l[c], xw16, N, 128,
                                                       128);
      gather16_k<<<nb_g16, 256, 0, stream>>>(rowstart, epack, xw16, dinv,
                                             bc[c], hout, N);
      hin = hout;
    }

    pool_seg_k<<<B, 128, 0, stream>>>(hin, bstart, catb, t * 128);
  }

  gemm_mfma<<<dim3(2, (B + 63) / 64), 256, 0, stream>>>(catb, w3t_h, w3t_l,
                                                        b3, z1, B, 256, 256,
                                                        1);
  gemm_mfma<<<dim3(1, (B + 63) / 64), 256, 0, stream>>>(z1, w4t_h, w4t_l, b4,
                                                        z2, B, 128, 256, 1);
  final_k<<<(B + 255) / 256, 256, 0, stream>>>(z2, W5, b5, out, B);
}

// Round 8
// 553.913 us; speedup vs baseline: 2.2441x; 1.2791x over previous
//
#include <hip/hip_runtime.h>
#include <cstdint>

// ---------------------------------------------------------------------------
// GCN twin-tower forward. Round 8: tower-merged dispatches.
//   Both towers are independent -> every stage becomes ONE dispatch with
//   blockIdx.z = tower (halves launch count, doubles per-dispatch
//   parallelism, better tail). Numerics identical to round 7:
//   3-MFMA fp16-split GEMMs, f16 xw gather path, f32 activations.
// ---------------------------------------------------------------------------

typedef _Float16 f16;
typedef f16 f16x8 __attribute__((ext_vector_type(8)));
typedef f16 f16x4 __attribute__((ext_vector_type(4)));
typedef float f32x4 __attribute__((ext_vector_type(4)));

// ---------------- BN stats: per-feature sum / sumsq, z = tower -------------
__global__ __launch_bounds__(256) void bn_stats_k(
    const float* __restrict__ x0, const float* __restrict__ x1,
    float* __restrict__ bnsum, float* __restrict__ bnsq, int n) {
  const float* x = blockIdx.z ? x1 : x0;
  float* bs = bnsum + blockIdx.z * 64;
  float* bq = bnsq + blockIdx.z * 64;
  __shared__ float ls[256], lq[256];
  const int tid = threadIdx.x;
  const int f = tid & 63;
  const int rb = tid >> 6;
  float s = 0.f, q = 0.f;
  for (int r = blockIdx.x * 4 + rb; r < n; r += gridDim.x * 4) {
    float v = x[(size_t)r * 64 + f];
    s += v;
    q += v * v;
  }
  ls[tid] = s;
  lq[tid] = q;
  __syncthreads();
  if (tid < 64) {
    s = ls[tid] + ls[tid + 64] + ls[tid + 128] + ls[tid + 192];
    q = lq[tid] + lq[tid + 64] + lq[tid + 128] + lq[tid + 192];
    atomicAdd(&bs[tid], s);
    atomicAdd(&bq[tid], q);
  }
}

// ------------- Fold BN affine into W1/b1, grid(2): x = tower ---------------
__global__ __launch_bounds__(256) void bn_fold_k(
    const float* __restrict__ bnsum, const float* __restrict__ bnsq,
    const float* __restrict__ gamma, const float* __restrict__ beta,
    const float* __restrict__ W1, const float* __restrict__ b1,
    float* __restrict__ W1f, float* __restrict__ b1f, float inv_n) {
  const int z = blockIdx.x;
  const float* bs = bnsum + z * 64;
  const float* bq = bnsq + z * 64;
  float* w1f = W1f + z * 16384;
  float* bf1 = b1f + z * 256;
  __shared__ float a[64], bf[64];
  const int tid = threadIdx.x;
  if (tid < 64) {
    float mu = bs[tid] * inv_n;
    float var = bq[tid] * inv_n - mu * mu;
    float s = gamma[tid] * rsqrtf(var + 1e-5f);
    a[tid] = s;
    bf[tid] = beta[tid] - mu * s;
  }
  __syncthreads();
  float acc = 0.f;
#pragma unroll
  for (int f = 0; f < 64; ++f) {
    float w = W1[f * 256 + tid];
    w1f[f * 256 + tid] = a[f] * w;
    acc += bf[f] * w;
  }
  bf1[tid] = b1[tid] + acc;
}

// ---- transpose + fp16-split: W[K][N] f32 -> Wt[N][K] f16, z-strided -------
__global__ __launch_bounds__(256) void wtrans_k(
    const float* __restrict__ W, int sstride, f16* __restrict__ Wth,
    f16* __restrict__ Wtl, int dstride, int K, int N) {
  const int z = blockIdx.z;
  const float* Wp = W + (size_t)z * sstride;
  f16* th = Wth + (size_t)z * dstride;
  f16* tl = Wtl + (size_t)z * dstride;
  int n = blockIdx.x * 64 + (threadIdx.x & 63);
  int k = blockIdx.y * 4 + (threadIdx.x >> 6);
  float v = Wp[(size_t)k * N + n];
  f16 h = (f16)v;
  f16 l = (f16)(v - (float)h);
  th[(size_t)n * K + k] = h;
  tl[(size_t)n * K + k] = l;
}

// ---------------- MFMA GEMM core (f32 or f16 output) -----------------------
// Tile 64(m) x 128(n), BK=32, 256 threads = 4 waves (2m x 2n), K%32==0.
template <int OUT16>
__device__ __forceinline__ void gemm_mfma_core(
    const float* __restrict__ A, const f16* __restrict__ Wth,
    const f16* __restrict__ Wtl, const float* __restrict__ bias,
    float* __restrict__ C, f16* __restrict__ C16, int M, int N, int K,
    int relu) {
  __shared__ f16 Ah[64][40], Al[64][40];
  __shared__ f16 Bh[128][40], Bl[128][40];
  const int tid = threadIdx.x;
  const int wave = tid >> 6;
  const int lane = tid & 63;
  const int wm = wave & 1;
  const int wn = wave >> 1;
  const int l15 = lane & 15;
  const int lk8 = (lane >> 4) * 8;
  const int sam = tid >> 2;
  const int sak = (tid & 3) * 8;
  const int sbn = tid >> 1;
  const int sbk = (tid & 1) * 16;
  const int arow = blockIdx.y * 64 + sam;
  const float* aptr = A + (size_t)arow * K + sak;
  const f16* bhp = Wth + (size_t)(blockIdx.x * 128 + sbn) * K + sbk;
  const f16* blp = Wtl + (size_t)(blockIdx.x * 128 + sbn) * K + sbk;

  f32x4 acc[2][4];
#pragma unroll
  for (int mi = 0; mi < 2; ++mi)
#pragma unroll
    for (int ni = 0; ni < 4; ++ni) acc[mi][ni] = (f32x4){0.f, 0.f, 0.f, 0.f};

  float4 pa0, pa1;
  if (arow < M) {
    pa0 = *(const float4*)aptr;
    pa1 = *(const float4*)(aptr + 4);
  } else {
    pa0 = make_float4(0.f, 0.f, 0.f, 0.f);
    pa1 = pa0;
  }
  f16x8 pbh0 = *(const f16x8*)bhp;
  f16x8 pbh1 = *(const f16x8*)(bhp + 8);
  f16x8 pbl0 = *(const f16x8*)blp;
  f16x8 pbl1 = *(const f16x8*)(blp + 8);

  const int nk = K / 32;
  for (int t = 0; t < nk; ++t) {
    if (t) __syncthreads();
    {
      float av[8] = {pa0.x, pa0.y, pa0.z, pa0.w, pa1.x, pa1.y, pa1.z, pa1.w};
      f16x8 vh, vl;
#pragma unroll
      for (int j = 0; j < 8; ++j) {
        f16 h = (f16)av[j];
        vh[j] = h;
        vl[j] = (f16)(av[j] - (float)h);
      }
      *(f16x8*)&Ah[sam][sak] = vh;
      *(f16x8*)&Al[sam][sak] = vl;
    }
    *(f16x8*)&Bh[sbn][sbk] = pbh0;
    *(f16x8*)&Bh[sbn][sbk + 8] = pbh1;
    *(f16x8*)&Bl[sbn][sbk] = pbl0;
    *(f16x8*)&Bl[sbn][sbk + 8] = pbl1;
    __syncthreads();
    if (t + 1 < nk) {
      const int k0 = (t + 1) * 32;
      if (arow < M) {
        pa0 = *(const float4*)(aptr + k0);
        pa1 = *(const float4*)(aptr + k0 + 4);
      } else {
        pa0 = make_float4(0.f, 0.f, 0.f, 0.f);
        pa1 = pa0;
      }
      pbh0 = *(const f16x8*)(bhp + k0);
      pbh1 = *(const f16x8*)(bhp + k0 + 8);
      pbl0 = *(const f16x8*)(blp + k0);
      pbl1 = *(const f16x8*)(blp + k0 + 8);
    }
    f16x8 ath[2], atl[2];
#pragma unroll
    for (int mi = 0; mi < 2; ++mi) {
      const int r = wm * 32 + mi * 16 + l15;
      ath[mi] = *(const f16x8*)&Ah[r][lk8];
      atl[mi] = *(const f16x8*)&Al[r][lk8];
    }
    f16x8 bth[4], btl[4];
#pragma unroll
    for (int ni = 0; ni < 4; ++ni) {
      const int r = wn * 64 + ni * 16 + l15;
      bth[ni] = *(const f16x8*)&Bh[r][lk8];
      btl[ni] = *(const f16x8*)&Bl[r][lk8];
    }
#pragma unroll
    for (int mi = 0; mi < 2; ++mi)
#pragma unroll
      for (int ni = 0; ni < 4; ++ni) {
        acc[mi][ni] = __builtin_amdgcn_mfma_f32_16x16x32_f16(
            bth[ni], ath[mi], acc[mi][ni], 0, 0, 0);
        acc[mi][ni] = __builtin_amdgcn_mfma_f32_16x16x32_f16(
            bth[ni], atl[mi], acc[mi][ni], 0, 0, 0);
        acc[mi][ni] = __builtin_amdgcn_mfma_f32_16x16x32_f16(
            btl[ni], ath[mi], acc[mi][ni], 0, 0, 0);
      }
  }

#pragma unroll
  for (int mi = 0; mi < 2; ++mi) {
    const int m = blockIdx.y * 64 + wm * 32 + mi * 16 + l15;
    if (m >= M) continue;
#pragma unroll
    for (int ni = 0; ni < 4; ++ni) {
      const int nb = blockIdx.x * 128 + wn * 64 + ni * 16 + (lane >> 4) * 4;
      if (OUT16) {
        f16x4 h;
        h[0] = (f16)acc[mi][ni][0];
        h[1] = (f16)acc[mi][ni][1];
        h[2] = (f16)acc[mi][ni][2];
        h[3] = (f16)acc[mi][ni][3];
        *(f16x4*)(C16 + (size_t)m * N + nb) = h;
      } else {
        float4 bv = make_float4(0.f, 0.f, 0.f, 0.f);
        if (bias) bv = *(const float4*)(bias + nb);
        float4 v;
        v.x = acc[mi][ni][0] + bv.x;
        v.y = acc[mi][ni][1] + bv.y;
        v.z = acc[mi][ni][2] + bv.z;
        v.w = acc[mi][ni][3] + bv.w;
        if (relu) {
          v.x = fmaxf(v.x, 0.f);
          v.y = fmaxf(v.y, 0.f);
          v.z = fmaxf(v.z, 0.f);
          v.w = fmaxf(v.w, 0.f);
        }
        *(float4*)(C + (size_t)m * N + nb) = v;
      }
    }
  }
}

// f32-out wrapper, z = tower (pointer pairs)
__global__ __launch_bounds__(256) void gemm_mfma(
    const float* __restrict__ A0, const float* __restrict__ A1,
    const f16* __restrict__ Wth0, const f16* __restrict__ Wth1,
    const f16* __restrict__ Wtl0, const f16* __restrict__ Wtl1,
    const float* __restrict__ bias0, const float* __restrict__ bias1,
    float* __restrict__ C0, float* __restrict__ C1, int M, int N, int K,
    int relu) {
  const int z = blockIdx.z;
  gemm_mfma_core<0>(z ? A1 : A0, z ? Wth1 : Wth0, z ? Wtl1 : Wtl0,
                    z ? bias1 : bias0, z ? C1 : C0, nullptr, M, N, K, relu);
}

// f16-out wrapper, z = tower
__global__ __launch_bounds__(256) void gemm_mfma_f16o(
    const float* __restrict__ A0, const float* __restrict__ A1,
    const f16* __restrict__ Wth, const f16* __restrict__ Wtl,
    f16* __restrict__ C0, f16* __restrict__ C1, int M, int N, int K) {
  const int z = blockIdx.z;
  gemm_mfma_core<1>(z ? A1 : A0, Wth, Wtl, nullptr, nullptr, z ? C1 : C0, M,
                    N, K, 0);
}

// ---------------- degree count, z = tower ----------------------------------
__global__ __launch_bounds__(256) void count_deg_k(
    const int* __restrict__ ei0, const int* __restrict__ ei1,
    int* __restrict__ cnt, int e, int n) {
  const int z = blockIdx.z;
  const int* dst = (z ? ei1 : ei0) + e;
  int* c = cnt + (size_t)z * n;
  int i = blockIdx.x * 256 + threadIdx.x;
  if (i < e) atomicAdd(&c[dst[i]], 1);
}

__global__ __launch_bounds__(256) void dinv_k(const int* __restrict__ cnt,
                                              float* __restrict__ dinv,
                                              int n) {
  const int z = blockIdx.z;
  const int* c = cnt + (size_t)z * n;
  float* dv = dinv + (size_t)z * n;
  int i = blockIdx.x * 256 + threadIdx.x;
  if (i < n) dv[i] = rsqrtf((float)(c[i] + 1));
}

// ---------------- CSR build scans, z = tower -------------------------------
__global__ __launch_bounds__(256) void scan1_k(const int* __restrict__ deg,
                                               int* __restrict__ bsum, int n) {
  const int z = blockIdx.z;
  const int* d = deg + (size_t)z * n;
  int* bs = bsum + z * 64;
  __shared__ int ls[256];
  const int base = blockIdx.x * 1024;
  int s = 0;
  for (int j = threadIdx.x; j < 1024; j += 256) {
    int i = base + j;
    s += (i < n) ? d[i] : 0;
  }
  ls[threadIdx.x] = s;
  __syncthreads();
  for (int off = 128; off > 0; off >>= 1) {
    if (threadIdx.x < off) ls[threadIdx.x] += ls[threadIdx.x + off];
    __syncthreads();
  }
  if (threadIdx.x == 0) bs[blockIdx.x] = ls[0];
}

__global__ void scan2_k(int* __restrict__ bsum, int nb) {
  int* bs = bsum + blockIdx.z * 64;
  if (threadIdx.x == 0) {
    int acc = 0;
    for (int i = 0; i < nb; ++i) {
      int v = bs[i];
      bs[i] = acc;
      acc += v;
    }
  }
}

__global__ __launch_bounds__(256) void scan3_k(
    const int* __restrict__ deg, const int* __restrict__ bsum,
    int* __restrict__ rowstart, int* __restrict__ cursor, int n, int e) {
  const int z = blockIdx.z;
  const int* d = deg + (size_t)z * n;
  const int* bs = bsum + z * 64;
  int* rs = rowstart + (size_t)z * (n + 1);
  int* cu = cursor + (size_t)z * n;
  __shared__ int ts[256];
  const int tid = threadIdx.x;
  const int i0 = blockIdx.x * 1024 + tid * 4;
  int v[4];
  int s = 0;
#pragma unroll
  for (int j = 0; j < 4; ++j) {
    int i = i0 + j;
    v[j] = (i < n) ? d[i] : 0;
    s += v[j];
  }
  ts[tid] = s;
  __syncthreads();
  for (int off = 1; off < 256; off <<= 1) {
    int t = (tid >= off) ? ts[tid - off] : 0;
    __syncthreads();
    ts[tid] += t;
    __syncthreads();
  }
  int run = bs[blockIdx.x] + ts[tid] - s;
#pragma unroll
  for (int j = 0; j < 4; ++j) {
    int i = i0 + j;
    if (i < n) {
      rs[i] = run;
      cu[i] = run;
    }
    run += v[j];
  }
  if (blockIdx.x == 0 && tid == 0) rs[n] = e;
}

// fill: dst-sorted packed (src, norm) edges, z = tower
__global__ __launch_bounds__(256) void fillnorm_k(
    const int* __restrict__ ei0, const int* __restrict__ ei1,
    const float* __restrict__ dinv, int* __restrict__ cursor,
    int2* __restrict__ epack, int e, int n) {
  const int z = blockIdx.z;
  const int* src = z ? ei1 : ei0;
  const int* dst = src + e;
  const float* dv = dinv + (size_t)z * n;
  int* cu = cursor + (size_t)z * n;
  int2* ep = epack + (size_t)z * e;
  int i = blockIdx.x * 256 + threadIdx.x;
  if (i >= e) return;
  int s = src[i], d = dst[i];
  int pos = atomicAdd(&cu[d], 1);
  ep[pos] = make_int2(s, __float_as_int(dv[s] * dv[d]));
}

// ---------------- gather (f16 rows), z = tower -----------------------------
// 16 threads per node, f16x8 (16B) per thread (128 feat).
__global__ __launch_bounds__(256) void gather16_k(
    const int* __restrict__ rowstart, const int2* __restrict__ epack,
    const f16* __restrict__ xw16, const float* __restrict__ dinv,
    const float* __restrict__ bias, float* __restrict__ out0,
    float* __restrict__ out1, int n, int e) {
  const int z = blockIdx.z;
  const int* rs = rowstart + (size_t)z * (n + 1);
  const int2* ep = epack + (size_t)z * e;
  const f16x8* x8 = (const f16x8*)(xw16 + (size_t)z * n * 128);
  const float* dv = dinv + (size_t)z * n;
  float* out = z ? out1 : out0;
  int gid = blockIdx.x * 256 + threadIdx.x;
  int v = gid >> 4;
  if (v >= n) return;
  int q = gid & 15;
  float d = dv[v];
  float sl = d * d;
  f16x8 sv = x8[(size_t)v * 16 + q];
  float acc[8];
#pragma unroll
  for (int j = 0; j < 8; ++j) acc[j] = (float)sv[j] * sl;
  int s0 = rs[v], s1 = rs[v + 1];
  for (int ed = s0; ed < s1; ++ed) {
    int2 edv = ep[ed];
    float w = __int_as_float(edv.y);
    f16x8 t = x8[(size_t)edv.x * 16 + q];
#pragma unroll
    for (int j = 0; j < 8; ++j) acc[j] += (float)t[j] * w;
  }
  float4 b0 = *(const float4*)(bias + q * 8);
  float4 b1 = *(const float4*)(bias + q * 8 + 4);
  float4 o0, o1;
  o0.x = fmaxf(acc[0] + b0.x, 0.f);
  o0.y = fmaxf(acc[1] + b0.y, 0.f);
  o0.z = fmaxf(acc[2] + b0.z, 0.f);
  o0.w = fmaxf(acc[3] + b0.w, 0.f);
  o1.x = fmaxf(acc[4] + b1.x, 0.f);
  o1.y = fmaxf(acc[5] + b1.y, 0.f);
  o1.z = fmaxf(acc[6] + b1.z, 0.f);
  o1.w = fmaxf(acc[7] + b1.w, 0.f);
  *(float4*)(out + (size_t)v * 128 + q * 8) = o0;
  *(float4*)(out + (size_t)v * 128 + q * 8 + 4) = o1;
}

// ---------------- pool: segmented mean, z = tower --------------------------
__global__ __launch_bounds__(256) void bstart_k(const int* __restrict__ b0,
                                                const int* __restrict__ b1,
                                                int* __restrict__ bstart,
                                                int n, int nb) {
  const int z = blockIdx.z;
  const int* batch = z ? b1 : b0;
  int* bst = bstart + (size_t)z * (nb + 1);
  int b = blockIdx.x * 256 + threadIdx.x;
  if (b > nb) return;
  int lo = 0, hi = n;
  while (lo < hi) {
    int mid = (lo + hi) >> 1;
    if (batch[mid] < b) lo = mid + 1; else hi = mid;
  }
  bst[b] = lo;
}

__global__ __launch_bounds__(128) void pool_seg_k(
    const float* __restrict__ h0, const float* __restrict__ h1,
    const int* __restrict__ bstart, float* __restrict__ cat, int nb) {
  const int z = blockIdx.z;
  const float* h = z ? h1 : h0;
  const int* bst = bstart + (size_t)z * (nb + 1);
  int b = blockIdx.x;
  int s = bst[b], e = bst[b + 1];
  int f = threadIdx.x;
  float acc = 0.f;
  for (int v = s; v < e; ++v) acc += h[(size_t)v * 128 + f];
  float c = fmaxf((float)(e - s), 1.f);
  cat[(size_t)b * 256 + z * 128 + f] = acc / c;
}

// ---------------- final: out[r] = z2[r,:]@W5 + b5 --------------------------
__global__ __launch_bounds__(256) void final_k(const float* __restrict__ z2,
                                               const float* __restrict__ W5,
                                               const float* __restrict__ b5,
                                               float* __restrict__ out,
                                               int rows) {
  int r = blockIdx.x * 256 + threadIdx.x;
  if (r >= rows) return;
  float acc = b5[0];
#pragma unroll
  for (int k = 0; k < 128; ++k) acc += z2[(size_t)r * 128 + k] * W5[k];
  out[r] = acc;
}

// ---------------------------------------------------------------------------
extern "C" void kernel_launch(void* const* d_in, const int* in_sizes, int n_in,
                              void* d_out, int out_size, void* d_ws,
                              size_t ws_size, hipStream_t stream) {
  const float* x0 = (const float*)d_in[0];
  const float* x1 = (const float*)d_in[3];
  const int* ei0 = (const int*)d_in[1];
  const int* ei1 = (const int*)d_in[4];
  const int* ba0 = (const int*)d_in[2];
  const int* ba1 = (const int*)d_in[5];
  const float* gamma = (const float*)d_in[6];
  const float* beta = (const float*)d_in[7];
  const float* W1 = (const float*)d_in[8];
  const float* b1 = (const float*)d_in[9];
  const float* W2 = (const float*)d_in[10];
  const float* b2 = (const float*)d_in[11];
  const float* Wc[3] = {(const float*)d_in[12], (const float*)d_in[14],
                        (const float*)d_in[16]};
  const float* bc[3] = {(const float*)d_in[13], (const float*)d_in[15],
                        (const float*)d_in[17]};
  const float* W3 = (const float*)d_in[18];
  const float* b3 = (const float*)d_in[19];
  const float* W4 = (const float*)d_in[20];
  const float* b4 = (const float*)d_in[21];
  const float* W5 = (const float*)d_in[22];
  const float* b5 = (const float*)d_in[23];
  float* out = (float*)d_out;

  const int N = in_sizes[0] / 64;  // 50000
  const int E = in_sizes[1] / 2;   // 600000
  const int B = out_size;          // 512

  // ---- workspace layout (both towers resident) ----
  float* ws = (float*)d_ws;
  float* bufA = ws;                              // 2 * N*256 (h0; conv D reuse)
  float* bufB = bufA + (size_t)2 * N * 256;      // 2 * N*128 (h1 / conv B)
  f16* xw16 = (f16*)(bufB + (size_t)2 * N * 128);  // 2 * N*128 f16
  float* dinv = (float*)(xw16 + (size_t)2 * N * 128);  // 2*N
  int2* epack = (int2*)(dinv + (size_t)2 * N);   // 2*E
  int* degc = (int*)(epack + (size_t)2 * E);     // 2*N (contig for one memset)
  int* rowstart = degc + (size_t)2 * N;          // 2*(N+1)
  int* cursor = rowstart + (size_t)2 * (N + 1);  // 2*N
  int* bsum = cursor + (size_t)2 * N;            // 2*64
  int* bstart = bsum + 128;                      // 2*(B+1)
  float* bnsum = (float*)(bstart + 2 * (B + 1)); // 128 (+128 bnsq contig)
  float* bnsq = bnsum + 128;
  float* W1f = bnsq + 128;                       // 2*16384
  float* b1f = W1f + 2 * 16384;                  // 2*256
  float* catb = b1f + 512;                       // B*256
  float* z1 = catb + (size_t)B * 256;            // B*256
  float* z2 = z1 + (size_t)B * 256;              // B*128
  f16* wtp = (f16*)(((uintptr_t)(z2 + (size_t)B * 128) + 63) &
                    ~(uintptr_t)63);
  f16* w1t_h = wtp; wtp += 2 * 16384;  // per tower [256][64]
  f16* w1t_l = wtp; wtp += 2 * 16384;
  f16* w2t_h = wtp; wtp += 32768;      // [128][256]
  f16* w2t_l = wtp; wtp += 32768;
  f16* wct_h[3]; f16* wct_l[3];
  for (int c = 0; c < 3; ++c) {
    wct_h[c] = wtp; wtp += 16384;      // [128][128]
    wct_l[c] = wtp; wtp += 16384;
  }
  f16* w3t_h = wtp; wtp += 65536;      // [256][256]
  f16* w3t_l = wtp; wtp += 65536;
  f16* w4t_h = wtp; wtp += 32768;      // [128][256]
  f16* w4t_l = wtp; wtp += 32768;
  size_t need = (size_t)((char*)wtp - (char*)d_ws);
  if (ws_size < need) return;  // workspace too small -> fail loudly

  // per-tower derived pointers
  float* h0_[2] = {bufA, bufA + (size_t)N * 256};
  float* hB_[2] = {bufB, bufB + (size_t)N * 128};
  float* hD_[2] = {bufA, bufA + (size_t)N * 256};  // reuse h0 area (N*128)
  f16* xw_[2] = {xw16, xw16 + (size_t)N * 128};

  const int nb_e = (E + 255) / 256;
  const int nb_n = (N + 255) / 256;
  const int nb_scan = (N + 1023) / 1024;
  const int nb_g16 = (N * 16 + 255) / 256;
  const int gby = (N + 63) / 64;  // 782

  // ---- zero accumulators (one memset each, both towers) ----
  hipMemsetAsync(degc, 0, (size_t)2 * N * sizeof(int), stream);
  hipMemsetAsync(bnsum, 0, 256 * sizeof(float), stream);

  // ---- shared weights: transpose+split once ----
  wtrans_k<<<dim3(2, 64, 1), 256, 0, stream>>>(W2, 0, w2t_h, w2t_l, 0, 256,
                                               128);
  for (int c = 0; c < 3; ++c)
    wtrans_k<<<dim3(2, 32, 1), 256, 0, stream>>>(Wc[c], 0, wct_h[c], wct_l[c],
                                                 0, 128, 128);
  wtrans_k<<<dim3(4, 64, 1), 256, 0, stream>>>(W3, 0, w3t_h, w3t_l, 0, 256,
                                               256);
  wtrans_k<<<dim3(2, 64, 1), 256, 0, stream>>>(W4, 0, w4t_h, w4t_l, 0, 256,
                                               128);

  // ---- BN -> folded W1 (per tower) ----
  bn_stats_k<<<dim3(256, 1, 2), 256, 0, stream>>>(x0, x1, bnsum, bnsq, N);
  bn_fold_k<<<2, 256, 0, stream>>>(bnsum, bnsq, gamma, beta, W1, b1, W1f, b1f,
                                   1.0f / (float)N);
  wtrans_k<<<dim3(4, 16, 2), 256, 0, stream>>>(W1f, 16384, w1t_h, w1t_l,
                                               16384, 64, 256);

  // ---- dense head of each tower ----
  gemm_mfma<<<dim3(2, gby, 2), 256, 0, stream>>>(
      x0, x1, w1t_h, w1t_h + 16384, w1t_l, w1t_l + 16384, b1f, b1f + 256,
      h0_[0], h0_[1], N, 256, 64, 1);
  gemm_mfma<<<dim3(1, gby, 2), 256, 0, stream>>>(
      h0_[0], h0_[1], w2t_h, w2t_h, w2t_l, w2t_l, b2, b2, hB_[0], hB_[1], N,
      128, 256, 1);

  // ---- CSR build (per tower in one dispatch) ----
  count_deg_k<<<dim3(nb_e, 1, 2), 256, 0, stream>>>(ei0, ei1, degc, E, N);
  dinv_k<<<dim3(nb_n, 1, 2), 256, 0, stream>>>(degc, dinv, N);
  scan1_k<<<dim3(nb_scan, 1, 2), 256, 0, stream>>>(degc, bsum, N);
  scan2_k<<<dim3(1, 1, 2), 64, 0, stream>>>(bsum, nb_scan);
  scan3_k<<<dim3(nb_scan, 1, 2), 256, 0, stream>>>(degc, bsum, rowstart,
                                                   cursor, N, E);
  fillnorm_k<<<dim3(nb_e, 1, 2), 256, 0, stream>>>(ei0, ei1, dinv, cursor,
                                                   epack, E, N);
  bstart_k<<<dim3((B + 256) / 256, 1, 2), 256, 0, stream>>>(ba0, ba1, bstart,
                                                            N, B);

  // ---- 3 conv layers: GEMM(f16 out) + gather, both towers per dispatch ----
  // chain: hB -> (c0) hD -> (c1) hB -> (c2) hD
  float* cin[3][2] = {{hB_[0], hB_[1]}, {hD_[0], hD_[1]}, {hB_[0], hB_[1]}};
  float* cout[3][2] = {{hD_[0], hD_[1]}, {hB_[0], hB_[1]}, {hD_[0], hD_[1]}};
  for (int c = 0; c < 3; ++c) {
    gemm_mfma_f16o<<<dim3(1, gby, 2), 256, 0, stream>>>(
        cin[c][0], cin[c][1], wct_h[c], wct_l[c], xw_[0], xw_[1], N, 128, 128);
    gather16_k<<<dim3(nb_g16, 1, 2), 256, 0, stream>>>(
        rowstart, epack, xw16, dinv, bc[c], cout[c][0], cout[c][1], N, E);
  }

  // ---- pool (both towers) ----
  pool_seg_k<<<dim3(B, 1, 2), 128, 0, stream>>>(hD_[0], hD_[1], bstart, catb,
                                                B);

  // ---- head MLP ----
  gemm_mfma<<<dim3(2, (B + 63) / 64, 1), 256, 0, stream>>>(
      catb, catb, w3t_h, w3t_h, w3t_l, w3t_l, b3, b3, z1, z1, B, 256, 256, 1);
  gemm_mfma<<<dim3(1, (B + 63) / 64, 1), 256, 0, stream>>>(
      z1, z1, w4t_h, w4t_h, w4t_l, w4t_l, b4, b4, z2, z2, B, 128, 256, 1);
  final_k<<<(B + 255) / 256, 256, 0, stream>>>(z2, W5, b5, out, B);
}

// Round 9
// 548.414 us; speedup vs baseline: 2.2666x; 1.0100x over previous
//
#include <hip/hip_runtime.h>
#include <cstdint>

// ---------------------------------------------------------------------------
// GCN twin-tower forward. Round 9: CSR fill rework.
//   - norm factored: xws[r] = dinv[r]*xw[r] folded into conv-GEMM f16
//     epilogue; gather: out[v] = relu(dinv[v]*(xws[v]+sum xws[src]) + bias).
//     Edge payload = src only (4B, was 8B int2), fill reads no dinv.
//   - fill pass-partitioned by dst range (grid.y=4): writes land in
//     contiguous ~600KB regions -> L2/L3 coalesce (was 64B/line per store).
//   - dinv computed inside scan3 (one fewer dispatch).
// Everything else as round 8 (tower-merged, 3-MFMA fp16-split GEMMs).
// ---------------------------------------------------------------------------

typedef _Float16 f16;
typedef f16 f16x8 __attribute__((ext_vector_type(8)));
typedef f16 f16x4 __attribute__((ext_vector_type(4)));
typedef float f32x4 __attribute__((ext_vector_type(4)));

#define NPASS 4

// ---------------- BN stats: per-feature sum / sumsq, z = tower -------------
__global__ __launch_bounds__(256) void bn_stats_k(
    const float* __restrict__ x0, const float* __restrict__ x1,
    float* __restrict__ bnsum, float* __restrict__ bnsq, int n) {
  const float* x = blockIdx.z ? x1 : x0;
  float* bs = bnsum + blockIdx.z * 64;
  float* bq = bnsq + blockIdx.z * 64;
  __shared__ float ls[256], lq[256];
  const int tid = threadIdx.x;
  const int f = tid & 63;
  const int rb = tid >> 6;
  float s = 0.f, q = 0.f;
  for (int r = blockIdx.x * 4 + rb; r < n; r += gridDim.x * 4) {
    float v = x[(size_t)r * 64 + f];
    s += v;
    q += v * v;
  }
  ls[tid] = s;
  lq[tid] = q;
  __syncthreads();
  if (tid < 64) {
    s = ls[tid] + ls[tid + 64] + ls[tid + 128] + ls[tid + 192];
    q = lq[tid] + lq[tid + 64] + lq[tid + 128] + lq[tid + 192];
    atomicAdd(&bs[tid], s);
    atomicAdd(&bq[tid], q);
  }
}

// ------------- Fold BN affine into W1/b1, grid(2): x = tower ---------------
__global__ __launch_bounds__(256) void bn_fold_k(
    const float* __restrict__ bnsum, const float* __restrict__ bnsq,
    const float* __restrict__ gamma, const float* __restrict__ beta,
    const float* __restrict__ W1, const float* __restrict__ b1,
    float* __restrict__ W1f, float* __restrict__ b1f, float inv_n) {
  const int z = blockIdx.x;
  const float* bs = bnsum + z * 64;
  const float* bq = bnsq + z * 64;
  float* w1f = W1f + z * 16384;
  float* bf1 = b1f + z * 256;
  __shared__ float a[64], bf[64];
  const int tid = threadIdx.x;
  if (tid < 64) {
    float mu = bs[tid] * inv_n;
    float var = bq[tid] * inv_n - mu * mu;
    float s = gamma[tid] * rsqrtf(var + 1e-5f);
    a[tid] = s;
    bf[tid] = beta[tid] - mu * s;
  }
  __syncthreads();
  float acc = 0.f;
#pragma unroll
  for (int f = 0; f < 64; ++f) {
    float w = W1[f * 256 + tid];
    w1f[f * 256 + tid] = a[f] * w;
    acc += bf[f] * w;
  }
  bf1[tid] = b1[tid] + acc;
}

// ---- transpose + fp16-split: W[K][N] f32 -> Wt[N][K] f16, z-strided -------
__global__ __launch_bounds__(256) void wtrans_k(
    const float* __restrict__ W, int sstride, f16* __restrict__ Wth,
    f16* __restrict__ Wtl, int dstride, int K, int N) {
  const int z = blockIdx.z;
  const float* Wp = W + (size_t)z * sstride;
  f16* th = Wth + (size_t)z * dstride;
  f16* tl = Wtl + (size_t)z * dstride;
  int n = blockIdx.x * 64 + (threadIdx.x & 63);
  int k = blockIdx.y * 4 + (threadIdx.x >> 6);
  float v = Wp[(size_t)k * N + n];
  f16 h = (f16)v;
  f16 l = (f16)(v - (float)h);
  th[(size_t)n * K + k] = h;
  tl[(size_t)n * K + k] = l;
}

// ---------------- MFMA GEMM core (f32 out, or f16 out scaled by dinv) ------
// Tile 64(m) x 128(n), BK=32, 256 threads = 4 waves (2m x 2n), K%32==0.
template <int OUT16>
__device__ __forceinline__ void gemm_mfma_core(
    const float* __restrict__ A, const f16* __restrict__ Wth,
    const f16* __restrict__ Wtl, const float* __restrict__ bias,
    float* __restrict__ C, f16* __restrict__ C16,
    const float* __restrict__ rowscale, int M, int N, int K, int relu) {
  __shared__ f16 Ah[64][40], Al[64][40];
  __shared__ f16 Bh[128][40], Bl[128][40];
  const int tid = threadIdx.x;
  const int wave = tid >> 6;
  const int lane = tid & 63;
  const int wm = wave & 1;
  const int wn = wave >> 1;
  const int l15 = lane & 15;
  const int lk8 = (lane >> 4) * 8;
  const int sam = tid >> 2;
  const int sak = (tid & 3) * 8;
  const int sbn = tid >> 1;
  const int sbk = (tid & 1) * 16;
  const int arow = blockIdx.y * 64 + sam;
  const float* aptr = A + (size_t)arow * K + sak;
  const f16* bhp = Wth + (size_t)(blockIdx.x * 128 + sbn) * K + sbk;
  const f16* blp = Wtl + (size_t)(blockIdx.x * 128 + sbn) * K + sbk;

  f32x4 acc[2][4];
#pragma unroll
  for (int mi = 0; mi < 2; ++mi)
#pragma unroll
    for (int ni = 0; ni < 4; ++ni) acc[mi][ni] = (f32x4){0.f, 0.f, 0.f, 0.f};

  float4 pa0, pa1;
  if (arow < M) {
    pa0 = *(const float4*)aptr;
    pa1 = *(const float4*)(aptr + 4);
  } else {
    pa0 = make_float4(0.f, 0.f, 0.f, 0.f);
    pa1 = pa0;
  }
  f16x8 pbh0 = *(const f16x8*)bhp;
  f16x8 pbh1 = *(const f16x8*)(bhp + 8);
  f16x8 pbl0 = *(const f16x8*)blp;
  f16x8 pbl1 = *(const f16x8*)(blp + 8);

  const int nk = K / 32;
  for (int t = 0; t < nk; ++t) {
    if (t) __syncthreads();
    {
      float av[8] = {pa0.x, pa0.y, pa0.z, pa0.w, pa1.x, pa1.y, pa1.z, pa1.w};
      f16x8 vh, vl;
#pragma unroll
      for (int j = 0; j < 8; ++j) {
        f16 h = (f16)av[j];
        vh[j] = h;
        vl[j] = (f16)(av[j] - (float)h);
      }
      *(f16x8*)&Ah[sam][sak] = vh;
      *(f16x8*)&Al[sam][sak] = vl;
    }
    *(f16x8*)&Bh[sbn][sbk] = pbh0;
    *(f16x8*)&Bh[sbn][sbk + 8] = pbh1;
    *(f16x8*)&Bl[sbn][sbk] = pbl0;
    *(f16x8*)&Bl[sbn][sbk + 8] = pbl1;
    __syncthreads();
    if (t + 1 < nk) {
      const int k0 = (t + 1) * 32;
      if (arow < M) {
        pa0 = *(const float4*)(aptr + k0);
        pa1 = *(const float4*)(aptr + k0 + 4);
      } else {
        pa0 = make_float4(0.f, 0.f, 0.f, 0.f);
        pa1 = pa0;
      }
      pbh0 = *(const f16x8*)(bhp + k0);
      pbh1 = *(const f16x8*)(bhp + k0 + 8);
      pbl0 = *(const f16x8*)(blp + k0);
      pbl1 = *(const f16x8*)(blp + k0 + 8);
    }
    f16x8 ath[2], atl[2];
#pragma unroll
    for (int mi = 0; mi < 2; ++mi) {
      const int r = wm * 32 + mi * 16 + l15;
      ath[mi] = *(const f16x8*)&Ah[r][lk8];
      atl[mi] = *(const f16x8*)&Al[r][lk8];
    }
    f16x8 bth[4], btl[4];
#pragma unroll
    for (int ni = 0; ni < 4; ++ni) {
      const int r = wn * 64 + ni * 16 + l15;
      bth[ni] = *(const f16x8*)&Bh[r][lk8];
      btl[ni] = *(const f16x8*)&Bl[r][lk8];
    }
#pragma unroll
    for (int mi = 0; mi < 2; ++mi)
#pragma unroll
      for (int ni = 0; ni < 4; ++ni) {
        acc[mi][ni] = __builtin_amdgcn_mfma_f32_16x16x32_f16(
            bth[ni], ath[mi], acc[mi][ni], 0, 0, 0);
        acc[mi][ni] = __builtin_amdgcn_mfma_f32_16x16x32_f16(
            bth[ni], atl[mi], acc[mi][ni], 0, 0, 0);
        acc[mi][ni] = __builtin_amdgcn_mfma_f32_16x16x32_f16(
            btl[ni], ath[mi], acc[mi][ni], 0, 0, 0);
      }
  }

#pragma unroll
  for (int mi = 0; mi < 2; ++mi) {
    const int m = blockIdx.y * 64 + wm * 32 + mi * 16 + l15;
    if (m >= M) continue;
#pragma unroll
    for (int ni = 0; ni < 4; ++ni) {
      const int nb = blockIdx.x * 128 + wn * 64 + ni * 16 + (lane >> 4) * 4;
      if (OUT16) {
        float s = rowscale[m];
        f16x4 h;
        h[0] = (f16)(acc[mi][ni][0] * s);
        h[1] = (f16)(acc[mi][ni][1] * s);
        h[2] = (f16)(acc[mi][ni][2] * s);
        h[3] = (f16)(acc[mi][ni][3] * s);
        *(f16x4*)(C16 + (size_t)m * N + nb) = h;
      } else {
        float4 bv = make_float4(0.f, 0.f, 0.f, 0.f);
        if (bias) bv = *(const float4*)(bias + nb);
        float4 v;
        v.x = acc[mi][ni][0] + bv.x;
        v.y = acc[mi][ni][1] + bv.y;
        v.z = acc[mi][ni][2] + bv.z;
        v.w = acc[mi][ni][3] + bv.w;
        if (relu) {
          v.x = fmaxf(v.x, 0.f);
          v.y = fmaxf(v.y, 0.f);
          v.z = fmaxf(v.z, 0.f);
          v.w = fmaxf(v.w, 0.f);
        }
        *(float4*)(C + (size_t)m * N + nb) = v;
      }
    }
  }
}

// f32-out wrapper, z = tower (pointer pairs)
__global__ __launch_bounds__(256) void gemm_mfma(
    const float* __restrict__ A0, const float* __restrict__ A1,
    const f16* __restrict__ Wth0, const f16* __restrict__ Wth1,
    const f16* __restrict__ Wtl0, const f16* __restrict__ Wtl1,
    const float* __restrict__ bias0, const float* __restrict__ bias1,
    float* __restrict__ C0, float* __restrict__ C1, int M, int N, int K,
    int relu) {
  const int z = blockIdx.z;
  gemm_mfma_core<0>(z ? A1 : A0, z ? Wth1 : Wth0, z ? Wtl1 : Wtl0,
                    z ? bias1 : bias0, z ? C1 : C0, nullptr, nullptr, M, N, K,
                    relu);
}

// f16-out wrapper (rows scaled by dinv), z = tower
__global__ __launch_bounds__(256) void gemm_mfma_f16o(
    const float* __restrict__ A0, const float* __restrict__ A1,
    const f16* __restrict__ Wth, const f16* __restrict__ Wtl,
    const float* __restrict__ dinv, f16* __restrict__ C0,
    f16* __restrict__ C1, int M, int N, int K) {
  const int z = blockIdx.z;
  gemm_mfma_core<1>(z ? A1 : A0, Wth, Wtl, nullptr, nullptr, z ? C1 : C0,
                    dinv + (size_t)z * M, M, N, K, 0);
}

// ---------------- degree count, z = tower ----------------------------------
__global__ __launch_bounds__(256) void count_deg_k(
    const int* __restrict__ ei0, const int* __restrict__ ei1,
    int* __restrict__ cnt, int e, int n) {
  const int z = blockIdx.z;
  const int* dst = (z ? ei1 : ei0) + e;
  int* c = cnt + (size_t)z * n;
  int i = blockIdx.x * 256 + threadIdx.x;
  if (i < e) atomicAdd(&c[dst[i]], 1);
}

// ---------------- CSR build scans, z = tower -------------------------------
__global__ __launch_bounds__(256) void scan1_k(const int* __restrict__ deg,
                                               int* __restrict__ bsum, int n) {
  const int z = blockIdx.z;
  const int* d = deg + (size_t)z * n;
  int* bs = bsum + z * 64;
  __shared__ int ls[256];
  const int base = blockIdx.x * 1024;
  int s = 0;
  for (int j = threadIdx.x; j < 1024; j += 256) {
    int i = base + j;
    s += (i < n) ? d[i] : 0;
  }
  ls[threadIdx.x] = s;
  __syncthreads();
  for (int off = 128; off > 0; off >>= 1) {
    if (threadIdx.x < off) ls[threadIdx.x] += ls[threadIdx.x + off];
    __syncthreads();
  }
  if (threadIdx.x == 0) bs[blockIdx.x] = ls[0];
}

__global__ void scan2_k(int* __restrict__ bsum, int nb) {
  int* bs = bsum + blockIdx.z * 64;
  if (threadIdx.x == 0) {
    int acc = 0;
    for (int i = 0; i < nb; ++i) {
      int v = bs[i];
      bs[i] = acc;
      acc += v;
    }
  }
}

// scan3: rowstart + cursor + dinv (folded)
__global__ __launch_bounds__(256) void scan3_k(
    const int* __restrict__ deg, const int* __restrict__ bsum,
    int* __restrict__ rowstart, int* __restrict__ cursor,
    float* __restrict__ dinv, int n, int e) {
  const int z = blockIdx.z;
  const int* d = deg + (size_t)z * n;
  const int* bs = bsum + z * 64;
  int* rs = rowstart + (size_t)z * (n + 1);
  int* cu = cursor + (size_t)z * n;
  float* dv = dinv + (size_t)z * n;
  __shared__ int ts[256];
  const int tid = threadIdx.x;
  const int i0 = blockIdx.x * 1024 + tid * 4;
  int v[4];
  int s = 0;
#pragma unroll
  for (int j = 0; j < 4; ++j) {
    int i = i0 + j;
    v[j] = (i < n) ? d[i] : 0;
    s += v[j];
  }
  ts[tid] = s;
  __syncthreads();
  for (int off = 1; off < 256; off <<= 1) {
    int t = (tid >= off) ? ts[tid - off] : 0;
    __syncthreads();
    ts[tid] += t;
    __syncthreads();
  }
  int run = bs[blockIdx.x] + ts[tid] - s;
#pragma unroll
  for (int j = 0; j < 4; ++j) {
    int i = i0 + j;
    if (i < n) {
      rs[i] = run;
      cu[i] = run;
      dv[i] = rsqrtf((float)(v[j] + 1));
    }
    run += v[j];
  }
  if (blockIdx.x == 0 && tid == 0) rs[n] = e;
}

// fill: dst-sorted src list, pass-partitioned by dst range for locality
// grid(x = edge blocks, y = NPASS, z = tower)
__global__ __launch_bounds__(256) void fill4_k(
    const int* __restrict__ ei0, const int* __restrict__ ei1,
    int* __restrict__ cursor, int* __restrict__ esrc, int e, int n) {
  const int z = blockIdx.z;
  const int pass = blockIdx.y;
  const int* src = z ? ei1 : ei0;
  const int* dst = src + e;
  int* cu = cursor + (size_t)z * n;
  int* es = esrc + (size_t)z * e;
  const int nq = (n + NPASS - 1) / NPASS;
  int i = blockIdx.x * 256 + threadIdx.x;
  if (i >= e) return;
  int d = dst[i];
  if (d / nq != pass) return;
  int pos = atomicAdd(&cu[d], 1);
  es[pos] = src[i];
}

// ---------------- gather (f16 rows, dinv-folded), z = tower ----------------
// 16 threads per node, f16x8 (16B) per thread (128 feat).
// out[v] = relu(dinv[v]*(xws[v] + sum_in xws[src]) + bias)
__global__ __launch_bounds__(256) void gather16_k(
    const int* __restrict__ rowstart, const int* __restrict__ esrc,
    const f16* __restrict__ xw16, const float* __restrict__ dinv,
    const float* __restrict__ bias, float* __restrict__ out0,
    float* __restrict__ out1, int n, int e) {
  const int z = blockIdx.z;
  const int* rs = rowstart + (size_t)z * (n + 1);
  const int* es = esrc + (size_t)z * e;
  const f16x8* x8 = (const f16x8*)(xw16 + (size_t)z * n * 128);
  const float* dv = dinv + (size_t)z * n;
  float* out = z ? out1 : out0;
  int gid = blockIdx.x * 256 + threadIdx.x;
  int v = gid >> 4;
  if (v >= n) return;
  int q = gid & 15;
  f16x8 sv = x8[(size_t)v * 16 + q];
  float acc[8];
#pragma unroll
  for (int j = 0; j < 8; ++j) acc[j] = (float)sv[j];
  int s0 = rs[v], s1 = rs[v + 1];
  for (int ed = s0; ed < s1; ++ed) {
    int s = es[ed];
    f16x8 t = x8[(size_t)s * 16 + q];
#pragma unroll
    for (int j = 0; j < 8; ++j) acc[j] += (float)t[j];
  }
  float d = dv[v];
  float4 b0 = *(const float4*)(bias + q * 8);
  float4 b1 = *(const float4*)(bias + q * 8 + 4);
  float4 o0, o1;
  o0.x = fmaxf(acc[0] * d + b0.x, 0.f);
  o0.y = fmaxf(acc[1] * d + b0.y, 0.f);
  o0.z = fmaxf(acc[2] * d + b0.z, 0.f);
  o0.w = fmaxf(acc[3] * d + b0.w, 0.f);
  o1.x = fmaxf(acc[4] * d + b1.x, 0.f);
  o1.y = fmaxf(acc[5] * d + b1.y, 0.f);
  o1.z = fmaxf(acc[6] * d + b1.z, 0.f);
  o1.w = fmaxf(acc[7] * d + b1.w, 0.f);
  *(float4*)(out + (size_t)v * 128 + q * 8) = o0;
  *(float4*)(out + (size_t)v * 128 + q * 8 + 4) = o1;
}

// ---------------- pool: segmented mean, z = tower --------------------------
__global__ __launch_bounds__(256) void bstart_k(const int* __restrict__ b0,
                                                const int* __restrict__ b1,
                                                int* __restrict__ bstart,
                                                int n, int nb) {
  const int z = blockIdx.z;
  const int* batch = z ? b1 : b0;
  int* bst = bstart + (size_t)z * (nb + 1);
  int b = blockIdx.x * 256 + threadIdx.x;
  if (b > nb) return;
  int lo = 0, hi = n;
  while (lo < hi) {
    int mid = (lo + hi) >> 1;
    if (batch[mid] < b) lo = mid + 1; else hi = mid;
  }
  bst[b] = lo;
}

__global__ __launch_bounds__(128) void pool_seg_k(
    const float* __restrict__ h0, const float* __restrict__ h1,
    const int* __restrict__ bstart, float* __restrict__ cat, int nb) {
  const int z = blockIdx.z;
  const float* h = z ? h1 : h0;
  const int* bst = bstart + (size_t)z * (nb + 1);
  int b = blockIdx.x;
  int s = bst[b], e = bst[b + 1];
  int f = threadIdx.x;
  float acc = 0.f;
  for (int v = s; v < e; ++v) acc += h[(size_t)v * 128 + f];
  float c = fmaxf((float)(e - s), 1.f);
  cat[(size_t)b * 256 + z * 128 + f] = acc / c;
}

// ---------------- final: out[r] = z2[r,:]@W5 + b5 --------------------------
__global__ __launch_bounds__(256) void final_k(const float* __restrict__ z2,
                                               const float* __restrict__ W5,
                                               const float* __restrict__ b5,
                                               float* __restrict__ out,
                                               int rows) {
  int r = blockIdx.x * 256 + threadIdx.x;
  if (r >= rows) return;
  float acc = b5[0];
#pragma unroll
  for (int k = 0; k < 128; ++k) acc += z2[(size_t)r * 128 + k] * W5[k];
  out[r] = acc;
}

// ---------------------------------------------------------------------------
extern "C" void kernel_launch(void* const* d_in, const int* in_sizes, int n_in,
                              void* d_out, int out_size, void* d_ws,
                              size_t ws_size, hipStream_t stream) {
  const float* x0 = (const float*)d_in[0];
  const float* x1 = (const float*)d_in[3];
  const int* ei0 = (const int*)d_in[1];
  const int* ei1 = (const int*)d_in[4];
  const int* ba0 = (const int*)d_in[2];
  const int* ba1 = (const int*)d_in[5];
  const float* gamma = (const float*)d_in[6];
  const float* beta = (const float*)d_in[7];
  const float* W1 = (const float*)d_in[8];
  const float* b1 = (const float*)d_in[9];
  const float* W2 = (const float*)d_in[10];
  const float* b2 = (const float*)d_in[11];
  const float* Wc[3] = {(const float*)d_in[12], (const float*)d_in[14],
                        (const float*)d_in[16]};
  const float* bc[3] = {(const float*)d_in[13], (const float*)d_in[15],
                        (const float*)d_in[17]};
  const float* W3 = (const float*)d_in[18];
  const float* b3 = (const float*)d_in[19];
  const float* W4 = (const float*)d_in[20];
  const float* b4 = (const float*)d_in[21];
  const float* W5 = (const float*)d_in[22];
  const float* b5 = (const float*)d_in[23];
  float* out = (float*)d_out;

  const int N = in_sizes[0] / 64;  // 50000
  const int E = in_sizes[1] / 2;   // 600000
  const int B = out_size;          // 512

  // ---- workspace layout (both towers resident) ----
  float* ws = (float*)d_ws;
  float* bufA = ws;                              // 2 * N*256 (h0; conv D reuse)
  float* bufB = bufA + (size_t)2 * N * 256;      // 2 * N*128 (h1 / conv B)
  f16* xw16 = (f16*)(bufB + (size_t)2 * N * 128);  // 2 * N*128 f16
  float* dinv = (float*)(xw16 + (size_t)2 * N * 128);  // 2*N
  int* esrc = (int*)(dinv + (size_t)2 * N);      // 2*E
  int* degc = esrc + (size_t)2 * E;              // 2*N (contig for one memset)
  int* rowstart = degc + (size_t)2 * N;          // 2*(N+1)
  int* cursor = rowstart + (size_t)2 * (N + 1);  // 2*N
  int* bsum = cursor + (size_t)2 * N;            // 2*64
  int* bstart = bsum + 128;                      // 2*(B+1)
  float* bnsum = (float*)(bstart + 2 * (B + 1)); // 128 (+128 bnsq contig)
  float* bnsq = bnsum + 128;
  float* W1f = bnsq + 128;                       // 2*16384
  float* b1f = W1f + 2 * 16384;                  // 2*256
  float* catb = b1f + 512;                       // B*256
  float* z1 = catb + (size_t)B * 256;            // B*256
  float* z2 = z1 + (size_t)B * 256;              // B*128
  f16* wtp = (f16*)(((uintptr_t)(z2 + (size_t)B * 128) + 63) &
                    ~(uintptr_t)63);
  f16* w1t_h = wtp; wtp += 2 * 16384;  // per tower [256][64]
  f16* w1t_l = wtp; wtp += 2 * 16384;
  f16* w2t_h = wtp; wtp += 32768;      // [128][256]
  f16* w2t_l = wtp; wtp += 32768;
  f16* wct_h[3]; f16* wct_l[3];
  for (int c = 0; c < 3; ++c) {
    wct_h[c] = wtp; wtp += 16384;      // [128][128]
    wct_l[c] = wtp; wtp += 16384;
  }
  f16* w3t_h = wtp; wtp += 65536;      // [256][256]
  f16* w3t_l = wtp; wtp += 65536;
  f16* w4t_h = wtp; wtp += 32768;      // [128][256]
  f16* w4t_l = wtp; wtp += 32768;
  size_t need = (size_t)((char*)wtp - (char*)d_ws);
  if (ws_size < need) return;  // workspace too small -> fail loudly

  // per-tower derived pointers
  float* h0_[2] = {bufA, bufA + (size_t)N * 256};
  float* hB_[2] = {bufB, bufB + (size_t)N * 128};
  float* hD_[2] = {bufA, bufA + (size_t)N * 256};  // reuse h0 area (N*128)
  f16* xw_[2] = {xw16, xw16 + (size_t)N * 128};

  const int nb_e = (E + 255) / 256;
  const int nb_scan = (N + 1023) / 1024;
  const int nb_g16 = (N * 16 + 255) / 256;
  const int gby = (N + 63) / 64;  // 782

  // ---- zero accumulators (one memset each, both towers) ----
  hipMemsetAsync(degc, 0, (size_t)2 * N * sizeof(int), stream);
  hipMemsetAsync(bnsum, 0, 256 * sizeof(float), stream);

  // ---- shared weights: transpose+split once ----
  wtrans_k<<<dim3(2, 64, 1), 256, 0, stream>>>(W2, 0, w2t_h, w2t_l, 0, 256,
                                               128);
  for (int c = 0; c < 3; ++c)
    wtrans_k<<<dim3(2, 32, 1), 256, 0, stream>>>(Wc[c], 0, wct_h[c], wct_l[c],
                                                 0, 128, 128);
  wtrans_k<<<dim3(4, 64, 1), 256, 0, stream>>>(W3, 0, w3t_h, w3t_l, 0, 256,
                                               256);
  wtrans_k<<<dim3(2, 64, 1), 256, 0, stream>>>(W4, 0, w4t_h, w4t_l, 0, 256,
                                               128);

  // ---- BN -> folded W1 (per tower) ----
  bn_stats_k<<<dim3(256, 1, 2), 256, 0, stream>>>(x0, x1, bnsum, bnsq, N);
  bn_fold_k<<<2, 256, 0, stream>>>(bnsum, bnsq, gamma, beta, W1, b1, W1f, b1f,
                                   1.0f / (float)N);
  wtrans_k<<<dim3(4, 16, 2), 256, 0, stream>>>(W1f, 16384, w1t_h, w1t_l,
                                               16384, 64, 256);

  // ---- dense head of each tower ----
  gemm_mfma<<<dim3(2, gby, 2), 256, 0, stream>>>(
      x0, x1, w1t_h, w1t_h + 16384, w1t_l, w1t_l + 16384, b1f, b1f + 256,
      h0_[0], h0_[1], N, 256, 64, 1);
  gemm_mfma<<<dim3(1, gby, 2), 256, 0, stream>>>(
      h0_[0], h0_[1], w2t_h, w2t_h, w2t_l, w2t_l, b2, b2, hB_[0], hB_[1], N,
      128, 256, 1);

  // ---- CSR build (per tower in one dispatch) ----
  count_deg_k<<<dim3(nb_e, 1, 2), 256, 0, stream>>>(ei0, ei1, degc, E, N);
  scan1_k<<<dim3(nb_scan, 1, 2), 256, 0, stream>>>(degc, bsum, N);
  scan2_k<<<dim3(1, 1, 2), 64, 0, stream>>>(bsum, nb_scan);
  scan3_k<<<dim3(nb_scan, 1, 2), 256, 0, stream>>>(degc, bsum, rowstart,
                                                   cursor, dinv, N, E);
  fill4_k<<<dim3(nb_e, NPASS, 2), 256, 0, stream>>>(ei0, ei1, cursor, esrc, E,
                                                    N);
  bstart_k<<<dim3((B + 256) / 256, 1, 2), 256, 0, stream>>>(ba0, ba1, bstart,
                                                            N, B);

  // ---- 3 conv layers: GEMM(f16 out, dinv-scaled) + gather ----
  // chain: hB -> (c0) hD -> (c1) hB -> (c2) hD
  float* cin[3][2] = {{hB_[0], hB_[1]}, {hD_[0], hD_[1]}, {hB_[0], hB_[1]}};
  float* cout[3][2] = {{hD_[0], hD_[1]}, {hB_[0], hB_[1]}, {hD_[0], hD_[1]}};
  for (int c = 0; c < 3; ++c) {
    gemm_mfma_f16o<<<dim3(1, gby, 2), 256, 0, stream>>>(
        cin[c][0], cin[c][1], wct_h[c], wct_l[c], dinv, xw_[0], xw_[1], N, 128,
        128);
    gather16_k<<<dim3(nb_g16, 1, 2), 256, 0, stream>>>(
        rowstart, esrc, xw16, dinv, bc[c], cout[c][0], cout[c][1], N, E);
  }

  // ---- pool (both towers) ----
  pool_seg_k<<<dim3(B, 1, 2), 128, 0, stream>>>(hD_[0], hD_[1], bstart, catb,
                                                B);

  // ---- head MLP ----
  gemm_mfma<<<dim3(2, (B + 63) / 64, 1), 256, 0, stream>>>(
      catb, catb, w3t_h, w3t_h, w3t_l, w3t_l, b3, b3, z1, z1, B, 256, 256, 1);
  gemm_mfma<<<dim3(1, (B + 63) / 64, 1), 256, 0, stream>>>(
      z1, z1, w4t_h, w4t_h, w4t_l, w4t_l, b4, b4, z2, z2, B, 128, 256, 1);
  final_k<<<(B + 255) / 256, 256, 0, stream>>>(z2, W5, b5, out, B);
}

// Round 10
// 523.494 us; speedup vs baseline: 2.3745x; 1.0476x over previous
//
#include <hip/hip_runtime.h>
#include <cstdint>

// ---------------------------------------------------------------------------
// GCN twin-tower forward. Round 10:
//   - fill: XCD-aligned dst-region partition (region = blockIdx.x & 7 ->
//     all writes to a region come from one XCD; kills line false sharing)
//     + ushort edge payload (N < 65536).
//   - f16 activation chain: h0/h/xw stored f16. A-f16 GEMMs use 2 MFMAs
//     (al == 0 exactly), halved A traffic, no split conversion in staging.
//   - gather writes f16, pool reads f16.
// ---------------------------------------------------------------------------

typedef _Float16 f16;
typedef f16 f16x8 __attribute__((ext_vector_type(8)));
typedef f16 f16x4 __attribute__((ext_vector_type(4)));
typedef float f32x4 __attribute__((ext_vector_type(4)));
typedef unsigned short u16;

// ---------------- BN stats: per-feature sum / sumsq, z = tower -------------
__global__ __launch_bounds__(256) void bn_stats_k(
    const float* __restrict__ x0, const float* __restrict__ x1,
    float* __restrict__ bnsum, float* __restrict__ bnsq, int n) {
  const float* x = blockIdx.z ? x1 : x0;
  float* bs = bnsum + blockIdx.z * 64;
  float* bq = bnsq + blockIdx.z * 64;
  __shared__ float ls[256], lq[256];
  const int tid = threadIdx.x;
  const int f = tid & 63;
  const int rb = tid >> 6;
  float s = 0.f, q = 0.f;
  for (int r = blockIdx.x * 4 + rb; r < n; r += gridDim.x * 4) {
    float v = x[(size_t)r * 64 + f];
    s += v;
    q += v * v;
  }
  ls[tid] = s;
  lq[tid] = q;
  __syncthreads();
  if (tid < 64) {
    s = ls[tid] + ls[tid + 64] + ls[tid + 128] + ls[tid + 192];
    q = lq[tid] + lq[tid + 64] + lq[tid + 128] + lq[tid + 192];
    atomicAdd(&bs[tid], s);
    atomicAdd(&bq[tid], q);
  }
}

// ------------- Fold BN affine into W1/b1, grid(2): x = tower ---------------
__global__ __launch_bounds__(256) void bn_fold_k(
    const float* __restrict__ bnsum, const float* __restrict__ bnsq,
    const float* __restrict__ gamma, const float* __restrict__ beta,
    const float* __restrict__ W1, const float* __restrict__ b1,
    float* __restrict__ W1f, float* __restrict__ b1f, float inv_n) {
  const int z = blockIdx.x;
  const float* bs = bnsum + z * 64;
  const float* bq = bnsq + z * 64;
  float* w1f = W1f + z * 16384;
  float* bf1 = b1f + z * 256;
  __shared__ float a[64], bf[64];
  const int tid = threadIdx.x;
  if (tid < 64) {
    float mu = bs[tid] * inv_n;
    float var = bq[tid] * inv_n - mu * mu;
    float s = gamma[tid] * rsqrtf(var + 1e-5f);
    a[tid] = s;
    bf[tid] = beta[tid] - mu * s;
  }
  __syncthreads();
  float acc = 0.f;
#pragma unroll
  for (int f = 0; f < 64; ++f) {
    float w = W1[f * 256 + tid];
    w1f[f * 256 + tid] = a[f] * w;
    acc += bf[f] * w;
  }
  bf1[tid] = b1[tid] + acc;
}

// ---- transpose + fp16-split: W[K][N] f32 -> Wt[N][K] f16, z-strided -------
__global__ __launch_bounds__(256) void wtrans_k(
    const float* __restrict__ W, int sstride, f16* __restrict__ Wth,
    f16* __restrict__ Wtl, int dstride, int K, int N) {
  const int z = blockIdx.z;
  const float* Wp = W + (size_t)z * sstride;
  f16* th = Wth + (size_t)z * dstride;
  f16* tl = Wtl + (size_t)z * dstride;
  int n = blockIdx.x * 64 + (threadIdx.x & 63);
  int k = blockIdx.y * 4 + (threadIdx.x >> 6);
  float v = Wp[(size_t)k * N + n];
  f16 h = (f16)v;
  f16 l = (f16)(v - (float)h);
  th[(size_t)n * K + k] = h;
  tl[(size_t)n * K + k] = l;
}

// ---------------- MFMA GEMM core ------------------------------------------
// A [M,K] row-major (f32 if !AF16, f16 if AF16); B = Wth/Wtl [N][K] f16.
// Tile 64(m) x 128(n), BK=32, 256 threads = 4 waves (2m x 2n), K%32==0.
// AF16: al==0 exactly -> 2 MFMAs. OUT16: f16 out, optional rowscale.
template <int AF16, int OUT16>
__device__ __forceinline__ void gemm_core(
    const void* __restrict__ Av, const f16* __restrict__ Wth,
    const f16* __restrict__ Wtl, const float* __restrict__ bias,
    const float* __restrict__ rowscale, float* __restrict__ C,
    f16* __restrict__ C16, int M, int N, int K, int relu) {
  __shared__ f16 Ah[64][40];
  __shared__ f16 Al[AF16 ? 1 : 64][40];  // elided when AF16
  __shared__ f16 Bh[128][40], Bl[128][40];
  const int tid = threadIdx.x;
  const int wave = tid >> 6;
  const int lane = tid & 63;
  const int wm = wave & 1;
  const int wn = wave >> 1;
  const int l15 = lane & 15;
  const int lk8 = (lane >> 4) * 8;
  const int sam = tid >> 2;
  const int sak = (tid & 3) * 8;
  const int sbn = tid >> 1;
  const int sbk = (tid & 1) * 16;
  const int arow = blockIdx.y * 64 + sam;
  const f16* bhp = Wth + (size_t)(blockIdx.x * 128 + sbn) * K + sbk;
  const f16* blp = Wtl + (size_t)(blockIdx.x * 128 + sbn) * K + sbk;
  const float* aptr32 = nullptr;
  const f16* aptr16 = nullptr;
  if constexpr (AF16)
    aptr16 = (const f16*)Av + (size_t)arow * K + sak;
  else
    aptr32 = (const float*)Av + (size_t)arow * K + sak;

  f32x4 acc[2][4];
#pragma unroll
  for (int mi = 0; mi < 2; ++mi)
#pragma unroll
    for (int ni = 0; ni < 4; ++ni) acc[mi][ni] = (f32x4){0.f, 0.f, 0.f, 0.f};

  float4 pa0, pa1;
  f16x8 pa16 = {0, 0, 0, 0, 0, 0, 0, 0};
  if constexpr (AF16) {
    if (arow < M) pa16 = *(const f16x8*)aptr16;
  } else {
    if (arow < M) {
      pa0 = *(const float4*)aptr32;
      pa1 = *(const float4*)(aptr32 + 4);
    } else {
      pa0 = make_float4(0.f, 0.f, 0.f, 0.f);
      pa1 = pa0;
    }
  }
  f16x8 pbh0 = *(const f16x8*)bhp;
  f16x8 pbh1 = *(const f16x8*)(bhp + 8);
  f16x8 pbl0 = *(const f16x8*)blp;
  f16x8 pbl1 = *(const f16x8*)(blp + 8);

  const int nk = K / 32;
  for (int t = 0; t < nk; ++t) {
    if (t) __syncthreads();
    if constexpr (AF16) {
      *(f16x8*)&Ah[sam][sak] = pa16;
    } else {
      float av[8] = {pa0.x, pa0.y, pa0.z, pa0.w, pa1.x, pa1.y, pa1.z, pa1.w};
      f16x8 vh, vl;
#pragma unroll
      for (int j = 0; j < 8; ++j) {
        f16 h = (f16)av[j];
        vh[j] = h;
        vl[j] = (f16)(av[j] - (float)h);
      }
      *(f16x8*)&Ah[sam][sak] = vh;
      *(f16x8*)&Al[sam][sak] = vl;
    }
    *(f16x8*)&Bh[sbn][sbk] = pbh0;
    *(f16x8*)&Bh[sbn][sbk + 8] = pbh1;
    *(f16x8*)&Bl[sbn][sbk] = pbl0;
    *(f16x8*)&Bl[sbn][sbk + 8] = pbl1;
    __syncthreads();
    if (t + 1 < nk) {
      const int k0 = (t + 1) * 32;
      if constexpr (AF16) {
        if (arow < M) pa16 = *(const f16x8*)(aptr16 + k0);
      } else {
        if (arow < M) {
          pa0 = *(const float4*)(aptr32 + k0);
          pa1 = *(const float4*)(aptr32 + k0 + 4);
        } else {
          pa0 = make_float4(0.f, 0.f, 0.f, 0.f);
          pa1 = pa0;
        }
      }
      pbh0 = *(const f16x8*)(bhp + k0);
      pbh1 = *(const f16x8*)(bhp + k0 + 8);
      pbl0 = *(const f16x8*)(blp + k0);
      pbl1 = *(const f16x8*)(blp + k0 + 8);
    }
    f16x8 ath[2], atl[2];
#pragma unroll
    for (int mi = 0; mi < 2; ++mi) {
      const int r = wm * 32 + mi * 16 + l15;
      ath[mi] = *(const f16x8*)&Ah[r][lk8];
      if constexpr (!AF16) atl[mi] = *(const f16x8*)&Al[r][lk8];
    }
    f16x8 bth[4], btl[4];
#pragma unroll
    for (int ni = 0; ni < 4; ++ni) {
      const int r = wn * 64 + ni * 16 + l15;
      bth[ni] = *(const f16x8*)&Bh[r][lk8];
      btl[ni] = *(const f16x8*)&Bl[r][lk8];
    }
#pragma unroll
    for (int mi = 0; mi < 2; ++mi)
#pragma unroll
      for (int ni = 0; ni < 4; ++ni) {
        acc[mi][ni] = __builtin_amdgcn_mfma_f32_16x16x32_f16(
            bth[ni], ath[mi], acc[mi][ni], 0, 0, 0);
        acc[mi][ni] = __builtin_amdgcn_mfma_f32_16x16x32_f16(
            btl[ni], ath[mi], acc[mi][ni], 0, 0, 0);
        if constexpr (!AF16)
          acc[mi][ni] = __builtin_amdgcn_mfma_f32_16x16x32_f16(
              bth[ni], atl[mi], acc[mi][ni], 0, 0, 0);
      }
  }

#pragma unroll
  for (int mi = 0; mi < 2; ++mi) {
    const int m = blockIdx.y * 64 + wm * 32 + mi * 16 + l15;
    if (m >= M) continue;
    float s = 1.f;
    if (OUT16 && rowscale) s = rowscale[m];
#pragma unroll
    for (int ni = 0; ni < 4; ++ni) {
      const int nb = blockIdx.x * 128 + wn * 64 + ni * 16 + (lane >> 4) * 4;
      float bv[4] = {0.f, 0.f, 0.f, 0.f};
      if (bias) {
        float4 b4 = *(const float4*)(bias + nb);
        bv[0] = b4.x; bv[1] = b4.y; bv[2] = b4.z; bv[3] = b4.w;
      }
      if constexpr (OUT16) {
        f16x4 h;
#pragma unroll
        for (int j = 0; j < 4; ++j) {
          float vj = acc[mi][ni][j] * s + bv[j];
          if (relu) vj = fmaxf(vj, 0.f);
          h[j] = (f16)vj;
        }
        *(f16x4*)(C16 + (size_t)m * N + nb) = h;
      } else {
        float4 v;
        v.x = acc[mi][ni][0] + bv[0];
        v.y = acc[mi][ni][1] + bv[1];
        v.z = acc[mi][ni][2] + bv[2];
        v.w = acc[mi][ni][3] + bv[3];
        if (relu) {
          v.x = fmaxf(v.x, 0.f);
          v.y = fmaxf(v.y, 0.f);
          v.z = fmaxf(v.z, 0.f);
          v.w = fmaxf(v.w, 0.f);
        }
        *(float4*)(C + (size_t)m * N + nb) = v;
      }
    }
  }
}

// GEMM1: A f32 (per-tower W/bias), f16 out
__global__ __launch_bounds__(256) void gemm_a32_f16o(
    const float* __restrict__ A0, const float* __restrict__ A1,
    const f16* __restrict__ Wth0, const f16* __restrict__ Wth1,
    const f16* __restrict__ Wtl0, const f16* __restrict__ Wtl1,
    const float* __restrict__ bias0, const float* __restrict__ bias1,
    f16* __restrict__ C0, f16* __restrict__ C1, int M, int N, int K,
    int relu) {
  const int z = blockIdx.z;
  gemm_core<0, 1>(z ? A1 : A0, z ? Wth1 : Wth0, z ? Wtl1 : Wtl0,
                  z ? bias1 : bias0, nullptr, nullptr, z ? C1 : C0, M, N, K,
                  relu);
}

// GEMM2/conv: A f16 (shared W), f16 out, optional bias / rowscale(dinv)
__global__ __launch_bounds__(256) void gemm_a16_f16o(
    const f16* __restrict__ A0, const f16* __restrict__ A1,
    const f16* __restrict__ Wth, const f16* __restrict__ Wtl,
    const float* __restrict__ bias, const float* __restrict__ rowscale,
    f16* __restrict__ C0, f16* __restrict__ C1, int M, int N, int K,
    int relu) {
  const int z = blockIdx.z;
  gemm_core<1, 1>(z ? A1 : A0, Wth, Wtl, bias,
                  rowscale ? rowscale + (size_t)z * M : nullptr, nullptr,
                  z ? C1 : C0, M, N, K, relu);
}

// head: A f32, f32 out
__global__ __launch_bounds__(256) void gemm_a32_f32o(
    const float* __restrict__ A, const f16* __restrict__ Wth,
    const f16* __restrict__ Wtl, const float* __restrict__ bias,
    float* __restrict__ C, int M, int N, int K, int relu) {
  gemm_core<0, 0>(A, Wth, Wtl, bias, nullptr, C, nullptr, M, N, K, relu);
}

// ---------------- degree count, z = tower ----------------------------------
__global__ __launch_bounds__(256) void count_deg_k(
    const int* __restrict__ ei0, const int* __restrict__ ei1,
    int* __restrict__ cnt, int e, int n) {
  const int z = blockIdx.z;
  const int* dst = (z ? ei1 : ei0) + e;
  int* c = cnt + (size_t)z * n;
  int i = blockIdx.x * 256 + threadIdx.x;
  if (i < e) atomicAdd(&c[dst[i]], 1);
}

// ---------------- CSR build scans, z = tower -------------------------------
__global__ __launch_bounds__(256) void scan1_k(const int* __restrict__ deg,
                                               int* __restrict__ bsum, int n) {
  const int z = blockIdx.z;
  const int* d = deg + (size_t)z * n;
  int* bs = bsum + z * 64;
  __shared__ int ls[256];
  const int base = blockIdx.x * 1024;
  int s = 0;
  for (int j = threadIdx.x; j < 1024; j += 256) {
    int i = base + j;
    s += (i < n) ? d[i] : 0;
  }
  ls[threadIdx.x] = s;
  __syncthreads();
  for (int off = 128; off > 0; off >>= 1) {
    if (threadIdx.x < off) ls[threadIdx.x] += ls[threadIdx.x + off];
    __syncthreads();
  }
  if (threadIdx.x == 0) bs[blockIdx.x] = ls[0];
}

__global__ void scan2_k(int* __restrict__ bsum, int nb) {
  int* bs = bsum + blockIdx.z * 64;
  if (threadIdx.x == 0) {
    int acc = 0;
    for (int i = 0; i < nb; ++i) {
      int v = bs[i];
      bs[i] = acc;
      acc += v;
    }
  }
}

// scan3: rowstart + cursor + dinv (folded)
__global__ __launch_bounds__(256) void scan3_k(
    const int* __restrict__ deg, const int* __restrict__ bsum,
    int* __restrict__ rowstart, int* __restrict__ cursor,
    float* __restrict__ dinv, int n, int e) {
  const int z = blockIdx.z;
  const int* d = deg + (size_t)z * n;
  const int* bs = bsum + z * 64;
  int* rs = rowstart + (size_t)z * (n + 1);
  int* cu = cursor + (size_t)z * n;
  float* dv = dinv + (size_t)z * n;
  __shared__ int ts[256];
  const int tid = threadIdx.x;
  const int i0 = blockIdx.x * 1024 + tid * 4;
  int v[4];
  int s = 0;
#pragma unroll
  for (int j = 0; j < 4; ++j) {
    int i = i0 + j;
    v[j] = (i < n) ? d[i] : 0;
    s += v[j];
  }
  ts[tid] = s;
  __syncthreads();
  for (int off = 1; off < 256; off <<= 1) {
    int t = (tid >= off) ? ts[tid - off] : 0;
    __syncthreads();
    ts[tid] += t;
    __syncthreads();
  }
  int run = bs[blockIdx.x] + ts[tid] - s;
#pragma unroll
  for (int j = 0; j < 4; ++j) {
    int i = i0 + j;
    if (i < n) {
      rs[i] = run;
      cu[i] = run;
      dv[i] = rsqrtf((float)(v[j] + 1));
    }
    run += v[j];
  }
  if (blockIdx.x == 0 && tid == 0) rs[n] = e;
}

// fill: XCD-aligned region partition. region = blockIdx.x & 7 so each dst
// region's writes are issued from one XCD (blockIdx -> XCD is % 8
// round-robin) -> esrc lines assemble in a single L2, no false sharing.
__global__ __launch_bounds__(256) void fill8_k(
    const int* __restrict__ ei0, const int* __restrict__ ei1,
    int* __restrict__ cursor, u16* __restrict__ esrc, int e, int n) {
  const int z = blockIdx.z;
  const int region = blockIdx.x & 7;
  const int chunk = blockIdx.x >> 3;
  const int* src = z ? ei1 : ei0;
  const int* dst = src + e;
  int* cu = cursor + (size_t)z * n;
  u16* es = esrc + (size_t)z * e;
  const int nq = (n + 7) / 8;
  int i = chunk * 256 + threadIdx.x;
  if (i >= e) return;
  int d = dst[i];
  if (d / nq != region) return;
  int pos = atomicAdd(&cu[d], 1);
  es[pos] = (u16)src[i];
}

// ---------------- gather (f16 rows, dinv-folded), z = tower ----------------
// 16 threads per node, f16x8 (16B) per thread (128 feat). f16 output.
// out[v] = relu(dinv[v]*(xws[v] + sum_in xws[src]) + bias)
__global__ __launch_bounds__(256) void gather16_k(
    const int* __restrict__ rowstart, const u16* __restrict__ esrc,
    const f16* __restrict__ xw16, const float* __restrict__ dinv,
    const float* __restrict__ bias, f16* __restrict__ out0,
    f16* __restrict__ out1, int n, int e) {
  const int z = blockIdx.z;
  const int* rs = rowstart + (size_t)z * (n + 1);
  const u16* es = esrc + (size_t)z * e;
  const f16x8* x8 = (const f16x8*)(xw16 + (size_t)z * n * 128);
  const float* dv = dinv + (size_t)z * n;
  f16* out = z ? out1 : out0;
  int gid = blockIdx.x * 256 + threadIdx.x;
  int v = gid >> 4;
  if (v >= n) return;
  int q = gid & 15;
  f16x8 sv = x8[(size_t)v * 16 + q];
  float acc[8];
#pragma unroll
  for (int j = 0; j < 8; ++j) acc[j] = (float)sv[j];
  int s0 = rs[v], s1 = rs[v + 1];
  for (int ed = s0; ed < s1; ++ed) {
    int s = es[ed];
    f16x8 t = x8[(size_t)s * 16 + q];
#pragma unroll
    for (int j = 0; j < 8; ++j) acc[j] += (float)t[j];
  }
  float d = dv[v];
  float4 b0 = *(const float4*)(bias + q * 8);
  float4 b1 = *(const float4*)(bias + q * 8 + 4);
  float bb[8] = {b0.x, b0.y, b0.z, b0.w, b1.x, b1.y, b1.z, b1.w};
  f16x8 o;
#pragma unroll
  for (int j = 0; j < 8; ++j) o[j] = (f16)fmaxf(acc[j] * d + bb[j], 0.f);
  *(f16x8*)(out + (size_t)v * 128 + q * 8) = o;
}

// ---------------- pool: segmented mean (f16 in, f32 out), z = tower --------
__global__ __launch_bounds__(256) void bstart_k(const int* __restrict__ b0,
                                                const int* __restrict__ b1,
                                                int* __restrict__ bstart,
                                                int n, int nb) {
  const int z = blockIdx.z;
  const int* batch = z ? b1 : b0;
  int* bst = bstart + (size_t)z * (nb + 1);
  int b = blockIdx.x * 256 + threadIdx.x;
  if (b > nb) return;
  int lo = 0, hi = n;
  while (lo < hi) {
    int mid = (lo + hi) >> 1;
    if (batch[mid] < b) lo = mid + 1; else hi = mid;
  }
  bst[b] = lo;
}

__global__ __launch_bounds__(128) void pool_seg_k(
    const f16* __restrict__ h0, const f16* __restrict__ h1,
    const int* __restrict__ bstart, float* __restrict__ cat, int nb) {
  const int z = blockIdx.z;
  const f16* h = z ? h1 : h0;
  const int* bst = bstart + (size_t)z * (nb + 1);
  int b = blockIdx.x;
  int s = bst[b], e = bst[b + 1];
  int f = threadIdx.x;
  float acc = 0.f;
  for (int v = s; v < e; ++v) acc += (float)h[(size_t)v * 128 + f];
  float c = fmaxf((float)(e - s), 1.f);
  cat[(size_t)b * 256 + z * 128 + f] = acc / c;
}

// ---------------- final: out[r] = z2[r,:]@W5 + b5 --------------------------
__global__ __launch_bounds__(256) void final_k(const float* __restrict__ z2,
                                               const float* __restrict__ W5,
                                               const float* __restrict__ b5,
                                               float* __restrict__ out,
                                               int rows) {
  int r = blockIdx.x * 256 + threadIdx.x;
  if (r >= rows) return;
  float acc = b5[0];
#pragma unroll
  for (int k = 0; k < 128; ++k) acc += z2[(size_t)r * 128 + k] * W5[k];
  out[r] = acc;
}

// ---------------------------------------------------------------------------
extern "C" void kernel_launch(void* const* d_in, const int* in_sizes, int n_in,
                              void* d_out, int out_size, void* d_ws,
                              size_t ws_size, hipStream_t stream) {
  const float* x0 = (const float*)d_in[0];
  const float* x1 = (const float*)d_in[3];
  const int* ei0 = (const int*)d_in[1];
  const int* ei1 = (const int*)d_in[4];
  const int* ba0 = (const int*)d_in[2];
  const int* ba1 = (const int*)d_in[5];
  const float* gamma = (const float*)d_in[6];
  const float* beta = (const float*)d_in[7];
  const float* W1 = (const float*)d_in[8];
  const float* b1 = (const float*)d_in[9];
  const float* W2 = (const float*)d_in[10];
  const float* b2 = (const float*)d_in[11];
  const float* Wc[3] = {(const float*)d_in[12], (const float*)d_in[14],
                        (const float*)d_in[16]};
  const float* bc[3] = {(const float*)d_in[13], (const float*)d_in[15],
                        (const float*)d_in[17]};
  const float* W3 = (const float*)d_in[18];
  const float* b3 = (const float*)d_in[19];
  const float* W4 = (const float*)d_in[20];
  const float* b4 = (const float*)d_in[21];
  const float* W5 = (const float*)d_in[22];
  const float* b5 = (const float*)d_in[23];
  float* out = (float*)d_out;

  const int N = in_sizes[0] / 64;  // 50000
  const int E = in_sizes[1] / 2;   // 600000
  const int B = out_size;          // 512

  // ---- workspace layout (f16 activations, both towers resident) ----
  f16* fp = (f16*)d_ws;
  f16* h0_16 = fp; fp += (size_t)2 * N * 256;  // GEMM1 out
  f16* hA16 = fp; fp += (size_t)2 * N * 128;   // activation ping
  f16* hB16 = fp; fp += (size_t)2 * N * 128;   // activation pong
  f16* xw16 = fp; fp += (size_t)2 * N * 128;   // conv GEMM out (dinv-scaled)
  float* dinv = (float*)fp;                    // 2*N
  u16* esrc = (u16*)(dinv + (size_t)2 * N);    // 2*E
  int* degc = (int*)(esrc + (size_t)2 * E);    // 2*N
  int* rowstart = degc + (size_t)2 * N;        // 2*(N+1)
  int* cursor = rowstart + (size_t)2 * (N + 1);
  int* bsum = cursor + (size_t)2 * N;          // 128
  int* bstart = bsum + 128;                    // 2*(B+1)
  float* bnsum = (float*)(bstart + 2 * (B + 1));
  float* bnsq = bnsum + 128;
  float* W1f = bnsq + 128;                     // 2*16384
  float* b1f = W1f + 2 * 16384;                // 512
  float* catb = b1f + 512;                     // B*256
  float* z1 = catb + (size_t)B * 256;          // B*256
  float* z2 = z1 + (size_t)B * 256;            // B*128
  f16* wtp = (f16*)(((uintptr_t)(z2 + (size_t)B * 128) + 63) &
                    ~(uintptr_t)63);
  f16* w1t_h = wtp; wtp += 2 * 16384;
  f16* w1t_l = wtp; wtp += 2 * 16384;
  f16* w2t_h = wtp; wtp += 32768;
  f16* w2t_l = wtp; wtp += 32768;
  f16* wct_h[3]; f16* wct_l[3];
  for (int c = 0; c < 3; ++c) {
    wct_h[c] = wtp; wtp += 16384;
    wct_l[c] = wtp; wtp += 16384;
  }
  f16* w3t_h = wtp; wtp += 65536;
  f16* w3t_l = wtp; wtp += 65536;
  f16* w4t_h = wtp; wtp += 32768;
  f16* w4t_l = wtp; wtp += 32768;
  size_t need = (size_t)((char*)wtp - (char*)d_ws);
  if (ws_size < need) return;

  f16* h0_[2] = {h0_16, h0_16 + (size_t)N * 256};
  f16* hA_[2] = {hA16, hA16 + (size_t)N * 128};
  f16* hB_[2] = {hB16, hB16 + (size_t)N * 128};

  const int nb_e = (E + 255) / 256;
  const int nb_scan = (N + 1023) / 1024;
  const int nb_g16 = (N * 16 + 255) / 256;
  const int gby = (N + 63) / 64;  // 782

  hipMemsetAsync(degc, 0, (size_t)2 * N * sizeof(int), stream);
  hipMemsetAsync(bnsum, 0, 256 * sizeof(float), stream);

  // ---- shared weights: transpose+split once ----
  wtrans_k<<<dim3(2, 64, 1), 256, 0, stream>>>(W2, 0, w2t_h, w2t_l, 0, 256,
                                               128);
  for (int c = 0; c < 3; ++c)
    wtrans_k<<<dim3(2, 32, 1), 256, 0, stream>>>(Wc[c], 0, wct_h[c], wct_l[c],
                                                 0, 128, 128);
  wtrans_k<<<dim3(4, 64, 1), 256, 0, stream>>>(W3, 0, w3t_h, w3t_l, 0, 256,
                                               256);
  wtrans_k<<<dim3(2, 64, 1), 256, 0, stream>>>(W4, 0, w4t_h, w4t_l, 0, 256,
                                               128);

  // ---- BN -> folded W1 (per tower) ----
  bn_stats_k<<<dim3(256, 1, 2), 256, 0, stream>>>(x0, x1, bnsum, bnsq, N);
  bn_fold_k<<<2, 256, 0, stream>>>(bnsum, bnsq, gamma, beta, W1, b1, W1f, b1f,
                                   1.0f / (float)N);
  wtrans_k<<<dim3(4, 16, 2), 256, 0, stream>>>(W1f, 16384, w1t_h, w1t_l,
                                               16384, 64, 256);

  // ---- dense head of each tower (f16 chain) ----
  gemm_a32_f16o<<<dim3(2, gby, 2), 256, 0, stream>>>(
      x0, x1, w1t_h, w1t_h + 16384, w1t_l, w1t_l + 16384, b1f, b1f + 256,
      h0_[0], h0_[1], N, 256, 64, 1);
  gemm_a16_f16o<<<dim3(1, gby, 2), 256, 0, stream>>>(
      h0_[0], h0_[1], w2t_h, w2t_l, b2, nullptr, hA_[0], hA_[1], N, 128, 256,
      1);

  // ---- CSR build ----
  count_deg_k<<<dim3(nb_e, 1, 2), 256, 0, stream>>>(ei0, ei1, degc, E, N);
  scan1_k<<<dim3(nb_scan, 1, 2), 256, 0, stream>>>(degc, bsum, N);
  scan2_k<<<dim3(1, 1, 2), 64, 0, stream>>>(bsum, nb_scan);
  scan3_k<<<dim3(nb_scan, 1, 2), 256, 0, stream>>>(degc, bsum, rowstart,
                                                   cursor, dinv, N, E);
  fill8_k<<<dim3(nb_e * 8, 1, 2), 256, 0, stream>>>(ei0, ei1, cursor, esrc, E,
                                                    N);
  bstart_k<<<dim3((B + 256) / 256, 1, 2), 256, 0, stream>>>(ba0, ba1, bstart,
                                                            N, B);

  // ---- 3 conv layers: GEMM(f16, dinv-scaled) + gather (f16 out) ----
  // chain: hA -> (c0) hB -> (c1) hA -> (c2) hB
  f16* cin[3][2] = {{hA_[0], hA_[1]}, {hB_[0], hB_[1]}, {hA_[0], hA_[1]}};
  f16* cout[3][2] = {{hB_[0], hB_[1]}, {hA_[0], hA_[1]}, {hB_[0], hB_[1]}};
  for (int c = 0; c < 3; ++c) {
    gemm_a16_f16o<<<dim3(1, gby, 2), 256, 0, stream>>>(
        cin[c][0], cin[c][1], wct_h[c], wct_l[c], nullptr, dinv, xw16,
        xw16 + (size_t)N * 128, N, 128, 128, 0);
    gather16_k<<<dim3(nb_g16, 1, 2), 256, 0, stream>>>(
        rowstart, esrc, xw16, dinv, bc[c], cout[c][0], cout[c][1], N, E);
  }

  // ---- pool (both towers) ----
  pool_seg_k<<<dim3(B, 1, 2), 128, 0, stream>>>(hB_[0], hB_[1], bstart, catb,
                                                B);

  // ---- head MLP (f32) ----
  gemm_a32_f32o<<<dim3(2, (B + 63) / 64, 1), 256, 0, stream>>>(
      catb, w3t_h, w3t_l, b3, z1, B, 256, 256, 1);
  gemm_a32_f32o<<<dim3(1, (B + 63) / 64, 1), 256, 0, stream>>>(
      z1, w4t_h, w4t_l, b4, z2, B, 128, 256, 1);
  final_k<<<(B + 255) / 256, 256, 0, stream>>>(z2, W5, b5, out, B);
}

// Round 11
// 485.369 us; speedup vs baseline: 2.5610x; 1.0785x over previous
//
#include <hip/hip_runtime.h>
#include <cstdint>

// ---------------------------------------------------------------------------
// GCN twin-tower forward. Round 11: gather latency attack.
//   - gather edge loop unrolled x4: 4 independent row loads in flight
//     (was a 1-deep dependent chain at ~600cy L3 latency -> latency-bound,
//     VALUBusy 21%).
//   - 1D grid with XCD decode: xcd = blk & 7, tower = xcd >> 2 -> each XCD's
//     L2 serves only one tower's 12.8MB xw (was both towers from every XCD).
// Rest unchanged from round 10 (f16 chain, 2-MFMA A-f16 GEMMs, XCD fill).
// ---------------------------------------------------------------------------

typedef _Float16 f16;
typedef f16 f16x8 __attribute__((ext_vector_type(8)));
typedef f16 f16x4 __attribute__((ext_vector_type(4)));
typedef float f32x4 __attribute__((ext_vector_type(4)));
typedef unsigned short u16;

// ---------------- BN stats: per-feature sum / sumsq, z = tower -------------
__global__ __launch_bounds__(256) void bn_stats_k(
    const float* __restrict__ x0, const float* __restrict__ x1,
    float* __restrict__ bnsum, float* __restrict__ bnsq, int n) {
  const float* x = blockIdx.z ? x1 : x0;
  float* bs = bnsum + blockIdx.z * 64;
  float* bq = bnsq + blockIdx.z * 64;
  __shared__ float ls[256], lq[256];
  const int tid = threadIdx.x;
  const int f = tid & 63;
  const int rb = tid >> 6;
  float s = 0.f, q = 0.f;
  for (int r = blockIdx.x * 4 + rb; r < n; r += gridDim.x * 4) {
    float v = x[(size_t)r * 64 + f];
    s += v;
    q += v * v;
  }
  ls[tid] = s;
  lq[tid] = q;
  __syncthreads();
  if (tid < 64) {
    s = ls[tid] + ls[tid + 64] + ls[tid + 128] + ls[tid + 192];
    q = lq[tid] + lq[tid + 64] + lq[tid + 128] + lq[tid + 192];
    atomicAdd(&bs[tid], s);
    atomicAdd(&bq[tid], q);
  }
}

// ------------- Fold BN affine into W1/b1, grid(2): x = tower ---------------
__global__ __launch_bounds__(256) void bn_fold_k(
    const float* __restrict__ bnsum, const float* __restrict__ bnsq,
    const float* __restrict__ gamma, const float* __restrict__ beta,
    const float* __restrict__ W1, const float* __restrict__ b1,
    float* __restrict__ W1f, float* __restrict__ b1f, float inv_n) {
  const int z = blockIdx.x;
  const float* bs = bnsum + z * 64;
  const float* bq = bnsq + z * 64;
  float* w1f = W1f + z * 16384;
  float* bf1 = b1f + z * 256;
  __shared__ float a[64], bf[64];
  const int tid = threadIdx.x;
  if (tid < 64) {
    float mu = bs[tid] * inv_n;
    float var = bq[tid] * inv_n - mu * mu;
    float s = gamma[tid] * rsqrtf(var + 1e-5f);
    a[tid] = s;
    bf[tid] = beta[tid] - mu * s;
  }
  __syncthreads();
  float acc = 0.f;
#pragma unroll
  for (int f = 0; f < 64; ++f) {
    float w = W1[f * 256 + tid];
    w1f[f * 256 + tid] = a[f] * w;
    acc += bf[f] * w;
  }
  bf1[tid] = b1[tid] + acc;
}

// ---- transpose + fp16-split: W[K][N] f32 -> Wt[N][K] f16, z-strided -------
__global__ __launch_bounds__(256) void wtrans_k(
    const float* __restrict__ W, int sstride, f16* __restrict__ Wth,
    f16* __restrict__ Wtl, int dstride, int K, int N) {
  const int z = blockIdx.z;
  const float* Wp = W + (size_t)z * sstride;
  f16* th = Wth + (size_t)z * dstride;
  f16* tl = Wtl + (size_t)z * dstride;
  int n = blockIdx.x * 64 + (threadIdx.x & 63);
  int k = blockIdx.y * 4 + (threadIdx.x >> 6);
  float v = Wp[(size_t)k * N + n];
  f16 h = (f16)v;
  f16 l = (f16)(v - (float)h);
  th[(size_t)n * K + k] = h;
  tl[(size_t)n * K + k] = l;
}

// ---------------- MFMA GEMM core ------------------------------------------
// A [M,K] row-major (f32 if !AF16, f16 if AF16); B = Wth/Wtl [N][K] f16.
// Tile 64(m) x 128(n), BK=32, 256 threads = 4 waves (2m x 2n), K%32==0.
// AF16: al==0 exactly -> 2 MFMAs. OUT16: f16 out, optional rowscale.
template <int AF16, int OUT16>
__device__ __forceinline__ void gemm_core(
    const void* __restrict__ Av, const f16* __restrict__ Wth,
    const f16* __restrict__ Wtl, const float* __restrict__ bias,
    const float* __restrict__ rowscale, float* __restrict__ C,
    f16* __restrict__ C16, int M, int N, int K, int relu) {
  __shared__ f16 Ah[64][40];
  __shared__ f16 Al[AF16 ? 1 : 64][40];  // elided when AF16
  __shared__ f16 Bh[128][40], Bl[128][40];
  const int tid = threadIdx.x;
  const int wave = tid >> 6;
  const int lane = tid & 63;
  const int wm = wave & 1;
  const int wn = wave >> 1;
  const int l15 = lane & 15;
  const int lk8 = (lane >> 4) * 8;
  const int sam = tid >> 2;
  const int sak = (tid & 3) * 8;
  const int sbn = tid >> 1;
  const int sbk = (tid & 1) * 16;
  const int arow = blockIdx.y * 64 + sam;
  const f16* bhp = Wth + (size_t)(blockIdx.x * 128 + sbn) * K + sbk;
  const f16* blp = Wtl + (size_t)(blockIdx.x * 128 + sbn) * K + sbk;
  const float* aptr32 = nullptr;
  const f16* aptr16 = nullptr;
  if constexpr (AF16)
    aptr16 = (const f16*)Av + (size_t)arow * K + sak;
  else
    aptr32 = (const float*)Av + (size_t)arow * K + sak;

  f32x4 acc[2][4];
#pragma unroll
  for (int mi = 0; mi < 2; ++mi)
#pragma unroll
    for (int ni = 0; ni < 4; ++ni) acc[mi][ni] = (f32x4){0.f, 0.f, 0.f, 0.f};

  float4 pa0, pa1;
  f16x8 pa16 = {0, 0, 0, 0, 0, 0, 0, 0};
  if constexpr (AF16) {
    if (arow < M) pa16 = *(const f16x8*)aptr16;
  } else {
    if (arow < M) {
      pa0 = *(const float4*)aptr32;
      pa1 = *(const float4*)(aptr32 + 4);
    } else {
      pa0 = make_float4(0.f, 0.f, 0.f, 0.f);
      pa1 = pa0;
    }
  }
  f16x8 pbh0 = *(const f16x8*)bhp;
  f16x8 pbh1 = *(const f16x8*)(bhp + 8);
  f16x8 pbl0 = *(const f16x8*)blp;
  f16x8 pbl1 = *(const f16x8*)(blp + 8);

  const int nk = K / 32;
  for (int t = 0; t < nk; ++t) {
    if (t) __syncthreads();
    if constexpr (AF16) {
      *(f16x8*)&Ah[sam][sak] = pa16;
    } else {
      float av[8] = {pa0.x, pa0.y, pa0.z, pa0.w, pa1.x, pa1.y, pa1.z, pa1.w};
      f16x8 vh, vl;
#pragma unroll
      for (int j = 0; j < 8; ++j) {
        f16 h = (f16)av[j];
        vh[j] = h;
        vl[j] = (f16)(av[j] - (float)h);
      }
      *(f16x8*)&Ah[sam][sak] = vh;
      *(f16x8*)&Al[sam][sak] = vl;
    }
    *(f16x8*)&Bh[sbn][sbk] = pbh0;
    *(f16x8*)&Bh[sbn][sbk + 8] = pbh1;
    *(f16x8*)&Bl[sbn][sbk] = pbl0;
    *(f16x8*)&Bl[sbn][sbk + 8] = pbl1;
    __syncthreads();
    if (t + 1 < nk) {
      const int k0 = (t + 1) * 32;
      if constexpr (AF16) {
        if (arow < M) pa16 = *(const f16x8*)(aptr16 + k0);
      } else {
        if (arow < M) {
          pa0 = *(const float4*)(aptr32 + k0);
          pa1 = *(const float4*)(aptr32 + k0 + 4);
        } else {
          pa0 = make_float4(0.f, 0.f, 0.f, 0.f);
          pa1 = pa0;
        }
      }
      pbh0 = *(const f16x8*)(bhp + k0);
      pbh1 = *(const f16x8*)(bhp + k0 + 8);
      pbl0 = *(const f16x8*)(blp + k0);
      pbl1 = *(const f16x8*)(blp + k0 + 8);
    }
    f16x8 ath[2], atl[2];
#pragma unroll
    for (int mi = 0; mi < 2; ++mi) {
      const int r = wm * 32 + mi * 16 + l15;
      ath[mi] = *(const f16x8*)&Ah[r][lk8];
      if constexpr (!AF16) atl[mi] = *(const f16x8*)&Al[r][lk8];
    }
    f16x8 bth[4], btl[4];
#pragma unroll
    for (int ni = 0; ni < 4; ++ni) {
      const int r = wn * 64 + ni * 16 + l15;
      bth[ni] = *(const f16x8*)&Bh[r][lk8];
      btl[ni] = *(const f16x8*)&Bl[r][lk8];
    }
#pragma unroll
    for (int mi = 0; mi < 2; ++mi)
#pragma unroll
      for (int ni = 0; ni < 4; ++ni) {
        acc[mi][ni] = __builtin_amdgcn_mfma_f32_16x16x32_f16(
            bth[ni], ath[mi], acc[mi][ni], 0, 0, 0);
        acc[mi][ni] = __builtin_amdgcn_mfma_f32_16x16x32_f16(
            btl[ni], ath[mi], acc[mi][ni], 0, 0, 0);
        if constexpr (!AF16)
          acc[mi][ni] = __builtin_amdgcn_mfma_f32_16x16x32_f16(
              bth[ni], atl[mi], acc[mi][ni], 0, 0, 0);
      }
  }

#pragma unroll
  for (int mi = 0; mi < 2; ++mi) {
    const int m = blockIdx.y * 64 + wm * 32 + mi * 16 + l15;
    if (m >= M) continue;
    float s = 1.f;
    if (OUT16 && rowscale) s = rowscale[m];
#pragma unroll
    for (int ni = 0; ni < 4; ++ni) {
      const int nb = blockIdx.x * 128 + wn * 64 + ni * 16 + (lane >> 4) * 4;
      float bv[4] = {0.f, 0.f, 0.f, 0.f};
      if (bias) {
        float4 b4 = *(const float4*)(bias + nb);
        bv[0] = b4.x; bv[1] = b4.y; bv[2] = b4.z; bv[3] = b4.w;
      }
      if constexpr (OUT16) {
        f16x4 h;
#pragma unroll
        for (int j = 0; j < 4; ++j) {
          float vj = acc[mi][ni][j] * s + bv[j];
          if (relu) vj = fmaxf(vj, 0.f);
          h[j] = (f16)vj;
        }
        *(f16x4*)(C16 + (size_t)m * N + nb) = h;
      } else {
        float4 v;
        v.x = acc[mi][ni][0] + bv[0];
        v.y = acc[mi][ni][1] + bv[1];
        v.z = acc[mi][ni][2] + bv[2];
        v.w = acc[mi][ni][3] + bv[3];
        if (relu) {
          v.x = fmaxf(v.x, 0.f);
          v.y = fmaxf(v.y, 0.f);
          v.z = fmaxf(v.z, 0.f);
          v.w = fmaxf(v.w, 0.f);
        }
        *(float4*)(C + (size_t)m * N + nb) = v;
      }
    }
  }
}

// GEMM1: A f32 (per-tower W/bias), f16 out
__global__ __launch_bounds__(256) void gemm_a32_f16o(
    const float* __restrict__ A0, const float* __restrict__ A1,
    const f16* __restrict__ Wth0, const f16* __restrict__ Wth1,
    const f16* __restrict__ Wtl0, const f16* __restrict__ Wtl1,
    const float* __restrict__ bias0, const float* __restrict__ bias1,
    f16* __restrict__ C0, f16* __restrict__ C1, int M, int N, int K,
    int relu) {
  const int z = blockIdx.z;
  gemm_core<0, 1>(z ? A1 : A0, z ? Wth1 : Wth0, z ? Wtl1 : Wtl0,
                  z ? bias1 : bias0, nullptr, nullptr, z ? C1 : C0, M, N, K,
                  relu);
}

// GEMM2/conv: A f16 (shared W), f16 out, optional bias / rowscale(dinv)
__global__ __launch_bounds__(256) void gemm_a16_f16o(
    const f16* __restrict__ A0, const f16* __restrict__ A1,
    const f16* __restrict__ Wth, const f16* __restrict__ Wtl,
    const float* __restrict__ bias, const float* __restrict__ rowscale,
    f16* __restrict__ C0, f16* __restrict__ C1, int M, int N, int K,
    int relu) {
  const int z = blockIdx.z;
  gemm_core<1, 1>(z ? A1 : A0, Wth, Wtl, bias,
                  rowscale ? rowscale + (size_t)z * M : nullptr, nullptr,
                  z ? C1 : C0, M, N, K, relu);
}

// head: A f32, f32 out
__global__ __launch_bounds__(256) void gemm_a32_f32o(
    const float* __restrict__ A, const f16* __restrict__ Wth,
    const f16* __restrict__ Wtl, const float* __restrict__ bias,
    float* __restrict__ C, int M, int N, int K, int relu) {
  gemm_core<0, 0>(A, Wth, Wtl, bias, nullptr, C, nullptr, M, N, K, relu);
}

// ---------------- degree count, z = tower ----------------------------------
__global__ __launch_bounds__(256) void count_deg_k(
    const int* __restrict__ ei0, const int* __restrict__ ei1,
    int* __restrict__ cnt, int e, int n) {
  const int z = blockIdx.z;
  const int* dst = (z ? ei1 : ei0) + e;
  int* c = cnt + (size_t)z * n;
  int i = blockIdx.x * 256 + threadIdx.x;
  if (i < e) atomicAdd(&c[dst[i]], 1);
}

// ---------------- CSR build scans, z = tower -------------------------------
__global__ __launch_bounds__(256) void scan1_k(const int* __restrict__ deg,
                                               int* __restrict__ bsum, int n) {
  const int z = blockIdx.z;
  const int* d = deg + (size_t)z * n;
  int* bs = bsum + z * 64;
  __shared__ int ls[256];
  const int base = blockIdx.x * 1024;
  int s = 0;
  for (int j = threadIdx.x; j < 1024; j += 256) {
    int i = base + j;
    s += (i < n) ? d[i] : 0;
  }
  ls[threadIdx.x] = s;
  __syncthreads();
  for (int off = 128; off > 0; off >>= 1) {
    if (threadIdx.x < off) ls[threadIdx.x] += ls[threadIdx.x + off];
    __syncthreads();
  }
  if (threadIdx.x == 0) bs[blockIdx.x] = ls[0];
}

__global__ void scan2_k(int* __restrict__ bsum, int nb) {
  int* bs = bsum + blockIdx.z * 64;
  if (threadIdx.x == 0) {
    int acc = 0;
    for (int i = 0; i < nb; ++i) {
      int v = bs[i];
      bs[i] = acc;
      acc += v;
    }
  }
}

// scan3: rowstart + cursor + dinv (folded)
__global__ __launch_bounds__(256) void scan3_k(
    const int* __restrict__ deg, const int* __restrict__ bsum,
    int* __restrict__ rowstart, int* __restrict__ cursor,
    float* __restrict__ dinv, int n, int e) {
  const int z = blockIdx.z;
  const int* d = deg + (size_t)z * n;
  const int* bs = bsum + z * 64;
  int* rs = rowstart + (size_t)z * (n + 1);
  int* cu = cursor + (size_t)z * n;
  float* dv = dinv + (size_t)z * n;
  __shared__ int ts[256];
  const int tid = threadIdx.x;
  const int i0 = blockIdx.x * 1024 + tid * 4;
  int v[4];
  int s = 0;
#pragma unroll
  for (int j = 0; j < 4; ++j) {
    int i = i0 + j;
    v[j] = (i < n) ? d[i] : 0;
    s += v[j];
  }
  ts[tid] = s;
  __syncthreads();
  for (int off = 1; off < 256; off <<= 1) {
    int t = (tid >= off) ? ts[tid - off] : 0;
    __syncthreads();
    ts[tid] += t;
    __syncthreads();
  }
  int run = bs[blockIdx.x] + ts[tid] - s;
#pragma unroll
  for (int j = 0; j < 4; ++j) {
    int i = i0 + j;
    if (i < n) {
      rs[i] = run;
      cu[i] = run;
      dv[i] = rsqrtf((float)(v[j] + 1));
    }
    run += v[j];
  }
  if (blockIdx.x == 0 && tid == 0) rs[n] = e;
}

// fill: XCD-aligned region partition (region = blockIdx.x & 7) + u16 payload
__global__ __launch_bounds__(256) void fill8_k(
    const int* __restrict__ ei0, const int* __restrict__ ei1,
    int* __restrict__ cursor, u16* __restrict__ esrc, int e, int n) {
  const int z = blockIdx.z;
  const int region = blockIdx.x & 7;
  const int chunk = blockIdx.x >> 3;
  const int* src = z ? ei1 : ei0;
  const int* dst = src + e;
  int* cu = cursor + (size_t)z * n;
  u16* es = esrc + (size_t)z * e;
  const int nq = (n + 7) / 8;
  int i = chunk * 256 + threadIdx.x;
  if (i >= e) return;
  int d = dst[i];
  if (d / nq != region) return;
  int pos = atomicAdd(&cu[d], 1);
  es[pos] = (u16)src[i];
}

// ---------------- gather: x4-unrolled, XCD-tower-partitioned ---------------
// 1D grid; xcd = blk & 7, tower = xcd >> 2, 4 XCDs per tower.
// 16 threads per node, f16x8 per thread. 4 independent row loads in flight.
__global__ __launch_bounds__(256) void gather16_k(
    const int* __restrict__ rowstart, const u16* __restrict__ esrc,
    const f16* __restrict__ xw16, const float* __restrict__ dinv,
    const float* __restrict__ bias, f16* __restrict__ out0,
    f16* __restrict__ out1, int n, int e, int bpt) {
  const int blk = blockIdx.x;
  const int xcd = blk & 7;
  const int z = xcd >> 2;
  const int idx = (blk >> 3) * 4 + (xcd & 3);  // block index within tower
  if (idx >= bpt) return;
  const int* rs = rowstart + (size_t)z * (n + 1);
  const u16* es = esrc + (size_t)z * e;
  const f16x8* x8 = (const f16x8*)(xw16 + (size_t)z * n * 128);
  const float* dv = dinv + (size_t)z * n;
  f16* out = z ? out1 : out0;
  int gid = idx * 256 + threadIdx.x;
  int v = gid >> 4;
  if (v >= n) return;
  int q = gid & 15;
  f16x8 sv = x8[(size_t)v * 16 + q];
  float acc[8];
#pragma unroll
  for (int j = 0; j < 8; ++j) acc[j] = (float)sv[j];
  const int s0 = rs[v], s1 = rs[v + 1];
  int ed = s0;
  for (; ed + 4 <= s1; ed += 4) {  // 4 independent loads in flight
    int sa = es[ed], sb = es[ed + 1], sc = es[ed + 2], sd = es[ed + 3];
    f16x8 ta = x8[(size_t)sa * 16 + q];
    f16x8 tb = x8[(size_t)sb * 16 + q];
    f16x8 tc = x8[(size_t)sc * 16 + q];
    f16x8 td = x8[(size_t)sd * 16 + q];
#pragma unroll
    for (int j = 0; j < 8; ++j)
      acc[j] += ((float)ta[j] + (float)tb[j]) + ((float)tc[j] + (float)td[j]);
  }
  for (; ed < s1; ++ed) {
    f16x8 t = x8[(size_t)es[ed] * 16 + q];
#pragma unroll
    for (int j = 0; j < 8; ++j) acc[j] += (float)t[j];
  }
  float d = dv[v];
  float4 b0 = *(const float4*)(bias + q * 8);
  float4 b1 = *(const float4*)(bias + q * 8 + 4);
  float bb[8] = {b0.x, b0.y, b0.z, b0.w, b1.x, b1.y, b1.z, b1.w};
  f16x8 o;
#pragma unroll
  for (int j = 0; j < 8; ++j) o[j] = (f16)fmaxf(acc[j] * d + bb[j], 0.f);
  *(f16x8*)(out + (size_t)v * 128 + q * 8) = o;
}

// ---------------- pool: segmented mean (f16 in, f32 out), z = tower --------
__global__ __launch_bounds__(256) void bstart_k(const int* __restrict__ b0,
                                                const int* __restrict__ b1,
                                                int* __restrict__ bstart,
                                                int n, int nb) {
  const int z = blockIdx.z;
  const int* batch = z ? b1 : b0;
  int* bst = bstart + (size_t)z * (nb + 1);
  int b = blockIdx.x * 256 + threadIdx.x;
  if (b > nb) return;
  int lo = 0, hi = n;
  while (lo < hi) {
    int mid = (lo + hi) >> 1;
    if (batch[mid] < b) lo = mid + 1; else hi = mid;
  }
  bst[b] = lo;
}

__global__ __launch_bounds__(128) void pool_seg_k(
    const f16* __restrict__ h0, const f16* __restrict__ h1,
    const int* __restrict__ bstart, float* __restrict__ cat, int nb) {
  const int z = blockIdx.z;
  const f16* h = z ? h1 : h0;
  const int* bst = bstart + (size_t)z * (nb + 1);
  int b = blockIdx.x;
  int s = bst[b], e = bst[b + 1];
  int f = threadIdx.x;
  float acc = 0.f;
  for (int v = s; v < e; ++v) acc += (float)h[(size_t)v * 128 + f];
  float c = fmaxf((float)(e - s), 1.f);
  cat[(size_t)b * 256 + z * 128 + f] = acc / c;
}

// ---------------- final: out[r] = z2[r,:]@W5 + b5 --------------------------
__global__ __launch_bounds__(256) void final_k(const float* __restrict__ z2,
                                               const float* __restrict__ W5,
                                               const float* __restrict__ b5,
                                               float* __restrict__ out,
                                               int rows) {
  int r = blockIdx.x * 256 + threadIdx.x;
  if (r >= rows) return;
  float acc = b5[0];
#pragma unroll
  for (int k = 0; k < 128; ++k) acc += z2[(size_t)r * 128 + k] * W5[k];
  out[r] = acc;
}

// ---------------------------------------------------------------------------
extern "C" void kernel_launch(void* const* d_in, const int* in_sizes, int n_in,
                              void* d_out, int out_size, void* d_ws,
                              size_t ws_size, hipStream_t stream) {
  const float* x0 = (const float*)d_in[0];
  const float* x1 = (const float*)d_in[3];
  const int* ei0 = (const int*)d_in[1];
  const int* ei1 = (const int*)d_in[4];
  const int* ba0 = (const int*)d_in[2];
  const int* ba1 = (const int*)d_in[5];
  const float* gamma = (const float*)d_in[6];
  const float* beta = (const float*)d_in[7];
  const float* W1 = (const float*)d_in[8];
  const float* b1 = (const float*)d_in[9];
  const float* W2 = (const float*)d_in[10];
  const float* b2 = (const float*)d_in[11];
  const float* Wc[3] = {(const float*)d_in[12], (const float*)d_in[14],
                        (const float*)d_in[16]};
  const float* bc[3] = {(const float*)d_in[13], (const float*)d_in[15],
                        (const float*)d_in[17]};
  const float* W3 = (const float*)d_in[18];
  const float* b3 = (const float*)d_in[19];
  const float* W4 = (const float*)d_in[20];
  const float* b4 = (const float*)d_in[21];
  const float* W5 = (const float*)d_in[22];
  const float* b5 = (const float*)d_in[23];
  float* out = (float*)d_out;

  const int N = in_sizes[0] / 64;  // 50000
  const int E = in_sizes[1] / 2;   // 600000
  const int B = out_size;          // 512

  // ---- workspace layout (f16 activations, both towers resident) ----
  f16* fp = (f16*)d_ws;
  f16* h0_16 = fp; fp += (size_t)2 * N * 256;  // GEMM1 out
  f16* hA16 = fp; fp += (size_t)2 * N * 128;   // activation ping
  f16* hB16 = fp; fp += (size_t)2 * N * 128;   // activation pong
  f16* xw16 = fp; fp += (size_t)2 * N * 128;   // conv GEMM out (dinv-scaled)
  float* dinv = (float*)fp;                    // 2*N
  u16* esrc = (u16*)(dinv + (size_t)2 * N);    // 2*E
  int* degc = (int*)(esrc + (size_t)2 * E);    // 2*N
  int* rowstart = degc + (size_t)2 * N;        // 2*(N+1)
  int* cursor = rowstart + (size_t)2 * (N + 1);
  int* bsum = cursor + (size_t)2 * N;          // 128
  int* bstart = bsum + 128;                    // 2*(B+1)
  float* bnsum = (float*)(bstart + 2 * (B + 1));
  float* bnsq = bnsum + 128;
  float* W1f = bnsq + 128;                     // 2*16384
  float* b1f = W1f + 2 * 16384;                // 512
  float* catb = b1f + 512;                     // B*256
  float* z1 = catb + (size_t)B * 256;          // B*256
  float* z2 = z1 + (size_t)B * 256;            // B*128
  f16* wtp = (f16*)(((uintptr_t)(z2 + (size_t)B * 128) + 63) &
                    ~(uintptr_t)63);
  f16* w1t_h = wtp; wtp += 2 * 16384;
  f16* w1t_l = wtp; wtp += 2 * 16384;
  f16* w2t_h = wtp; wtp += 32768;
  f16* w2t_l = wtp; wtp += 32768;
  f16* wct_h[3]; f16* wct_l[3];
  for (int c = 0; c < 3; ++c) {
    wct_h[c] = wtp; wtp += 16384;
    wct_l[c] = wtp; wtp += 16384;
  }
  f16* w3t_h = wtp; wtp += 65536;
  f16* w3t_l = wtp; wtp += 65536;
  f16* w4t_h = wtp; wtp += 32768;
  f16* w4t_l = wtp; wtp += 32768;
  size_t need = (size_t)((char*)wtp - (char*)d_ws);
  if (ws_size < need) return;

  f16* h0_[2] = {h0_16, h0_16 + (size_t)N * 256};
  f16* hA_[2] = {hA16, hA16 + (size_t)N * 128};
  f16* hB_[2] = {hB16, hB16 + (size_t)N * 128};

  const int nb_e = (E + 255) / 256;
  const int nb_scan = (N + 1023) / 1024;
  const int nb_g16 = (N * 16 + 255) / 256;          // blocks per tower
  const int g_grid = ((nb_g16 + 3) / 4) * 8;        // XCD-decoded 1D grid
  const int gby = (N + 63) / 64;  // 782

  hipMemsetAsync(degc, 0, (size_t)2 * N * sizeof(int), stream);
  hipMemsetAsync(bnsum, 0, 256 * sizeof(float), stream);

  // ---- shared weights: transpose+split once ----
  wtrans_k<<<dim3(2, 64, 1), 256, 0, stream>>>(W2, 0, w2t_h, w2t_l, 0, 256,
                                               128);
  for (int c = 0; c < 3; ++c)
    wtrans_k<<<dim3(2, 32, 1), 256, 0, stream>>>(Wc[c], 0, wct_h[c], wct_l[c],
                                                 0, 128, 128);
  wtrans_k<<<dim3(4, 64, 1), 256, 0, stream>>>(W3, 0, w3t_h, w3t_l, 0, 256,
                                               256);
  wtrans_k<<<dim3(2, 64, 1), 256, 0, stream>>>(W4, 0, w4t_h, w4t_l, 0, 256,
                                               128);

  // ---- BN -> folded W1 (per tower) ----
  bn_stats_k<<<dim3(256, 1, 2), 256, 0, stream>>>(x0, x1, bnsum, bnsq, N);
  bn_fold_k<<<2, 256, 0, stream>>>(bnsum, bnsq, gamma, beta, W1, b1, W1f, b1f,
                                   1.0f / (float)N);
  wtrans_k<<<dim3(4, 16, 2), 256, 0, stream>>>(W1f, 16384, w1t_h, w1t_l,
                                               16384, 64, 256);

  // ---- dense head of each tower (f16 chain) ----
  gemm_a32_f16o<<<dim3(2, gby, 2), 256, 0, stream>>>(
      x0, x1, w1t_h, w1t_h + 16384, w1t_l, w1t_l + 16384, b1f, b1f + 256,
      h0_[0], h0_[1], N, 256, 64, 1);
  gemm_a16_f16o<<<dim3(1, gby, 2), 256, 0, stream>>>(
      h0_[0], h0_[1], w2t_h, w2t_l, b2, nullptr, hA_[0], hA_[1], N, 128, 256,
      1);

  // ---- CSR build ----
  count_deg_k<<<dim3(nb_e, 1, 2), 256, 0, stream>>>(ei0, ei1, degc, E, N);
  scan1_k<<<dim3(nb_scan, 1, 2), 256, 0, stream>>>(degc, bsum, N);
  scan2_k<<<dim3(1, 1, 2), 64, 0, stream>>>(bsum, nb_scan);
  scan3_k<<<dim3(nb_scan, 1, 2), 256, 0, stream>>>(degc, bsum, rowstart,
                                                   cursor, dinv, N, E);
  fill8_k<<<dim3(nb_e * 8, 1, 2), 256, 0, stream>>>(ei0, ei1, cursor, esrc, E,
                                                    N);
  bstart_k<<<dim3((B + 256) / 256, 1, 2), 256, 0, stream>>>(ba0, ba1, bstart,
                                                            N, B);

  // ---- 3 conv layers: GEMM(f16, dinv-scaled) + gather (f16 out) ----
  // chain: hA -> (c0) hB -> (c1) hA -> (c2) hB
  f16* cin[3][2] = {{hA_[0], hA_[1]}, {hB_[0], hB_[1]}, {hA_[0], hA_[1]}};
  f16* cout[3][2] = {{hB_[0], hB_[1]}, {hA_[0], hA_[1]}, {hB_[0], hB_[1]}};
  for (int c = 0; c < 3; ++c) {
    gemm_a16_f16o<<<dim3(1, gby, 2), 256, 0, stream>>>(
        cin[c][0], cin[c][1], wct_h[c], wct_l[c], nullptr, dinv, xw16,
        xw16 + (size_t)N * 128, N, 128, 128, 0);
    gather16_k<<<dim3(g_grid, 1, 1), 256, 0, stream>>>(
        rowstart, esrc, xw16, dinv, bc[c], cout[c][0], cout[c][1], N, E,
        nb_g16);
  }

  // ---- pool (both towers) ----
  pool_seg_k<<<dim3(B, 1, 2), 128, 0, stream>>>(hB_[0], hB_[1], bstart, catb,
                                                B);

  // ---- head MLP (f32) ----
  gemm_a32_f32o<<<dim3(2, (B + 63) / 64, 1), 256, 0, stream>>>(
      catb, w3t_h, w3t_l, b3, z1, B, 256, 256, 1);
  gemm_a32_f32o<<<dim3(1, (B + 63) / 64, 1), 256, 0, stream>>>(
      z1, w4t_h, w4t_l, b4, z2, B, 128, 256, 1);
  final_k<<<(B + 255) / 256, 256, 0, stream>>>(z2, W5, b5, out, B);
}